// Round 4
// baseline (157.030 us; speedup 1.0000x reference)
//
#include <hip/hip_runtime.h>
#include <hip/hip_bf16.h>
#include <math.h>
#include <stdint.h>

// Problem constants (SparseAttention_46969762349725)
#define HEADS 8
#define IN_C  256
#define MDL   512
#define NB    4        // batch
#define LL    4096     // nodes
#define NE    65536    // edges
#define EDIM  64       // per-head dim = MDL/HEADS
#define TEMP  0.125f   // 1/sqrt(64)

typedef __bf16 bf16x8 __attribute__((ext_vector_type(8)));
typedef float  f32x4  __attribute__((ext_vector_type(4)));
typedef short  short8 __attribute__((ext_vector_type(8)));

__device__ __forceinline__ void glds16(const void* g, void* l) {
    __builtin_amdgcn_global_load_lds(
        (const __attribute__((address_space(1))) void*)g,
        (__attribute__((address_space(3))) void*)l, 16, 0, 0);
}

// ---------------- bf16 MFMA GEMM body ---------------------------------------
// 128x128 tile, BK=32, 4 waves (2x2, 64x64 each), 16x16x32 bf16 MFMA.
template<int OUTBF>
__device__ __forceinline__ void gemm_body(
    const __hip_bfloat16* __restrict__ A, const __hip_bfloat16* __restrict__ Bt,
    const float* __restrict__ bias, float* __restrict__ Cf,
    __hip_bfloat16* __restrict__ Cb, int M, int N, int K,
    __hip_bfloat16* As, __hip_bfloat16* Bs)
{
    const int tid  = threadIdx.x;
    const int lane = tid & 63;
    const int w    = tid >> 6;
    const int wr   = w >> 1, wc = w & 1;
    const int bm   = blockIdx.y * 128, bn = blockIdx.x * 128;

    const int r0 = tid >> 2;
    const int c0 = (tid & 3) ^ (r0 & 3);
    const int r1 = (256 + tid) >> 2;
    const int c1 = ((256 + tid) & 3) ^ (r1 & 3);
    const __hip_bfloat16* gA0 = A  + (size_t)(bm + r0) * K + c0 * 8;
    const __hip_bfloat16* gA1 = A  + (size_t)(bm + r1) * K + c1 * 8;
    const __hip_bfloat16* gB0 = Bt + (size_t)(bn + r0) * K + c0 * 8;
    const __hip_bfloat16* gB1 = Bt + (size_t)(bn + r1) * K + c1 * 8;
    __hip_bfloat16* lA0 = As + (size_t)(w * 64) * 8;
    __hip_bfloat16* lA1 = As + (size_t)(256 + w * 64) * 8;
    __hip_bfloat16* lB0 = Bs + (size_t)(w * 64) * 8;
    __hip_bfloat16* lB1 = Bs + (size_t)(256 + w * 64) * 8;

    int fa[4], fb[4];
    #pragma unroll
    for (int i = 0; i < 4; i++) {
        int rA = wr * 64 + i * 16 + (lane & 15);
        fa[i] = rA * 32 + (((lane >> 4) ^ (rA & 3)) * 8);
        int rB = wc * 64 + i * 16 + (lane & 15);
        fb[i] = rB * 32 + (((lane >> 4) ^ (rB & 3)) * 8);
    }

    f32x4 acc[4][4] = {};

    for (int k0 = 0; k0 < K; k0 += 32) {
        glds16(gA0 + k0, lA0);
        glds16(gA1 + k0, lA1);
        glds16(gB0 + k0, lB0);
        glds16(gB1 + k0, lB1);
        __syncthreads();

        bf16x8 av[4], bv[4];
        #pragma unroll
        for (int i = 0; i < 4; i++) av[i] = *(const bf16x8*)(As + fa[i]);
        #pragma unroll
        for (int i = 0; i < 4; i++) bv[i] = *(const bf16x8*)(Bs + fb[i]);
        #pragma unroll
        for (int mi = 0; mi < 4; mi++)
            #pragma unroll
            for (int ni = 0; ni < 4; ni++)
                acc[mi][ni] = __builtin_amdgcn_mfma_f32_16x16x32_bf16(
                    av[mi], bv[ni], acc[mi][ni], 0, 0, 0);
        __syncthreads();
    }

    #pragma unroll
    for (int mi = 0; mi < 4; mi++) {
        int row = bm + wr * 64 + mi * 16 + (lane >> 4) * 4;
        #pragma unroll
        for (int ni = 0; ni < 4; ni++) {
            int col = bn + wc * 64 + ni * 16 + (lane & 15);
            float bb = bias[col];
            #pragma unroll
            for (int j = 0; j < 4; j++) {
                float vv = acc[mi][ni][j] + bb;
                if (OUTBF) Cb[(size_t)(row + j) * N + col] = __float2bfloat16(vv);
                else       Cf[(size_t)(row + j) * N + col] = vv;
            }
        }
    }
}

// QKV: one launch, gridDim.z = 3 selects the matrix
__global__ __launch_bounds__(256) void gemm_qkv(
    const __hip_bfloat16* __restrict__ A0, const __hip_bfloat16* __restrict__ A1,
    const __hip_bfloat16* __restrict__ A2,
    const __hip_bfloat16* __restrict__ B0, const __hip_bfloat16* __restrict__ B1,
    const __hip_bfloat16* __restrict__ B2,
    const float* __restrict__ b0, const float* __restrict__ b1,
    const float* __restrict__ b2,
    __hip_bfloat16* __restrict__ C0, __hip_bfloat16* __restrict__ C1,
    __hip_bfloat16* __restrict__ C2, int M, int N, int K)
{
    __shared__ __align__(16) __hip_bfloat16 As[128 * 32];
    __shared__ __align__(16) __hip_bfloat16 Bs[128 * 32];
    int z = blockIdx.z;
    const __hip_bfloat16* A  = (z == 0) ? A0 : (z == 1) ? A1 : A2;
    const __hip_bfloat16* Bt = (z == 0) ? B0 : (z == 1) ? B1 : B2;
    const float* bias        = (z == 0) ? b0 : (z == 1) ? b1 : b2;
    __hip_bfloat16* C        = (z == 0) ? C0 : (z == 1) ? C1 : C2;
    gemm_body<1>(A, Bt, bias, nullptr, C, M, N, K, As, Bs);
}

__global__ __launch_bounds__(256) void gemm_out(
    const __hip_bfloat16* __restrict__ A, const __hip_bfloat16* __restrict__ Bt,
    const float* __restrict__ bias, float* __restrict__ C, int M, int N, int K)
{
    __shared__ __align__(16) __hip_bfloat16 As[128 * 32];
    __shared__ __align__(16) __hip_bfloat16 Bs[128 * 32];
    gemm_body<0>(A, Bt, bias, C, nullptr, M, N, K, As, Bs);
}

// ---------------- CSR build over dst = adj[0] --------------------------------
__global__ void count_edges(const int* __restrict__ dst, int* __restrict__ counts, int ne) {
    int e = blockIdx.x * blockDim.x + threadIdx.x;
    if (e < ne) atomicAdd(&counts[dst[e]], 1);
}

__global__ __launch_bounds__(1024) void scan_offsets(
    const int* __restrict__ counts, int* __restrict__ offsets, int* __restrict__ cursor)
{
    __shared__ int wsum[16];
    const int tid  = threadIdx.x;
    const int lane = tid & 63;
    const int wid  = tid >> 6;

    int c[4];
    int base = tid * 4;
    int s = 0;
    #pragma unroll
    for (int i = 0; i < 4; i++) { c[i] = counts[base + i]; s += c[i]; }

    int v = s;
    #pragma unroll
    for (int off = 1; off < 64; off <<= 1) {
        int t = __shfl_up(v, off);
        if (lane >= off) v += t;
    }
    if (lane == 63) wsum[wid] = v;
    __syncthreads();
    if (wid == 0) {
        int wv = (lane < 16) ? wsum[lane] : 0;
        #pragma unroll
        for (int off = 1; off < 16; off <<= 1) {
            int t = __shfl_up(wv, off);
            if (lane >= off) wv += t;
        }
        if (lane < 16) wsum[lane] = wv;
    }
    __syncthreads();

    int prefix = (wid > 0 ? wsum[wid - 1] : 0) + (v - s);
    int run = prefix;
    #pragma unroll
    for (int i = 0; i < 4; i++) {
        offsets[base + i] = run;
        cursor[base + i]  = run;
        run += c[i];
    }
    if (tid == 1023) offsets[4096] = run;
}

// ---------------- fused prep: scatter(+gather) | cvt fp32->bf16 | transposes -
// blocks [0,256): scatter edges + gather src/epe into CSR order
// blocks [256,6400): convert q/k/v inputs to bf16 (N8 float4-pairs each)
// blocks [6400,7040): weight transpose+convert W[K][N] -> Wt[N][K] bf16
#define N8 524288   // (16384*256)/8 per input
__global__ __launch_bounds__(256) void prep(
    const int* __restrict__ dst, const int* __restrict__ srcarr,
    const float* __restrict__ epe, int* __restrict__ cursor,
    int* __restrict__ src_s, float* __restrict__ epe_s,
    const float* __restrict__ q, const float* __restrict__ k,
    const float* __restrict__ v,
    __hip_bfloat16* __restrict__ Qin, __hip_bfloat16* __restrict__ Kin,
    __hip_bfloat16* __restrict__ Vin,
    const float* __restrict__ Wq, const float* __restrict__ Wk,
    const float* __restrict__ Wv, const float* __restrict__ Wo,
    __hip_bfloat16* __restrict__ Wqt, __hip_bfloat16* __restrict__ Wkt,
    __hip_bfloat16* __restrict__ Wvt, __hip_bfloat16* __restrict__ Wot)
{
    __shared__ float t[32][33];
    const int b = blockIdx.x;

    if (b < 256) {
        // ---- scatter + gather ----
        int e = b * 256 + threadIdx.x;
        int p = atomicAdd(&cursor[dst[e]], 1);
        src_s[p] = srcarr[e];
        #pragma unroll
        for (int n = 0; n < NB; n++) {
            float4 a2, b2;
            const float* base = epe + (size_t)(n * HEADS) * NE + e;
            a2.x = base[0 * NE]; a2.y = base[1 * NE]; a2.z = base[2 * NE]; a2.w = base[3 * NE];
            b2.x = base[4 * NE]; b2.y = base[5 * NE]; b2.z = base[6 * NE]; b2.w = base[7 * NE];
            float* o = epe_s + ((size_t)n * NE + p) * 8;
            *(float4*)o       = a2;
            *(float4*)(o + 4) = b2;
        }
    } else if (b < 6400) {
        // ---- input conversion ----
        int i = (b - 256) * 256 + threadIdx.x;      // 0 .. 3*N8
        int which = i >> 19;                         // /N8
        int j = i & (N8 - 1);
        const float* x = (which == 0) ? q : (which == 1) ? k : v;
        __hip_bfloat16* y = (which == 0) ? Qin : (which == 1) ? Kin : Vin;
        const float4* xv = (const float4*)x;
        float4 a2 = xv[2 * j], b2 = xv[2 * j + 1];
        union { short8 v8; __hip_bfloat16 h[8]; } u;
        u.h[0] = __float2bfloat16(a2.x); u.h[1] = __float2bfloat16(a2.y);
        u.h[2] = __float2bfloat16(a2.z); u.h[3] = __float2bfloat16(a2.w);
        u.h[4] = __float2bfloat16(b2.x); u.h[5] = __float2bfloat16(b2.y);
        u.h[6] = __float2bfloat16(b2.z); u.h[7] = __float2bfloat16(b2.w);
        *(short8*)(y + (size_t)j * 8) = u.v8;
    } else {
        // ---- weight transpose ----
        int bb = b - 6400;
        const float* W; __hip_bfloat16* Wt; int K, tt;
        if (bb < 384) {
            int m = bb >> 7; tt = bb & 127; K = IN_C;
            W  = (m == 0) ? Wq  : (m == 1) ? Wk  : Wv;
            Wt = (m == 0) ? Wqt : (m == 1) ? Wkt : Wvt;
        } else {
            tt = bb - 384; K = MDL; W = Wo; Wt = Wot;
        }
        const int N = MDL;
        int bx = (tt & 15) * 32;            // n
        int by = (tt >> 4) * 32;            // k
        int tx = threadIdx.x & 31, ty = threadIdx.x >> 5;   // 32 x 8
        #pragma unroll
        for (int i = 0; i < 4; i++)
            t[ty + i * 8][tx] = W[(size_t)(by + ty + i * 8) * N + bx + tx];
        __syncthreads();
        #pragma unroll
        for (int i = 0; i < 4; i++)
            Wt[(size_t)(bx + ty + i * 8) * K + by + tx] =
                __float2bfloat16(t[tx][ty + i * 8]);
    }
}

// ---------------- fused sparse attention, XCD-partitioned, 3-deep pipeline ---
// wave = one (n, dst) node; 8-lane group per head; lane holds 8 dims (bf16x8).
// n = (blockIdx%8)>>1 : each batch's K/V working set touched by only 2 XCDs.
__global__ __launch_bounds__(128, 3) void sparse_attn4(
    const __hip_bfloat16* __restrict__ Qb, const __hip_bfloat16* __restrict__ Kb,
    const __hip_bfloat16* __restrict__ Vb,
    const int* __restrict__ src_s, const float* __restrict__ epe_s,
    const int* __restrict__ offsets, __hip_bfloat16* __restrict__ O)
{
    const int lane = threadIdx.x & 63;
    const int bid  = blockIdx.x;                     // 8192
    const int xcd  = bid & 7;
    const int n    = xcd >> 1;                       // 2 XCDs per batch n
    const int dstn = ((((bid >> 3) << 1) | (xcd & 1)) << 1) | (threadIdx.x >> 6);
    const int task = n * LL + dstn;
    const int hg   = lane >> 3;                      // head 0..7

    const size_t rowbase = (size_t)task * MDL;
    const int beg = offsets[dstn];
    const int end = offsets[dstn + 1];

    union { short8 v8; __hip_bfloat16 h[8]; } uo;
    if (beg == end) {
        #pragma unroll
        for (int j = 0; j < 8; j++) uo.h[j] = __float2bfloat16(0.0f);
        *(short8*)(O + rowbase + lane * 8) = uo.v8;
        return;
    }

    bf16x8 q8 = *(const bf16x8*)(Qb + rowbase + lane * 8);
    float qf[8];
    #pragma unroll
    for (int j = 0; j < 8; j++) qf[j] = (float)q8[j];

    const __hip_bfloat16* Kn = Kb + (size_t)n * LL * MDL + lane * 8;
    const __hip_bfloat16* Vn = Vb + (size_t)n * LL * MDL + lane * 8;
    const float* pe_n = epe_s + (size_t)n * NE * 8 + hg;

    float m = -INFINITY, z = 0.0f;
    float acc[8] = {};

    bf16x8 k0[4], v0[4], k1[4], v1[4], k2[4], v2[4];
    float  p0[4], p1[4], p2[4];

    #define LOADB(i, kk, vv, pp)                                            \
        _Pragma("unroll")                                                   \
        for (int j = 0; j < 4; j++) {                                       \
            int idx = (i) + j;                                              \
            int ok  = idx < end;                                            \
            int s   = ok ? src_s[idx] : 0;                                  \
            size_t rk = (size_t)s * MDL;                                    \
            kk[j] = *(const bf16x8*)(Kn + rk);                              \
            vv[j] = *(const bf16x8*)(Vn + rk);                              \
            pp[j] = ok ? pe_n[(size_t)idx * 8] : -INFINITY;                 \
        }

    #define COMPUTE(kk, vv, pp)                                             \
    {                                                                       \
        float sc4[4];                                                       \
        _Pragma("unroll")                                                   \
        for (int j = 0; j < 4; j++) {                                       \
            float d = 0.0f;                                                 \
            _Pragma("unroll")                                               \
            for (int dd = 0; dd < 8; dd++) d += qf[dd] * (float)kk[j][dd];  \
            d += __shfl_xor(d, 1);                                          \
            d += __shfl_xor(d, 2);                                          \
            d += __shfl_xor(d, 4);                                          \
            sc4[j] = TEMP * (d + pp[j]);                                    \
        }                                                                   \
        float mb   = fmaxf(fmaxf(sc4[0], sc4[1]), fmaxf(sc4[2], sc4[3]));   \
        float mnew = fmaxf(m, mb);                                          \
        float sc   = __expf(m - mnew);                                      \
        float pe0 = __expf(sc4[0] - mnew);                                  \
        float pe1 = __expf(sc4[1] - mnew);                                  \
        float pe2 = __expf(sc4[2] - mnew);                                  \
        float pe3 = __expf(sc4[3] - mnew);                                  \
        z = z * sc + (pe0 + pe1 + pe2 + pe3);                               \
        _Pragma("unroll")                                                   \
        for (int dd = 0; dd < 8; dd++) {                                    \
            float tt = acc[dd] * sc;                                        \
            tt = fmaf(pe0, (float)vv[0][dd], tt);                           \
            tt = fmaf(pe1, (float)vv[1][dd], tt);                           \
            tt = fmaf(pe2, (float)vv[2][dd], tt);                           \
            tt = fmaf(pe3, (float)vv[3][dd], tt);                           \
            acc[dd] = tt;                                                   \
        }                                                                   \
        m = mnew;                                                           \
    }

    // prologue: fill 2 batches
    LOADB(beg,     k0, v0, p0)
    LOADB(beg + 4, k1, v1, p1)

    // 3-way rotated main loop: load (i+8) into the free set, compute current
    int i = beg;
    while (true) {
        LOADB(i + 8, k2, v2, p2)
        COMPUTE(k0, v0, p0)
        i += 4; if (i >= end) break;
        LOADB(i + 8, k0, v0, p0)
        COMPUTE(k1, v1, p1)
        i += 4; if (i >= end) break;
        LOADB(i + 8, k1, v1, p1)
        COMPUTE(k2, v2, p2)
        i += 4; if (i >= end) break;
    }

    float inv = 1.0f / z;
    #pragma unroll
    for (int j = 0; j < 8; j++) uo.h[j] = __float2bfloat16(acc[j] * inv);
    *(short8*)(O + rowbase + lane * 8) = uo.v8;
    #undef LOADB
    #undef COMPUTE
}

// ---------------- launch ------------------------------------------------------
extern "C" void kernel_launch(void* const* d_in, const int* in_sizes, int n_in,
                              void* d_out, int out_size, void* d_ws, size_t ws_size,
                              hipStream_t stream)
{
    const float* queries = (const float*)d_in[0];
    const float* keys    = (const float*)d_in[1];
    const float* values  = (const float*)d_in[2];
    const int*   adj     = (const int*)d_in[3];
    const float* epe     = (const float*)d_in[4];
    const float* Wq = (const float*)d_in[5];
    const float* bq = (const float*)d_in[6];
    const float* Wk = (const float*)d_in[7];
    const float* bk = (const float*)d_in[8];
    const float* Wv = (const float*)d_in[9];
    const float* bv = (const float*)d_in[10];
    const float* Wo = (const float*)d_in[11];
    const float* bo = (const float*)d_in[12];
    float* out = (float*)d_out;

    const int* dst = adj;
    const int* src = adj + NE;

    const int    M   = NB * LL;                     // 16384
    const size_t NLM = (size_t)M * MDL;             // 8,388,608
    const size_t NLK = (size_t)M * IN_C;            // 4,194,304

    char* w = (char*)d_ws;
    __hip_bfloat16* Qb  = (__hip_bfloat16*)w; w += NLM * 2;      // 16.78 MB
    __hip_bfloat16* Kb  = (__hip_bfloat16*)w; w += NLM * 2;
    __hip_bfloat16* Vb  = (__hip_bfloat16*)w; w += NLM * 2;
    char* inbf_base = w;
    __hip_bfloat16* Qin = (__hip_bfloat16*)w; w += NLK * 2;      // 8.39 MB
    __hip_bfloat16* Kin = (__hip_bfloat16*)w; w += NLK * 2;
    __hip_bfloat16* Vin = (__hip_bfloat16*)w; w += NLK * 2;
    __hip_bfloat16* Ob  = (__hip_bfloat16*)inbf_base;            // aliases Qin/Kin
    __hip_bfloat16* Wqt = (__hip_bfloat16*)w; w += (size_t)MDL * IN_C * 2;
    __hip_bfloat16* Wkt = (__hip_bfloat16*)w; w += (size_t)MDL * IN_C * 2;
    __hip_bfloat16* Wvt = (__hip_bfloat16*)w; w += (size_t)MDL * IN_C * 2;
    __hip_bfloat16* Wot = (__hip_bfloat16*)w; w += (size_t)MDL * MDL * 2;
    int* counts  = (int*)w; w += 4096 * sizeof(int);
    int* offsets = (int*)w; w += 4100 * sizeof(int);
    int* cursor  = (int*)w; w += 4096 * sizeof(int);
    int*   src_s = (int*)w; w += NE * sizeof(int);
    float* epe_s = (float*)w; w += (size_t)NB * NE * 8 * sizeof(float);  // 8.39 MB

    // CSR build
    hipMemsetAsync(counts, 0, 4096 * sizeof(int), stream);
    count_edges<<<NE / 256, 256, 0, stream>>>(dst, counts, NE);
    scan_offsets<<<1, 1024, 0, stream>>>(counts, offsets, cursor);

    // fused prep: scatter+gather | input cvt | weight transposes
    prep<<<7040, 256, 0, stream>>>(dst, src, epe, cursor, src_s, epe_s,
                                   queries, keys, values, Qin, Kin, Vin,
                                   Wq, Wk, Wv, Wo, Wqt, Wkt, Wvt, Wot);

    // QKV projections (one launch, z=3)
    dim3 g3(MDL / 128, M / 128, 3);
    gemm_qkv<<<g3, 256, 0, stream>>>(Qin, Kin, Vin, Wqt, Wkt, Wvt, bq, bk, bv,
                                     Qb, Kb, Vb, M, MDL, IN_C);

    // fused sparse attention (16384 node-waves, 2 waves/block, XCD-partitioned)
    sparse_attn4<<<(NB * LL) / 2, 128, 0, stream>>>(Qb, Kb, Vb, src_s, epe_s, offsets, Ob);

    // output projection (fp32 out + bias)
    dim3 g(MDL / 128, M / 128);
    gemm_out<<<g, 256, 0, stream>>>(Ob, Wot, bo, out, M, MDL, MDL);
}

// Round 5
// 151.652 us; speedup vs baseline: 1.0355x; 1.0355x over previous
//
#include <hip/hip_runtime.h>
#include <hip/hip_bf16.h>
#include <math.h>
#include <stdint.h>

// Problem constants (SparseAttention_46969762349725)
#define HEADS 8
#define IN_C  256
#define MDL   512
#define NB    4        // batch
#define LL    4096     // nodes
#define NE    65536    // edges
#define EDIM  64       // per-head dim = MDL/HEADS
#define TEMP  0.125f   // 1/sqrt(64)

typedef __bf16 bf16x8 __attribute__((ext_vector_type(8)));
typedef float  f32x4  __attribute__((ext_vector_type(4)));
typedef short  short8 __attribute__((ext_vector_type(8)));

__device__ __forceinline__ void glds16(const void* g, void* l) {
    __builtin_amdgcn_global_load_lds(
        (const __attribute__((address_space(1))) void*)g,
        (__attribute__((address_space(3))) void*)l, 16, 0, 0);
}

// ---------------- bf16 MFMA GEMM body ---------------------------------------
// 128x128 tile, BK=32, 4 waves (2x2, 64x64 each), 16x16x32 bf16 MFMA.
template<int OUTBF>
__device__ __forceinline__ void gemm_body(
    const __hip_bfloat16* __restrict__ A, const __hip_bfloat16* __restrict__ Bt,
    const float* __restrict__ bias, float* __restrict__ Cf,
    __hip_bfloat16* __restrict__ Cb, int M, int N, int K,
    __hip_bfloat16* As, __hip_bfloat16* Bs)
{
    const int tid  = threadIdx.x;
    const int lane = tid & 63;
    const int w    = tid >> 6;
    const int wr   = w >> 1, wc = w & 1;
    const int bm   = blockIdx.y * 128, bn = blockIdx.x * 128;

    const int r0 = tid >> 2;
    const int c0 = (tid & 3) ^ (r0 & 3);
    const int r1 = (256 + tid) >> 2;
    const int c1 = ((256 + tid) & 3) ^ (r1 & 3);
    const __hip_bfloat16* gA0 = A  + (size_t)(bm + r0) * K + c0 * 8;
    const __hip_bfloat16* gA1 = A  + (size_t)(bm + r1) * K + c1 * 8;
    const __hip_bfloat16* gB0 = Bt + (size_t)(bn + r0) * K + c0 * 8;
    const __hip_bfloat16* gB1 = Bt + (size_t)(bn + r1) * K + c1 * 8;
    __hip_bfloat16* lA0 = As + (size_t)(w * 64) * 8;
    __hip_bfloat16* lA1 = As + (size_t)(256 + w * 64) * 8;
    __hip_bfloat16* lB0 = Bs + (size_t)(w * 64) * 8;
    __hip_bfloat16* lB1 = Bs + (size_t)(256 + w * 64) * 8;

    int fa[4], fb[4];
    #pragma unroll
    for (int i = 0; i < 4; i++) {
        int rA = wr * 64 + i * 16 + (lane & 15);
        fa[i] = rA * 32 + (((lane >> 4) ^ (rA & 3)) * 8);
        int rB = wc * 64 + i * 16 + (lane & 15);
        fb[i] = rB * 32 + (((lane >> 4) ^ (rB & 3)) * 8);
    }

    f32x4 acc[4][4] = {};

    for (int k0 = 0; k0 < K; k0 += 32) {
        glds16(gA0 + k0, lA0);
        glds16(gA1 + k0, lA1);
        glds16(gB0 + k0, lB0);
        glds16(gB1 + k0, lB1);
        __syncthreads();

        bf16x8 av[4], bv[4];
        #pragma unroll
        for (int i = 0; i < 4; i++) av[i] = *(const bf16x8*)(As + fa[i]);
        #pragma unroll
        for (int i = 0; i < 4; i++) bv[i] = *(const bf16x8*)(Bs + fb[i]);
        #pragma unroll
        for (int mi = 0; mi < 4; mi++)
            #pragma unroll
            for (int ni = 0; ni < 4; ni++)
                acc[mi][ni] = __builtin_amdgcn_mfma_f32_16x16x32_bf16(
                    av[mi], bv[ni], acc[mi][ni], 0, 0, 0);
        __syncthreads();
    }

    #pragma unroll
    for (int mi = 0; mi < 4; mi++) {
        int row = bm + wr * 64 + mi * 16 + (lane >> 4) * 4;
        #pragma unroll
        for (int ni = 0; ni < 4; ni++) {
            int col = bn + wc * 64 + ni * 16 + (lane & 15);
            float bb = bias[col];
            #pragma unroll
            for (int j = 0; j < 4; j++) {
                float vv = acc[mi][ni][j] + bb;
                if (OUTBF) Cb[(size_t)(row + j) * N + col] = __float2bfloat16(vv);
                else       Cf[(size_t)(row + j) * N + col] = vv;
            }
        }
    }
}

// QKV: one launch, gridDim.z = 3 selects the matrix
__global__ __launch_bounds__(256) void gemm_qkv(
    const __hip_bfloat16* __restrict__ A0, const __hip_bfloat16* __restrict__ A1,
    const __hip_bfloat16* __restrict__ A2,
    const __hip_bfloat16* __restrict__ B0, const __hip_bfloat16* __restrict__ B1,
    const __hip_bfloat16* __restrict__ B2,
    const float* __restrict__ b0, const float* __restrict__ b1,
    const float* __restrict__ b2,
    __hip_bfloat16* __restrict__ C0, __hip_bfloat16* __restrict__ C1,
    __hip_bfloat16* __restrict__ C2, int M, int N, int K)
{
    __shared__ __align__(16) __hip_bfloat16 As[128 * 32];
    __shared__ __align__(16) __hip_bfloat16 Bs[128 * 32];
    int z = blockIdx.z;
    const __hip_bfloat16* A  = (z == 0) ? A0 : (z == 1) ? A1 : A2;
    const __hip_bfloat16* Bt = (z == 0) ? B0 : (z == 1) ? B1 : B2;
    const float* bias        = (z == 0) ? b0 : (z == 1) ? b1 : b2;
    __hip_bfloat16* C        = (z == 0) ? C0 : (z == 1) ? C1 : C2;
    gemm_body<1>(A, Bt, bias, nullptr, C, M, N, K, As, Bs);
}

__global__ __launch_bounds__(256) void gemm_out(
    const __hip_bfloat16* __restrict__ A, const __hip_bfloat16* __restrict__ Bt,
    const float* __restrict__ bias, float* __restrict__ C, int M, int N, int K)
{
    __shared__ __align__(16) __hip_bfloat16 As[128 * 32];
    __shared__ __align__(16) __hip_bfloat16 Bs[128 * 32];
    gemm_body<0>(A, Bt, bias, C, nullptr, M, N, K, As, Bs);
}

// ---------------- CSR build over dst = adj[0] --------------------------------
__global__ void count_edges(const int* __restrict__ dst, int* __restrict__ counts, int ne) {
    int e = blockIdx.x * blockDim.x + threadIdx.x;
    if (e < ne) atomicAdd(&counts[dst[e]], 1);
}

__global__ __launch_bounds__(1024) void scan_offsets(
    const int* __restrict__ counts, int* __restrict__ offsets, int* __restrict__ cursor)
{
    __shared__ int wsum[16];
    const int tid  = threadIdx.x;
    const int lane = tid & 63;
    const int wid  = tid >> 6;

    int c[4];
    int base = tid * 4;
    int s = 0;
    #pragma unroll
    for (int i = 0; i < 4; i++) { c[i] = counts[base + i]; s += c[i]; }

    int v = s;
    #pragma unroll
    for (int off = 1; off < 64; off <<= 1) {
        int t = __shfl_up(v, off);
        if (lane >= off) v += t;
    }
    if (lane == 63) wsum[wid] = v;
    __syncthreads();
    if (wid == 0) {
        int wv = (lane < 16) ? wsum[lane] : 0;
        #pragma unroll
        for (int off = 1; off < 16; off <<= 1) {
            int t = __shfl_up(wv, off);
            if (lane >= off) wv += t;
        }
        if (lane < 16) wsum[lane] = wv;
    }
    __syncthreads();

    int prefix = (wid > 0 ? wsum[wid - 1] : 0) + (v - s);
    int run = prefix;
    #pragma unroll
    for (int i = 0; i < 4; i++) {
        offsets[base + i] = run;
        cursor[base + i]  = run;
        run += c[i];
    }
    if (tid == 1023) offsets[4096] = run;
}

// ---------------- fused prep: scatter(+gather) | cvt fp32->bf16 | transposes -
#define N8 524288   // (16384*256)/8 per input
__global__ __launch_bounds__(256) void prep(
    const int* __restrict__ dst, const int* __restrict__ srcarr,
    const float* __restrict__ epe, int* __restrict__ cursor,
    int* __restrict__ src_s, float* __restrict__ epe_s,
    const float* __restrict__ q, const float* __restrict__ k,
    const float* __restrict__ v,
    __hip_bfloat16* __restrict__ Qin, __hip_bfloat16* __restrict__ Kin,
    __hip_bfloat16* __restrict__ Vin,
    const float* __restrict__ Wq, const float* __restrict__ Wk,
    const float* __restrict__ Wv, const float* __restrict__ Wo,
    __hip_bfloat16* __restrict__ Wqt, __hip_bfloat16* __restrict__ Wkt,
    __hip_bfloat16* __restrict__ Wvt, __hip_bfloat16* __restrict__ Wot)
{
    __shared__ float t[32][33];
    const int b = blockIdx.x;

    if (b < 256) {
        // ---- scatter + gather ----
        int e = b * 256 + threadIdx.x;
        int p = atomicAdd(&cursor[dst[e]], 1);
        src_s[p] = srcarr[e];
        #pragma unroll
        for (int n = 0; n < NB; n++) {
            float4 a2, b2;
            const float* base = epe + (size_t)(n * HEADS) * NE + e;
            a2.x = base[0 * NE]; a2.y = base[1 * NE]; a2.z = base[2 * NE]; a2.w = base[3 * NE];
            b2.x = base[4 * NE]; b2.y = base[5 * NE]; b2.z = base[6 * NE]; b2.w = base[7 * NE];
            float* o = epe_s + ((size_t)n * NE + p) * 8;
            *(float4*)o       = a2;
            *(float4*)(o + 4) = b2;
        }
    } else if (b < 6400) {
        // ---- input conversion ----
        int i = (b - 256) * 256 + threadIdx.x;      // 0 .. 3*N8
        int which = i >> 19;                         // /N8
        int j = i & (N8 - 1);
        const float* x = (which == 0) ? q : (which == 1) ? k : v;
        __hip_bfloat16* y = (which == 0) ? Qin : (which == 1) ? Kin : Vin;
        const float4* xv = (const float4*)x;
        float4 a2 = xv[2 * j], b2 = xv[2 * j + 1];
        union { short8 v8; __hip_bfloat16 h[8]; } u;
        u.h[0] = __float2bfloat16(a2.x); u.h[1] = __float2bfloat16(a2.y);
        u.h[2] = __float2bfloat16(a2.z); u.h[3] = __float2bfloat16(a2.w);
        u.h[4] = __float2bfloat16(b2.x); u.h[5] = __float2bfloat16(b2.y);
        u.h[6] = __float2bfloat16(b2.z); u.h[7] = __float2bfloat16(b2.w);
        *(short8*)(y + (size_t)j * 8) = u.v8;
    } else {
        // ---- weight transpose ----
        int bb = b - 6400;
        const float* W; __hip_bfloat16* Wt; int K, tt;
        if (bb < 384) {
            int m = bb >> 7; tt = bb & 127; K = IN_C;
            W  = (m == 0) ? Wq  : (m == 1) ? Wk  : Wv;
            Wt = (m == 0) ? Wqt : (m == 1) ? Wkt : Wvt;
        } else {
            tt = bb - 384; K = MDL; W = Wo; Wt = Wot;
        }
        const int N = MDL;
        int bx = (tt & 15) * 32;            // n
        int by = (tt >> 4) * 32;            // k
        int tx = threadIdx.x & 31, ty = threadIdx.x >> 5;   // 32 x 8
        #pragma unroll
        for (int i = 0; i < 4; i++)
            t[ty + i * 8][tx] = W[(size_t)(by + ty + i * 8) * N + bx + tx];
        __syncthreads();
        #pragma unroll
        for (int i = 0; i < 4; i++)
            Wt[(size_t)(bx + ty + i * 8) * K + by + tx] =
                __float2bfloat16(t[tx][ty + i * 8]);
    }
}

// ---------------- fused sparse attention v5 ----------------------------------
// wave = one (n, dst) node; 8-lane group per head; lane holds 8 dims (bf16x8).
// n = (blockIdx%8)>>1 : each batch's K/V working set touched by only 2 XCDs.
// Node's src indices pre-loaded into registers (one per lane), distributed by
// __shfl -- removes the src_s memory hop from every batch's critical path.
__global__ __launch_bounds__(256) void sparse_attn5(
    const __hip_bfloat16* __restrict__ Qb, const __hip_bfloat16* __restrict__ Kb,
    const __hip_bfloat16* __restrict__ Vb,
    const int* __restrict__ src_s, const float* __restrict__ epe_s,
    const int* __restrict__ offsets, __hip_bfloat16* __restrict__ O)
{
    const int lane = threadIdx.x & 63;
    const int wid  = threadIdx.x >> 6;               // 0..3
    const int bid  = blockIdx.x;                     // 0..4095
    const int xcd  = bid & 7;
    const int n    = xcd >> 1;                       // 2 XCDs per batch n
    const int base = ((bid >> 3) << 1) | (xcd & 1);  // 0..1023
    const int dstn = (base << 2) | wid;
    const int task = n * LL + dstn;
    const int hg   = lane >> 3;                      // head 0..7

    const size_t rowbase = (size_t)task * MDL;
    const int beg = offsets[dstn];
    const int end = offsets[dstn + 1];

    union { short8 v8; __hip_bfloat16 h[8]; } uo;
    if (beg == end) {
        #pragma unroll
        for (int j = 0; j < 8; j++) uo.h[j] = __float2bfloat16(0.0f);
        *(short8*)(O + rowbase + lane * 8) = uo.v8;
        return;
    }

    // whole edge list -> registers (covers degree <= 64; guarded fallback past)
    int my_src = src_s[(beg + lane < end) ? (beg + lane) : (end - 1)];

    bf16x8 q8 = *(const bf16x8*)(Qb + rowbase + lane * 8);
    float qf[8];
    #pragma unroll
    for (int j = 0; j < 8; j++) qf[j] = (float)q8[j];

    const __hip_bfloat16* Kn = Kb + (size_t)n * LL * MDL + lane * 8;
    const __hip_bfloat16* Vn = Vb + (size_t)n * LL * MDL + lane * 8;
    const float* pe_n = epe_s + (size_t)n * NE * 8 + hg;

    float m = -INFINITY, z = 0.0f;
    float acc[8] = {};

    bf16x8 ka[4], va[4], kb2[4], vb2[4];
    float  pa[4], pb2[4];

    #define LOADB(i, kk, vv, pp)                                            \
        _Pragma("unroll")                                                   \
        for (int j = 0; j < 4; j++) {                                       \
            int idx = (i) + j;                                              \
            int rel = idx - beg;                                            \
            int ok  = idx < end;                                            \
            int s;                                                          \
            if (rel < 64) s = __shfl(my_src, rel);  /* wave-uniform branch */\
            else          s = ok ? src_s[idx] : 0;                          \
            s = ok ? s : 0;                                                 \
            size_t rk = (size_t)s * MDL;                                    \
            kk[j] = *(const bf16x8*)(Kn + rk);                              \
            vv[j] = *(const bf16x8*)(Vn + rk);                              \
            pp[j] = ok ? pe_n[(size_t)idx * 8] : -INFINITY;                 \
        }

    #define COMPUTE(kk, vv, pp)                                             \
    {                                                                       \
        float sc4[4];                                                       \
        _Pragma("unroll")                                                   \
        for (int j = 0; j < 4; j++) {                                       \
            float d = 0.0f;                                                 \
            _Pragma("unroll")                                               \
            for (int dd = 0; dd < 8; dd++) d += qf[dd] * (float)kk[j][dd];  \
            d += __shfl_xor(d, 1);                                          \
            d += __shfl_xor(d, 2);                                          \
            d += __shfl_xor(d, 4);                                          \
            sc4[j] = TEMP * (d + pp[j]);                                    \
        }                                                                   \
        float mb   = fmaxf(fmaxf(sc4[0], sc4[1]), fmaxf(sc4[2], sc4[3]));   \
        float mnew = fmaxf(m, mb);                                          \
        float sc   = __expf(m - mnew);                                      \
        float pe0 = __expf(sc4[0] - mnew);                                  \
        float pe1 = __expf(sc4[1] - mnew);                                  \
        float pe2 = __expf(sc4[2] - mnew);                                  \
        float pe3 = __expf(sc4[3] - mnew);                                  \
        z = z * sc + (pe0 + pe1 + pe2 + pe3);                               \
        _Pragma("unroll")                                                   \
        for (int dd = 0; dd < 8; dd++) {                                    \
            float tt = acc[dd] * sc;                                        \
            tt = fmaf(pe0, (float)vv[0][dd], tt);                           \
            tt = fmaf(pe1, (float)vv[1][dd], tt);                           \
            tt = fmaf(pe2, (float)vv[2][dd], tt);                           \
            tt = fmaf(pe3, (float)vv[3][dd], tt);                           \
            acc[dd] = tt;                                                   \
        }                                                                   \
        m = mnew;                                                           \
    }

    LOADB(beg, ka, va, pa)

    for (int i = beg; i < end; i += 4) {
        if (i + 4 < end) { LOADB(i + 4, kb2, vb2, pb2) }
        COMPUTE(ka, va, pa)
        #pragma unroll
        for (int j = 0; j < 4; j++) { ka[j] = kb2[j]; va[j] = vb2[j]; pa[j] = pb2[j]; }
    }

    float inv = 1.0f / z;
    #pragma unroll
    for (int j = 0; j < 8; j++) uo.h[j] = __float2bfloat16(acc[j] * inv);
    *(short8*)(O + rowbase + lane * 8) = uo.v8;
    #undef LOADB
    #undef COMPUTE
}

// ---------------- launch ------------------------------------------------------
extern "C" void kernel_launch(void* const* d_in, const int* in_sizes, int n_in,
                              void* d_out, int out_size, void* d_ws, size_t ws_size,
                              hipStream_t stream)
{
    const float* queries = (const float*)d_in[0];
    const float* keys    = (const float*)d_in[1];
    const float* values  = (const float*)d_in[2];
    const int*   adj     = (const int*)d_in[3];
    const float* epe     = (const float*)d_in[4];
    const float* Wq = (const float*)d_in[5];
    const float* bq = (const float*)d_in[6];
    const float* Wk = (const float*)d_in[7];
    const float* bk = (const float*)d_in[8];
    const float* Wv = (const float*)d_in[9];
    const float* bv = (const float*)d_in[10];
    const float* Wo = (const float*)d_in[11];
    const float* bo = (const float*)d_in[12];
    float* out = (float*)d_out;

    const int* dst = adj;
    const int* src = adj + NE;

    const int    M   = NB * LL;                     // 16384
    const size_t NLM = (size_t)M * MDL;             // 8,388,608
    const size_t NLK = (size_t)M * IN_C;            // 4,194,304

    char* w = (char*)d_ws;
    __hip_bfloat16* Qb  = (__hip_bfloat16*)w; w += NLM * 2;      // 16.78 MB
    __hip_bfloat16* Kb  = (__hip_bfloat16*)w; w += NLM * 2;
    __hip_bfloat16* Vb  = (__hip_bfloat16*)w; w += NLM * 2;
    char* inbf_base = w;
    __hip_bfloat16* Qin = (__hip_bfloat16*)w; w += NLK * 2;      // 8.39 MB
    __hip_bfloat16* Kin = (__hip_bfloat16*)w; w += NLK * 2;
    __hip_bfloat16* Vin = (__hip_bfloat16*)w; w += NLK * 2;
    __hip_bfloat16* Ob  = (__hip_bfloat16*)inbf_base;            // aliases Qin/Kin
    __hip_bfloat16* Wqt = (__hip_bfloat16*)w; w += (size_t)MDL * IN_C * 2;
    __hip_bfloat16* Wkt = (__hip_bfloat16*)w; w += (size_t)MDL * IN_C * 2;
    __hip_bfloat16* Wvt = (__hip_bfloat16*)w; w += (size_t)MDL * IN_C * 2;
    __hip_bfloat16* Wot = (__hip_bfloat16*)w; w += (size_t)MDL * MDL * 2;
    int* counts  = (int*)w; w += 4096 * sizeof(int);
    int* offsets = (int*)w; w += 4100 * sizeof(int);
    int* cursor  = (int*)w; w += 4096 * sizeof(int);
    int*   src_s = (int*)w; w += NE * sizeof(int);
    float* epe_s = (float*)w; w += (size_t)NB * NE * 8 * sizeof(float);  // 8.39 MB

    // CSR build
    hipMemsetAsync(counts, 0, 4096 * sizeof(int), stream);
    count_edges<<<NE / 256, 256, 0, stream>>>(dst, counts, NE);
    scan_offsets<<<1, 1024, 0, stream>>>(counts, offsets, cursor);

    // fused prep: scatter+gather | input cvt | weight transposes
    prep<<<7040, 256, 0, stream>>>(dst, src, epe, cursor, src_s, epe_s,
                                   queries, keys, values, Qin, Kin, Vin,
                                   Wq, Wk, Wv, Wo, Wqt, Wkt, Wvt, Wot);

    // QKV projections (one launch, z=3)
    dim3 g3(MDL / 128, M / 128, 3);
    gemm_qkv<<<g3, 256, 0, stream>>>(Qin, Kin, Vin, Wqt, Wkt, Wvt, bq, bk, bv,
                                     Qb, Kb, Vb, M, MDL, IN_C);

    // fused sparse attention (16384 node-waves, 4 waves/block, XCD-partitioned)
    sparse_attn5<<<(NB * LL) / 4, 256, 0, stream>>>(Qb, Kb, Vb, src_s, epe_s, offsets, Ob);

    // output projection (fp32 out + bias)
    dim3 g(MDL / 128, M / 128);
    gemm_out<<<g, 256, 0, stream>>>(Ob, Wot, bo, out, M, MDL, MDL);
}

// Round 6
// 140.203 us; speedup vs baseline: 1.1200x; 1.0817x over previous
//
#include <hip/hip_runtime.h>
#include <hip/hip_bf16.h>
#include <math.h>
#include <stdint.h>

// Problem constants (SparseAttention_46969762349725)
#define HEADS 8
#define IN_C  256
#define MDL   512
#define NB    4        // batch
#define LL    4096     // nodes
#define NE    65536    // edges
#define EDIM  64       // per-head dim = MDL/HEADS
#define TEMP  0.125f   // 1/sqrt(64)

typedef __bf16 bf16x8 __attribute__((ext_vector_type(8)));
typedef float  f32x4  __attribute__((ext_vector_type(4)));
typedef short  short8 __attribute__((ext_vector_type(8)));

__device__ __forceinline__ void glds16(const void* g, void* l) {
    __builtin_amdgcn_global_load_lds(
        (const __attribute__((address_space(1))) void*)g,
        (__attribute__((address_space(3))) void*)l, 16, 0, 0);
}

// ---------------- bf16 MFMA GEMM body ---------------------------------------
// 128x128 tile, BK=32, 4 waves (2x2, 64x64 each), 16x16x32 bf16 MFMA.
template<int OUTBF>
__device__ __forceinline__ void gemm_body(
    const __hip_bfloat16* __restrict__ A, const __hip_bfloat16* __restrict__ Bt,
    const float* __restrict__ bias, float* __restrict__ Cf,
    __hip_bfloat16* __restrict__ Cb, int M, int N, int K,
    __hip_bfloat16* As, __hip_bfloat16* Bs)
{
    const int tid  = threadIdx.x;
    const int lane = tid & 63;
    const int w    = tid >> 6;
    const int wr   = w >> 1, wc = w & 1;
    const int bm   = blockIdx.y * 128, bn = blockIdx.x * 128;

    const int r0 = tid >> 2;
    const int c0 = (tid & 3) ^ (r0 & 3);
    const int r1 = (256 + tid) >> 2;
    const int c1 = ((256 + tid) & 3) ^ (r1 & 3);
    const __hip_bfloat16* gA0 = A  + (size_t)(bm + r0) * K + c0 * 8;
    const __hip_bfloat16* gA1 = A  + (size_t)(bm + r1) * K + c1 * 8;
    const __hip_bfloat16* gB0 = Bt + (size_t)(bn + r0) * K + c0 * 8;
    const __hip_bfloat16* gB1 = Bt + (size_t)(bn + r1) * K + c1 * 8;
    __hip_bfloat16* lA0 = As + (size_t)(w * 64) * 8;
    __hip_bfloat16* lA1 = As + (size_t)(256 + w * 64) * 8;
    __hip_bfloat16* lB0 = Bs + (size_t)(w * 64) * 8;
    __hip_bfloat16* lB1 = Bs + (size_t)(256 + w * 64) * 8;

    int fa[4], fb[4];
    #pragma unroll
    for (int i = 0; i < 4; i++) {
        int rA = wr * 64 + i * 16 + (lane & 15);
        fa[i] = rA * 32 + (((lane >> 4) ^ (rA & 3)) * 8);
        int rB = wc * 64 + i * 16 + (lane & 15);
        fb[i] = rB * 32 + (((lane >> 4) ^ (rB & 3)) * 8);
    }

    f32x4 acc[4][4] = {};

    for (int k0 = 0; k0 < K; k0 += 32) {
        glds16(gA0 + k0, lA0);
        glds16(gA1 + k0, lA1);
        glds16(gB0 + k0, lB0);
        glds16(gB1 + k0, lB1);
        __syncthreads();

        bf16x8 av[4], bv[4];
        #pragma unroll
        for (int i = 0; i < 4; i++) av[i] = *(const bf16x8*)(As + fa[i]);
        #pragma unroll
        for (int i = 0; i < 4; i++) bv[i] = *(const bf16x8*)(Bs + fb[i]);
        #pragma unroll
        for (int mi = 0; mi < 4; mi++)
            #pragma unroll
            for (int ni = 0; ni < 4; ni++)
                acc[mi][ni] = __builtin_amdgcn_mfma_f32_16x16x32_bf16(
                    av[mi], bv[ni], acc[mi][ni], 0, 0, 0);
        __syncthreads();
    }

    #pragma unroll
    for (int mi = 0; mi < 4; mi++) {
        int row = bm + wr * 64 + mi * 16 + (lane >> 4) * 4;
        #pragma unroll
        for (int ni = 0; ni < 4; ni++) {
            int col = bn + wc * 64 + ni * 16 + (lane & 15);
            float bb = bias[col];
            #pragma unroll
            for (int j = 0; j < 4; j++) {
                float vv = acc[mi][ni][j] + bb;
                if (OUTBF) Cb[(size_t)(row + j) * N + col] = __float2bfloat16(vv);
                else       Cf[(size_t)(row + j) * N + col] = vv;
            }
        }
    }
}

// QKV: one launch, gridDim.z = 3 selects the matrix
__global__ __launch_bounds__(256) void gemm_qkv(
    const __hip_bfloat16* __restrict__ A0, const __hip_bfloat16* __restrict__ A1,
    const __hip_bfloat16* __restrict__ A2,
    const __hip_bfloat16* __restrict__ B0, const __hip_bfloat16* __restrict__ B1,
    const __hip_bfloat16* __restrict__ B2,
    const float* __restrict__ b0, const float* __restrict__ b1,
    const float* __restrict__ b2,
    __hip_bfloat16* __restrict__ C0, __hip_bfloat16* __restrict__ C1,
    __hip_bfloat16* __restrict__ C2, int M, int N, int K)
{
    __shared__ __align__(16) __hip_bfloat16 As[128 * 32];
    __shared__ __align__(16) __hip_bfloat16 Bs[128 * 32];
    int z = blockIdx.z;
    const __hip_bfloat16* A  = (z == 0) ? A0 : (z == 1) ? A1 : A2;
    const __hip_bfloat16* Bt = (z == 0) ? B0 : (z == 1) ? B1 : B2;
    const float* bias        = (z == 0) ? b0 : (z == 1) ? b1 : b2;
    __hip_bfloat16* C        = (z == 0) ? C0 : (z == 1) ? C1 : C2;
    gemm_body<1>(A, Bt, bias, nullptr, C, M, N, K, As, Bs);
}

__global__ __launch_bounds__(256) void gemm_out(
    const __hip_bfloat16* __restrict__ A, const __hip_bfloat16* __restrict__ Bt,
    const float* __restrict__ bias, float* __restrict__ C, int M, int N, int K)
{
    __shared__ __align__(16) __hip_bfloat16 As[128 * 32];
    __shared__ __align__(16) __hip_bfloat16 Bs[128 * 32];
    gemm_body<0>(A, Bt, bias, C, nullptr, M, N, K, As, Bs);
}

// ---------------- CSR build over dst = adj[0] --------------------------------
__global__ void count_edges(const int* __restrict__ dst, int* __restrict__ counts, int ne) {
    int e = blockIdx.x * blockDim.x + threadIdx.x;
    if (e < ne) atomicAdd(&counts[dst[e]], 1);
}

__global__ __launch_bounds__(1024) void scan_offsets(
    const int* __restrict__ counts, int* __restrict__ offsets, int* __restrict__ cursor)
{
    __shared__ int wsum[16];
    const int tid  = threadIdx.x;
    const int lane = tid & 63;
    const int wid  = tid >> 6;

    int c[4];
    int base = tid * 4;
    int s = 0;
    #pragma unroll
    for (int i = 0; i < 4; i++) { c[i] = counts[base + i]; s += c[i]; }

    int v = s;
    #pragma unroll
    for (int off = 1; off < 64; off <<= 1) {
        int t = __shfl_up(v, off);
        if (lane >= off) v += t;
    }
    if (lane == 63) wsum[wid] = v;
    __syncthreads();
    if (wid == 0) {
        int wv = (lane < 16) ? wsum[lane] : 0;
        #pragma unroll
        for (int off = 1; off < 16; off <<= 1) {
            int t = __shfl_up(wv, off);
            if (lane >= off) wv += t;
        }
        if (lane < 16) wsum[lane] = wv;
    }
    __syncthreads();

    int prefix = (wid > 0 ? wsum[wid - 1] : 0) + (v - s);
    int run = prefix;
    #pragma unroll
    for (int i = 0; i < 4; i++) {
        offsets[base + i] = run;
        cursor[base + i]  = run;
        run += c[i];
    }
    if (tid == 1023) offsets[4096] = run;
}

// ---------------- fused prep: scatter(+gather) | cvt fp32->bf16 | transposes -
#define N8 524288   // (16384*256)/8 per input
__global__ __launch_bounds__(256) void prep(
    const int* __restrict__ dst, const int* __restrict__ srcarr,
    const float* __restrict__ epe, int* __restrict__ cursor,
    int* __restrict__ src_s, float* __restrict__ epe_s,
    const float* __restrict__ q, const float* __restrict__ k,
    const float* __restrict__ v,
    __hip_bfloat16* __restrict__ Qin, __hip_bfloat16* __restrict__ Kin,
    __hip_bfloat16* __restrict__ Vin,
    const float* __restrict__ Wq, const float* __restrict__ Wk,
    const float* __restrict__ Wv, const float* __restrict__ Wo,
    __hip_bfloat16* __restrict__ Wqt, __hip_bfloat16* __restrict__ Wkt,
    __hip_bfloat16* __restrict__ Wvt, __hip_bfloat16* __restrict__ Wot)
{
    __shared__ float t[32][33];
    const int b = blockIdx.x;

    if (b < 256) {
        // ---- scatter + gather ----
        int e = b * 256 + threadIdx.x;
        int p = atomicAdd(&cursor[dst[e]], 1);
        src_s[p] = srcarr[e];
        #pragma unroll
        for (int n = 0; n < NB; n++) {
            float4 a2, b2;
            const float* base = epe + (size_t)(n * HEADS) * NE + e;
            a2.x = base[0 * NE]; a2.y = base[1 * NE]; a2.z = base[2 * NE]; a2.w = base[3 * NE];
            b2.x = base[4 * NE]; b2.y = base[5 * NE]; b2.z = base[6 * NE]; b2.w = base[7 * NE];
            float* o = epe_s + ((size_t)n * NE + p) * 8;
            *(float4*)o       = a2;
            *(float4*)(o + 4) = b2;
        }
    } else if (b < 6400) {
        // ---- input conversion ----
        int i = (b - 256) * 256 + threadIdx.x;      // 0 .. 3*N8
        int which = i >> 19;                         // /N8
        int j = i & (N8 - 1);
        const float* x = (which == 0) ? q : (which == 1) ? k : v;
        __hip_bfloat16* y = (which == 0) ? Qin : (which == 1) ? Kin : Vin;
        const float4* xv = (const float4*)x;
        float4 a2 = xv[2 * j], b2 = xv[2 * j + 1];
        union { short8 v8; __hip_bfloat16 h[8]; } u;
        u.h[0] = __float2bfloat16(a2.x); u.h[1] = __float2bfloat16(a2.y);
        u.h[2] = __float2bfloat16(a2.z); u.h[3] = __float2bfloat16(a2.w);
        u.h[4] = __float2bfloat16(b2.x); u.h[5] = __float2bfloat16(b2.y);
        u.h[6] = __float2bfloat16(b2.z); u.h[7] = __float2bfloat16(b2.w);
        *(short8*)(y + (size_t)j * 8) = u.v8;
    } else {
        // ---- weight transpose ----
        int bb = b - 6400;
        const float* W; __hip_bfloat16* Wt; int K, tt;
        if (bb < 384) {
            int m = bb >> 7; tt = bb & 127; K = IN_C;
            W  = (m == 0) ? Wq  : (m == 1) ? Wk  : Wv;
            Wt = (m == 0) ? Wqt : (m == 1) ? Wkt : Wvt;
        } else {
            tt = bb - 384; K = MDL; W = Wo; Wt = Wot;
        }
        const int N = MDL;
        int bx = (tt & 15) * 32;            // n
        int by = (tt >> 4) * 32;            // k
        int tx = threadIdx.x & 31, ty = threadIdx.x >> 5;   // 32 x 8
        #pragma unroll
        for (int i = 0; i < 4; i++)
            t[ty + i * 8][tx] = W[(size_t)(by + ty + i * 8) * N + bx + tx];
        __syncthreads();
        #pragma unroll
        for (int i = 0; i < 4; i++)
            Wt[(size_t)(bx + ty + i * 8) * K + by + tx] =
                __float2bfloat16(t[tx][ty + i * 8]);
    }
}

// ---------------- fused sparse attention v6: two-phase, in-register ----------
// wave = one (n, dst) node; 8-lane group per head; lane holds 8 dims (bf16x8).
// Pass 1 (K only): per 8-edge slot, 8 partial dots/lane + 3-stage transpose-
// reduce butterfly -> edge r's score lands in lane 8*hg+r. Scalar m/z chain.
// Between passes: alpha = exp(s-m)*zinv folded per-lane.
// Pass 2 (V only): pure gather+FMA, alphas via one shfl. No serial chain.
__global__ __launch_bounds__(256) void sparse_attn6(
    const __hip_bfloat16* __restrict__ Qb, const __hip_bfloat16* __restrict__ Kb,
    const __hip_bfloat16* __restrict__ Vb,
    const int* __restrict__ src_s, const float* __restrict__ epe_s,
    const int* __restrict__ offsets, __hip_bfloat16* __restrict__ O)
{
    const int lane = threadIdx.x & 63;
    const int wid  = threadIdx.x >> 6;               // 0..3
    const int bid  = blockIdx.x;                     // 0..4095
    const int xcd  = bid & 7;
    const int n    = xcd >> 1;                       // 2 XCDs per batch n
    const int base = ((bid >> 3) << 1) | (xcd & 1);  // 0..1023
    const int dstn = (base << 2) | wid;
    const int task = n * LL + dstn;
    const int hg   = lane >> 3;                      // head 0..7

    const size_t rowbase = (size_t)task * MDL;
    const int beg = offsets[dstn];
    const int end = offsets[dstn + 1];
    const int deg = end - beg;

    union { short8 v8; __hip_bfloat16 h[8]; } uo;
    if (deg == 0) {
        #pragma unroll
        for (int j = 0; j < 8; j++) uo.h[j] = __float2bfloat16(0.0f);
        *(short8*)(O + rowbase + lane * 8) = uo.v8;
        return;
    }

    bf16x8 q8 = *(const bf16x8*)(Qb + rowbase + lane * 8);
    float qf[8];
    #pragma unroll
    for (int j = 0; j < 8; j++) qf[j] = (float)q8[j];

    const __hip_bfloat16* Kn = Kb + (size_t)n * LL * MDL + lane * 8;
    const __hip_bfloat16* Vn = Vb + (size_t)n * LL * MDL + lane * 8;
    const float* pe_n = epe_s + (size_t)n * NE * 8 + hg;

    float acc[8] = {};

    if (deg <= 64) {
        // whole edge list in registers, one per lane
        const int my_src = src_s[beg + ((lane < deg) ? lane : (deg - 1))];

        float m = -INFINITY, z = 0.0f;
        float s_st[8];

        // ---------- pass 1: scores (K only) ----------
        #pragma unroll
        for (int slot = 0; slot < 8; slot++) {
            const int r0 = slot * 8;
            if (r0 < deg) {
                bf16x8 kk[8];
                #pragma unroll
                for (int j = 0; j < 8; j++) {
                    int s = __shfl(my_src, r0 + j);   // pads clamp to valid row
                    kk[j] = *(const bf16x8*)(Kn + (size_t)s * MDL);
                }
                const int rel_mine = r0 + (lane & 7);
                float pp = (rel_mine < deg)
                         ? pe_n[(size_t)(beg + rel_mine) * 8] : -INFINITY;

                float p[8];
                #pragma unroll
                for (int j = 0; j < 8; j++) {
                    float d = 0.0f;
                    #pragma unroll
                    for (int dd = 0; dd < 8; dd++)
                        d = fmaf(qf[dd], (float)kk[j][dd], d);
                    p[j] = d;
                }
                // transpose-reduce butterfly within 8-lane groups:
                // result: lane 8*hg + r holds full dot of edge r0+r, head hg
                float n0, n1, n2, n3, u0, u1, sraw;
                {
                    float a0 = (lane & 1) ? p[1] : p[0];
                    float b0 = (lane & 1) ? p[0] : p[1];
                    n0 = a0 + __shfl_xor(b0, 1);
                    float a1 = (lane & 1) ? p[3] : p[2];
                    float b1 = (lane & 1) ? p[2] : p[3];
                    n1 = a1 + __shfl_xor(b1, 1);
                    float a2 = (lane & 1) ? p[5] : p[4];
                    float b2 = (lane & 1) ? p[4] : p[5];
                    n2 = a2 + __shfl_xor(b2, 1);
                    float a3 = (lane & 1) ? p[7] : p[6];
                    float b3 = (lane & 1) ? p[6] : p[7];
                    n3 = a3 + __shfl_xor(b3, 1);

                    float c0 = (lane & 2) ? n1 : n0;
                    float d0 = (lane & 2) ? n0 : n1;
                    u0 = c0 + __shfl_xor(d0, 2);
                    float c1 = (lane & 2) ? n3 : n2;
                    float d1 = (lane & 2) ? n2 : n3;
                    u1 = c1 + __shfl_xor(d1, 2);

                    float e0 = (lane & 4) ? u1 : u0;
                    float f0 = (lane & 4) ? u0 : u1;
                    sraw = e0 + __shfl_xor(f0, 4);
                }

                float sc_my = TEMP * (sraw + pp);     // pads -> -inf
                s_st[slot] = sc_my;

                // group max (8 lanes)
                float gm = sc_my;
                gm = fmaxf(gm, __shfl_xor(gm, 1));
                gm = fmaxf(gm, __shfl_xor(gm, 2));
                gm = fmaxf(gm, __shfl_xor(gm, 4));
                float mnew = fmaxf(m, gm);
                float e_my = __expf(sc_my - mnew);    // -inf -> 0
                float gs = e_my;
                gs += __shfl_xor(gs, 1);
                gs += __shfl_xor(gs, 2);
                gs += __shfl_xor(gs, 4);
                z = z * __expf(m - mnew) + gs;        // first slot: exp(-inf)=0
                m = mnew;
            } else {
                s_st[slot] = -INFINITY;
            }
        }

        // ---------- fold softmax into per-lane alphas ----------
        const float zinv = 1.0f / z;
        float a_st[8];
        #pragma unroll
        for (int slot = 0; slot < 8; slot++)
            a_st[slot] = __expf(s_st[slot] - m) * zinv;   // pads -> 0

        // ---------- pass 2: output (V only), no ordering constraints ----------
        #pragma unroll
        for (int slot = 0; slot < 8; slot++) {
            const int r0 = slot * 8;
            if (r0 < deg) {
                bf16x8 vv[8];
                #pragma unroll
                for (int j = 0; j < 8; j++) {
                    int s = __shfl(my_src, r0 + j);
                    vv[j] = *(const bf16x8*)(Vn + (size_t)s * MDL);
                }
                #pragma unroll
                for (int j = 0; j < 8; j++) {
                    float al = __shfl(a_st[slot], (lane & 56) | j);  // lane 8*hg+j
                    #pragma unroll
                    for (int dd = 0; dd < 8; dd++)
                        acc[dd] = fmaf(al, (float)vv[j][dd], acc[dd]);
                }
            }
        }
    } else {
        // ---------- fallback (deg > 64): fused online softmax, 2-deep ----------
        float m = -INFINITY, z = 0.0f;
        bf16x8 ka[4], va[4], kb2[4], vb2[4];
        float  pa[4], pb2[4];

        #define LOADB(i, kk, vv, pp)                                        \
            _Pragma("unroll")                                               \
            for (int j = 0; j < 4; j++) {                                   \
                int idx = (i) + j;                                          \
                int ok  = idx < end;                                        \
                int s   = ok ? src_s[idx] : src_s[beg];                     \
                size_t rk = (size_t)s * MDL;                                \
                kk[j] = *(const bf16x8*)(Kn + rk);                          \
                vv[j] = *(const bf16x8*)(Vn + rk);                          \
                pp[j] = ok ? pe_n[(size_t)idx * 8] : -INFINITY;             \
            }

        #define COMPUTE(kk, vv, pp)                                         \
        {                                                                   \
            float sc4[4];                                                   \
            _Pragma("unroll")                                               \
            for (int j = 0; j < 4; j++) {                                   \
                float d = 0.0f;                                             \
                _Pragma("unroll")                                           \
                for (int dd = 0; dd < 8; dd++) d += qf[dd] * (float)kk[j][dd]; \
                d += __shfl_xor(d, 1);                                      \
                d += __shfl_xor(d, 2);                                      \
                d += __shfl_xor(d, 4);                                      \
                sc4[j] = TEMP * (d + pp[j]);                                \
            }                                                               \
            float mb   = fmaxf(fmaxf(sc4[0], sc4[1]), fmaxf(sc4[2], sc4[3])); \
            float mnew = fmaxf(m, mb);                                      \
            float sc   = __expf(m - mnew);                                  \
            float pe0 = __expf(sc4[0] - mnew);                              \
            float pe1 = __expf(sc4[1] - mnew);                              \
            float pe2 = __expf(sc4[2] - mnew);                              \
            float pe3 = __expf(sc4[3] - mnew);                              \
            z = z * sc + (pe0 + pe1 + pe2 + pe3);                           \
            _Pragma("unroll")                                               \
            for (int dd = 0; dd < 8; dd++) {                                \
                float tt = acc[dd] * sc;                                    \
                tt = fmaf(pe0, (float)vv[0][dd], tt);                       \
                tt = fmaf(pe1, (float)vv[1][dd], tt);                       \
                tt = fmaf(pe2, (float)vv[2][dd], tt);                       \
                tt = fmaf(pe3, (float)vv[3][dd], tt);                       \
                acc[dd] = tt;                                               \
            }                                                               \
            m = mnew;                                                       \
        }

        LOADB(beg, ka, va, pa)
        for (int i = beg; i < end; i += 4) {
            if (i + 4 < end) { LOADB(i + 4, kb2, vb2, pb2) }
            COMPUTE(ka, va, pa)
            #pragma unroll
            for (int j = 0; j < 4; j++) { ka[j] = kb2[j]; va[j] = vb2[j]; pa[j] = pb2[j]; }
        }
        float inv = 1.0f / z;
        #pragma unroll
        for (int dd = 0; dd < 8; dd++) acc[dd] *= inv;
        #undef LOADB
        #undef COMPUTE
    }

    #pragma unroll
    for (int j = 0; j < 8; j++) uo.h[j] = __float2bfloat16(acc[j]);
    *(short8*)(O + rowbase + lane * 8) = uo.v8;
}

// ---------------- launch ------------------------------------------------------
extern "C" void kernel_launch(void* const* d_in, const int* in_sizes, int n_in,
                              void* d_out, int out_size, void* d_ws, size_t ws_size,
                              hipStream_t stream)
{
    const float* queries = (const float*)d_in[0];
    const float* keys    = (const float*)d_in[1];
    const float* values  = (const float*)d_in[2];
    const int*   adj     = (const int*)d_in[3];
    const float* epe     = (const float*)d_in[4];
    const float* Wq = (const float*)d_in[5];
    const float* bq = (const float*)d_in[6];
    const float* Wk = (const float*)d_in[7];
    const float* bk = (const float*)d_in[8];
    const float* Wv = (const float*)d_in[9];
    const float* bv = (const float*)d_in[10];
    const float* Wo = (const float*)d_in[11];
    const float* bo = (const float*)d_in[12];
    float* out = (float*)d_out;

    const int* dst = adj;
    const int* src = adj + NE;

    const int    M   = NB * LL;                     // 16384
    const size_t NLM = (size_t)M * MDL;             // 8,388,608
    const size_t NLK = (size_t)M * IN_C;            // 4,194,304

    char* w = (char*)d_ws;
    __hip_bfloat16* Qb  = (__hip_bfloat16*)w; w += NLM * 2;      // 16.78 MB
    __hip_bfloat16* Kb  = (__hip_bfloat16*)w; w += NLM * 2;
    __hip_bfloat16* Vb  = (__hip_bfloat16*)w; w += NLM * 2;
    char* inbf_base = w;
    __hip_bfloat16* Qin = (__hip_bfloat16*)w; w += NLK * 2;      // 8.39 MB
    __hip_bfloat16* Kin = (__hip_bfloat16*)w; w += NLK * 2;
    __hip_bfloat16* Vin = (__hip_bfloat16*)w; w += NLK * 2;
    __hip_bfloat16* Ob  = (__hip_bfloat16*)inbf_base;            // aliases Qin/Kin
    __hip_bfloat16* Wqt = (__hip_bfloat16*)w; w += (size_t)MDL * IN_C * 2;
    __hip_bfloat16* Wkt = (__hip_bfloat16*)w; w += (size_t)MDL * IN_C * 2;
    __hip_bfloat16* Wvt = (__hip_bfloat16*)w; w += (size_t)MDL * IN_C * 2;
    __hip_bfloat16* Wot = (__hip_bfloat16*)w; w += (size_t)MDL * MDL * 2;
    int* counts  = (int*)w; w += 4096 * sizeof(int);
    int* offsets = (int*)w; w += 4100 * sizeof(int);
    int* cursor  = (int*)w; w += 4096 * sizeof(int);
    int*   src_s = (int*)w; w += NE * sizeof(int);
    float* epe_s = (float*)w; w += (size_t)NB * NE * 8 * sizeof(float);  // 8.39 MB

    // CSR build
    hipMemsetAsync(counts, 0, 4096 * sizeof(int), stream);
    count_edges<<<NE / 256, 256, 0, stream>>>(dst, counts, NE);
    scan_offsets<<<1, 1024, 0, stream>>>(counts, offsets, cursor);

    // fused prep: scatter+gather | input cvt | weight transposes
    prep<<<7040, 256, 0, stream>>>(dst, src, epe, cursor, src_s, epe_s,
                                   queries, keys, values, Qin, Kin, Vin,
                                   Wq, Wk, Wv, Wo, Wqt, Wkt, Wvt, Wot);

    // QKV projections (one launch, z=3)
    dim3 g3(MDL / 128, M / 128, 3);
    gemm_qkv<<<g3, 256, 0, stream>>>(Qin, Kin, Vin, Wqt, Wkt, Wvt, bq, bk, bv,
                                     Qb, Kb, Vb, M, MDL, IN_C);

    // fused sparse attention (16384 node-waves, 4 waves/block, XCD-partitioned)
    sparse_attn6<<<(NB * LL) / 4, 256, 0, stream>>>(Qb, Kb, Vb, src_s, epe_s, offsets, Ob);

    // output projection (fp32 out + bias)
    dim3 g(MDL / 128, M / 128);
    gemm_out<<<g, 256, 0, stream>>>(Ob, Wot, bo, out, M, MDL, MDL);
}

// Round 7
// 138.320 us; speedup vs baseline: 1.1353x; 1.0136x over previous
//
#include <hip/hip_runtime.h>
#include <hip/hip_bf16.h>
#include <math.h>
#include <stdint.h>

// Problem constants (SparseAttention_46969762349725)
#define HEADS 8
#define IN_C  256
#define MDL   512
#define NB    4        // batch
#define LL    4096     // nodes
#define NE    65536    // edges
#define EDIM  64       // per-head dim = MDL/HEADS
#define TEMP  0.125f   // 1/sqrt(64)

typedef __bf16 bf16x8 __attribute__((ext_vector_type(8)));
typedef float  f32x4  __attribute__((ext_vector_type(4)));
typedef short  short8 __attribute__((ext_vector_type(8)));

__device__ __forceinline__ void glds16(const void* g, void* l) {
    __builtin_amdgcn_global_load_lds(
        (const __attribute__((address_space(1))) void*)g,
        (__attribute__((address_space(3))) void*)l, 16, 0, 0);
}

__device__ __forceinline__ short8 cvt8(float4 a, float4 b) {
    union { short8 v; __hip_bfloat16 h[8]; } u;
    u.h[0] = __float2bfloat16(a.x); u.h[1] = __float2bfloat16(a.y);
    u.h[2] = __float2bfloat16(a.z); u.h[3] = __float2bfloat16(a.w);
    u.h[4] = __float2bfloat16(b.x); u.h[5] = __float2bfloat16(b.y);
    u.h[6] = __float2bfloat16(b.z); u.h[7] = __float2bfloat16(b.w);
    return u.v;
}

// ---------------- QKV GEMM: A fp32 (fused convert), Bt bf16, C bf16 ----------
// 128x128 tile, BK=32, 4 waves (2x2), 16x16x32 bf16 MFMA.
// A-staging: reg-stage fp32 -> cvt -> ds_write_b128 (same XOR swizzle).
__global__ __launch_bounds__(256) void gemm_qkv(
    const float* __restrict__ A0, const float* __restrict__ A1,
    const float* __restrict__ A2,
    const __hip_bfloat16* __restrict__ B0, const __hip_bfloat16* __restrict__ B1,
    const __hip_bfloat16* __restrict__ B2,
    const float* __restrict__ b0, const float* __restrict__ b1,
    const float* __restrict__ b2,
    __hip_bfloat16* __restrict__ C0, __hip_bfloat16* __restrict__ C1,
    __hip_bfloat16* __restrict__ C2, int M, int N, int K)
{
    __shared__ __align__(16) __hip_bfloat16 As[128 * 32];
    __shared__ __align__(16) __hip_bfloat16 Bs[128 * 32];

    const int z = blockIdx.z;
    const float* A           = (z == 0) ? A0 : (z == 1) ? A1 : A2;
    const __hip_bfloat16* Bt = (z == 0) ? B0 : (z == 1) ? B1 : B2;
    const float* bias        = (z == 0) ? b0 : (z == 1) ? b1 : b2;
    __hip_bfloat16* C        = (z == 0) ? C0 : (z == 1) ? C1 : C2;

    const int tid  = threadIdx.x;
    const int lane = tid & 63;
    const int w    = tid >> 6;
    const int wr   = w >> 1, wc = w & 1;
    const int bm   = blockIdx.y * 128, bn = blockIdx.x * 128;

    // A staging (fp32, reg-staged): 2 iters; row r, chunk position cc, data chunk c
    const int r0  = tid >> 2;
    const int cc0 = tid & 3;
    const int ca0 = cc0 ^ (r0 & 3);
    const int r1  = r0 + 64;
    const int ca1 = cc0 ^ (r1 & 3);
    const float* gA0 = A + (size_t)(bm + r0) * K + ca0 * 8;
    const float* gA1 = A + (size_t)(bm + r1) * K + ca1 * 8;
    __hip_bfloat16* lA0w = As + r0 * 32 + cc0 * 8;
    __hip_bfloat16* lA1w = As + r1 * 32 + cc0 * 8;

    // B staging via global_load_lds (unchanged pattern)
    const int cb0 = (tid & 3) ^ (r0 & 3);
    const int cb1 = (tid & 3) ^ (r1 & 3);
    const __hip_bfloat16* gB0 = Bt + (size_t)(bn + r0) * K + cb0 * 8;
    const __hip_bfloat16* gB1 = Bt + (size_t)(bn + r1) * K + cb1 * 8;
    __hip_bfloat16* lB0 = Bs + (size_t)(w * 64) * 8;
    __hip_bfloat16* lB1 = Bs + (size_t)(256 + w * 64) * 8;

    int fa[4], fb[4];
    #pragma unroll
    for (int i = 0; i < 4; i++) {
        int rA = wr * 64 + i * 16 + (lane & 15);
        fa[i] = rA * 32 + (((lane >> 4) ^ (rA & 3)) * 8);
        int rB = wc * 64 + i * 16 + (lane & 15);
        fb[i] = rB * 32 + (((lane >> 4) ^ (rB & 3)) * 8);
    }

    f32x4 acc[4][4] = {};

    for (int k0 = 0; k0 < K; k0 += 32) {
        glds16(gB0 + k0, lB0);
        glds16(gB1 + k0, lB1);
        float4 a0  = *(const float4*)(gA0 + k0);
        float4 a0b = *(const float4*)(gA0 + k0 + 4);
        float4 a1  = *(const float4*)(gA1 + k0);
        float4 a1b = *(const float4*)(gA1 + k0 + 4);
        *(short8*)lA0w = cvt8(a0, a0b);
        *(short8*)lA1w = cvt8(a1, a1b);
        __syncthreads();

        bf16x8 av[4], bv[4];
        #pragma unroll
        for (int i = 0; i < 4; i++) av[i] = *(const bf16x8*)(As + fa[i]);
        #pragma unroll
        for (int i = 0; i < 4; i++) bv[i] = *(const bf16x8*)(Bs + fb[i]);
        #pragma unroll
        for (int mi = 0; mi < 4; mi++)
            #pragma unroll
            for (int ni = 0; ni < 4; ni++)
                acc[mi][ni] = __builtin_amdgcn_mfma_f32_16x16x32_bf16(
                    av[mi], bv[ni], acc[mi][ni], 0, 0, 0);
        __syncthreads();
    }

    #pragma unroll
    for (int mi = 0; mi < 4; mi++) {
        int row = bm + wr * 64 + mi * 16 + (lane >> 4) * 4;
        #pragma unroll
        for (int ni = 0; ni < 4; ni++) {
            int col = bn + wc * 64 + ni * 16 + (lane & 15);
            float bb = bias[col];
            #pragma unroll
            for (int j = 0; j < 4; j++)
                C[(size_t)(row + j) * N + col] = __float2bfloat16(acc[mi][ni][j] + bb);
        }
    }
}

// ---------------- output GEMM: bf16 x bf16 -> fp32, BK=64 --------------------
__global__ __launch_bounds__(256) void gemm_out(
    const __hip_bfloat16* __restrict__ A, const __hip_bfloat16* __restrict__ Bt,
    const float* __restrict__ bias, float* __restrict__ C, int M, int N, int K)
{
    __shared__ __align__(16) __hip_bfloat16 As[128 * 64];
    __shared__ __align__(16) __hip_bfloat16 Bs[128 * 64];

    const int tid  = threadIdx.x;
    const int lane = tid & 63;
    const int w    = tid >> 6;
    const int wr   = w >> 1, wc = w & 1;
    const int bm   = blockIdx.y * 128, bn = blockIdx.x * 128;

    // staging: 1024 chunks (128 rows x 8 chunks) per matrix, 4 per thread
    const __hip_bfloat16* gA[4];
    const __hip_bfloat16* gB[4];
    __hip_bfloat16* lA[4];
    __hip_bfloat16* lB[4];
    #pragma unroll
    for (int it = 0; it < 4; it++) {
        int idx = it * 256 + tid;
        int r = idx >> 3;
        int c = (idx & 7) ^ (r & 7);
        gA[it] = A  + (size_t)(bm + r) * K + c * 8;
        gB[it] = Bt + (size_t)(bn + r) * K + c * 8;
        lA[it] = As + (size_t)(it * 256 + w * 64) * 8;
        lB[it] = Bs + (size_t)(it * 256 + w * 64) * 8;
    }

    int fa[2][4], fb[2][4];
    #pragma unroll
    for (int kk = 0; kk < 2; kk++)
        #pragma unroll
        for (int i = 0; i < 4; i++) {
            int rA = wr * 64 + i * 16 + (lane & 15);
            int gc = kk * 4 + (lane >> 4);
            fa[kk][i] = rA * 64 + (gc ^ (rA & 7)) * 8;
            int rB = wc * 64 + i * 16 + (lane & 15);
            fb[kk][i] = rB * 64 + (gc ^ (rB & 7)) * 8;
        }

    f32x4 acc[4][4] = {};

    for (int k0 = 0; k0 < K; k0 += 64) {
        #pragma unroll
        for (int it = 0; it < 4; it++) {
            glds16(gA[it] + k0, lA[it]);
            glds16(gB[it] + k0, lB[it]);
        }
        __syncthreads();

        #pragma unroll
        for (int kk = 0; kk < 2; kk++) {
            bf16x8 av[4], bv[4];
            #pragma unroll
            for (int i = 0; i < 4; i++) av[i] = *(const bf16x8*)(As + fa[kk][i]);
            #pragma unroll
            for (int i = 0; i < 4; i++) bv[i] = *(const bf16x8*)(Bs + fb[kk][i]);
            #pragma unroll
            for (int mi = 0; mi < 4; mi++)
                #pragma unroll
                for (int ni = 0; ni < 4; ni++)
                    acc[mi][ni] = __builtin_amdgcn_mfma_f32_16x16x32_bf16(
                        av[mi], bv[ni], acc[mi][ni], 0, 0, 0);
        }
        __syncthreads();
    }

    #pragma unroll
    for (int mi = 0; mi < 4; mi++) {
        int row = bm + wr * 64 + mi * 16 + (lane >> 4) * 4;
        #pragma unroll
        for (int ni = 0; ni < 4; ni++) {
            int col = bn + wc * 64 + ni * 16 + (lane & 15);
            float bb = bias[col];
            #pragma unroll
            for (int j = 0; j < 4; j++)
                C[(size_t)(row + j) * N + col] = acc[mi][ni][j] + bb;
        }
    }
}

// ---------------- CSR build over dst = adj[0] --------------------------------
__global__ void count_edges(const int* __restrict__ dst, int* __restrict__ counts, int ne) {
    int e = blockIdx.x * blockDim.x + threadIdx.x;
    if (e < ne) atomicAdd(&counts[dst[e]], 1);
}

// scan + cursor + degree-descending bucket reorder (heaviest nodes first)
__global__ __launch_bounds__(1024) void scan_offsets(
    const int* __restrict__ counts, int* __restrict__ offsets,
    int* __restrict__ cursor, int* __restrict__ reorder)
{
    __shared__ int wsum[16];
    __shared__ int bcnt[9], boff[9];
    const int tid  = threadIdx.x;
    const int lane = tid & 63;
    const int wid  = tid >> 6;

    if (tid < 9) bcnt[tid] = 0;

    int c[4];
    int base = tid * 4;
    int s = 0;
    #pragma unroll
    for (int i = 0; i < 4; i++) { c[i] = counts[base + i]; s += c[i]; }

    int v = s;
    #pragma unroll
    for (int off = 1; off < 64; off <<= 1) {
        int t = __shfl_up(v, off);
        if (lane >= off) v += t;
    }
    if (lane == 63) wsum[wid] = v;
    __syncthreads();
    if (wid == 0) {
        int wv = (lane < 16) ? wsum[lane] : 0;
        #pragma unroll
        for (int off = 1; off < 16; off <<= 1) {
            int t = __shfl_up(wv, off);
            if (lane >= off) wv += t;
        }
        if (lane < 16) wsum[lane] = wv;
    }
    __syncthreads();

    int prefix = (wid > 0 ? wsum[wid - 1] : 0) + (v - s);
    int run = prefix;
    int mybk[4];
    #pragma unroll
    for (int i = 0; i < 4; i++) {
        offsets[base + i] = run;
        cursor[base + i]  = run;
        run += c[i];
        int sc = (c[i] + 7) >> 3; if (sc > 8) sc = 8;
        mybk[i] = 8 - sc;                       // 0 = heaviest bucket
        atomicAdd(&bcnt[mybk[i]], 1);
    }
    if (tid == 1023) offsets[4096] = run;
    __syncthreads();
    if (tid == 0) {
        int acc0 = 0;
        #pragma unroll
        for (int b = 0; b < 9; b++) { boff[b] = acc0; acc0 += bcnt[b]; }
    }
    __syncthreads();
    #pragma unroll
    for (int i = 0; i < 4; i++) {
        int pos = atomicAdd(&boff[mybk[i]], 1);
        reorder[pos] = base + i;
    }
}

// ---------------- fused prep: scatter(+gather) | weight transposes -----------
__global__ __launch_bounds__(256) void prep(
    const int* __restrict__ dst, const int* __restrict__ srcarr,
    const float* __restrict__ epe, int* __restrict__ cursor,
    int* __restrict__ src_s, float* __restrict__ epe_s,
    const float* __restrict__ Wq, const float* __restrict__ Wk,
    const float* __restrict__ Wv, const float* __restrict__ Wo,
    __hip_bfloat16* __restrict__ Wqt, __hip_bfloat16* __restrict__ Wkt,
    __hip_bfloat16* __restrict__ Wvt, __hip_bfloat16* __restrict__ Wot)
{
    __shared__ float t[32][33];
    const int b = blockIdx.x;

    if (b < 256) {
        // ---- scatter + gather ----
        int e = b * 256 + threadIdx.x;
        int p = atomicAdd(&cursor[dst[e]], 1);
        src_s[p] = srcarr[e];
        #pragma unroll
        for (int n = 0; n < NB; n++) {
            float4 a2, b2;
            const float* base = epe + (size_t)(n * HEADS) * NE + e;
            a2.x = base[0 * NE]; a2.y = base[1 * NE]; a2.z = base[2 * NE]; a2.w = base[3 * NE];
            b2.x = base[4 * NE]; b2.y = base[5 * NE]; b2.z = base[6 * NE]; b2.w = base[7 * NE];
            float* o = epe_s + ((size_t)n * NE + p) * 8;
            *(float4*)o       = a2;
            *(float4*)(o + 4) = b2;
        }
    } else {
        // ---- weight transpose: W[K][N] fp32 -> Wt[N][K] bf16 ----
        int bb = b - 256;
        const float* W; __hip_bfloat16* Wt; int K, tt;
        if (bb < 384) {
            int m = bb >> 7; tt = bb & 127; K = IN_C;
            W  = (m == 0) ? Wq  : (m == 1) ? Wk  : Wv;
            Wt = (m == 0) ? Wqt : (m == 1) ? Wkt : Wvt;
        } else {
            tt = bb - 384; K = MDL; W = Wo; Wt = Wot;
        }
        const int N = MDL;
        int bx = (tt & 15) * 32;            // n
        int by = (tt >> 4) * 32;            // k
        int tx = threadIdx.x & 31, ty = threadIdx.x >> 5;   // 32 x 8
        #pragma unroll
        for (int i = 0; i < 4; i++)
            t[ty + i * 8][tx] = W[(size_t)(by + ty + i * 8) * N + bx + tx];
        __syncthreads();
        #pragma unroll
        for (int i = 0; i < 4; i++)
            Wt[(size_t)(bx + ty + i * 8) * K + by + tx] =
                __float2bfloat16(t[tx][ty + i * 8]);
    }
}

// ---------------- fused sparse attention v7: two-phase + reorder -------------
__global__ __launch_bounds__(256) void sparse_attn7(
    const __hip_bfloat16* __restrict__ Qb, const __hip_bfloat16* __restrict__ Kb,
    const __hip_bfloat16* __restrict__ Vb,
    const int* __restrict__ src_s, const float* __restrict__ epe_s,
    const int* __restrict__ offsets, const int* __restrict__ reorder,
    __hip_bfloat16* __restrict__ O)
{
    const int lane = threadIdx.x & 63;
    const int wid  = threadIdx.x >> 6;               // 0..3
    const int bid  = blockIdx.x;                     // 0..4095
    const int xcd  = bid & 7;
    const int n    = xcd >> 1;                       // 2 XCDs per batch n
    const int base = ((bid >> 3) << 1) | (xcd & 1);  // 0..1023
    const int dstn = reorder[(base << 2) | wid];     // degree-descending order
    const int task = n * LL + dstn;
    const int hg   = lane >> 3;                      // head 0..7

    const size_t rowbase = (size_t)task * MDL;
    const int beg = offsets[dstn];
    const int end = offsets[dstn + 1];
    const int deg = end - beg;

    union { short8 v8; __hip_bfloat16 h[8]; } uo;
    if (deg == 0) {
        #pragma unroll
        for (int j = 0; j < 8; j++) uo.h[j] = __float2bfloat16(0.0f);
        *(short8*)(O + rowbase + lane * 8) = uo.v8;
        return;
    }

    bf16x8 q8 = *(const bf16x8*)(Qb + rowbase + lane * 8);
    float qf[8];
    #pragma unroll
    for (int j = 0; j < 8; j++) qf[j] = (float)q8[j];

    const __hip_bfloat16* Kn = Kb + (size_t)n * LL * MDL + lane * 8;
    const __hip_bfloat16* Vn = Vb + (size_t)n * LL * MDL + lane * 8;
    const float* pe_n = epe_s + (size_t)n * NE * 8 + hg;

    float acc[8] = {};

    if (deg <= 64) {
        const int my_src = src_s[beg + ((lane < deg) ? lane : (deg - 1))];

        float m = -INFINITY, z = 0.0f;
        float s_st[8];

        // ---------- pass 1: scores (K only) ----------
        #pragma unroll
        for (int slot = 0; slot < 8; slot++) {
            const int r0 = slot * 8;
            if (r0 < deg) {
                bf16x8 kk[8];
                #pragma unroll
                for (int j = 0; j < 8; j++) {
                    int s = __shfl(my_src, r0 + j);   // pads clamp to valid row
                    kk[j] = *(const bf16x8*)(Kn + (size_t)s * MDL);
                }
                const int rel_mine = r0 + (lane & 7);
                float pp = (rel_mine < deg)
                         ? pe_n[(size_t)(beg + rel_mine) * 8] : -INFINITY;

                float p[8];
                #pragma unroll
                for (int j = 0; j < 8; j++) {
                    float d = 0.0f;
                    #pragma unroll
                    for (int dd = 0; dd < 8; dd++)
                        d = fmaf(qf[dd], (float)kk[j][dd], d);
                    p[j] = d;
                }
                // transpose-reduce butterfly within 8-lane groups
                float n0, n1, n2, n3, u0, u1, sraw;
                {
                    float a0 = (lane & 1) ? p[1] : p[0];
                    float b0 = (lane & 1) ? p[0] : p[1];
                    n0 = a0 + __shfl_xor(b0, 1);
                    float a1 = (lane & 1) ? p[3] : p[2];
                    float b1 = (lane & 1) ? p[2] : p[3];
                    n1 = a1 + __shfl_xor(b1, 1);
                    float a2 = (lane & 1) ? p[5] : p[4];
                    float b2 = (lane & 1) ? p[4] : p[5];
                    n2 = a2 + __shfl_xor(b2, 1);
                    float a3 = (lane & 1) ? p[7] : p[6];
                    float b3 = (lane & 1) ? p[6] : p[7];
                    n3 = a3 + __shfl_xor(b3, 1);

                    float c0 = (lane & 2) ? n1 : n0;
                    float d0 = (lane & 2) ? n0 : n1;
                    u0 = c0 + __shfl_xor(d0, 2);
                    float c1 = (lane & 2) ? n3 : n2;
                    float d1 = (lane & 2) ? n2 : n3;
                    u1 = c1 + __shfl_xor(d1, 2);

                    float e0 = (lane & 4) ? u1 : u0;
                    float f0 = (lane & 4) ? u0 : u1;
                    sraw = e0 + __shfl_xor(f0, 4);
                }

                float sc_my = TEMP * (sraw + pp);     // pads -> -inf
                s_st[slot] = sc_my;

                float gm = sc_my;
                gm = fmaxf(gm, __shfl_xor(gm, 1));
                gm = fmaxf(gm, __shfl_xor(gm, 2));
                gm = fmaxf(gm, __shfl_xor(gm, 4));
                float mnew = fmaxf(m, gm);
                float e_my = __expf(sc_my - mnew);
                float gs = e_my;
                gs += __shfl_xor(gs, 1);
                gs += __shfl_xor(gs, 2);
                gs += __shfl_xor(gs, 4);
                z = z * __expf(m - mnew) + gs;
                m = mnew;
            } else {
                s_st[slot] = -INFINITY;
            }
        }

        const float zinv = 1.0f / z;
        float a_st[8];
        #pragma unroll
        for (int slot = 0; slot < 8; slot++)
            a_st[slot] = __expf(s_st[slot] - m) * zinv;   // pads -> 0

        // ---------- pass 2: output (V only) ----------
        #pragma unroll
        for (int slot = 0; slot < 8; slot++) {
            const int r0 = slot * 8;
            if (r0 < deg) {
                bf16x8 vv[8];
                #pragma unroll
                for (int j = 0; j < 8; j++) {
                    int s = __shfl(my_src, r0 + j);
                    vv[j] = *(const bf16x8*)(Vn + (size_t)s * MDL);
                }
                #pragma unroll
                for (int j = 0; j < 8; j++) {
                    float al = __shfl(a_st[slot], (lane & 56) | j);
                    #pragma unroll
                    for (int dd = 0; dd < 8; dd++)
                        acc[dd] = fmaf(al, (float)vv[j][dd], acc[dd]);
                }
            }
        }
    } else {
        // ---------- fallback (deg > 64): fused online softmax, 2-deep ----------
        float m = -INFINITY, z = 0.0f;
        bf16x8 ka[4], va[4], kb2[4], vb2[4];
        float  pa[4], pb2[4];

        #define LOADB(i, kk, vv, pp)                                        \
            _Pragma("unroll")                                               \
            for (int j = 0; j < 4; j++) {                                   \
                int idx = (i) + j;                                          \
                int ok  = idx < end;                                        \
                int s   = ok ? src_s[idx] : src_s[beg];                     \
                size_t rk = (size_t)s * MDL;                                \
                kk[j] = *(const bf16x8*)(Kn + rk);                          \
                vv[j] = *(const bf16x8*)(Vn + rk);                          \
                pp[j] = ok ? pe_n[(size_t)idx * 8] : -INFINITY;             \
            }

        #define COMPUTE(kk, vv, pp)                                         \
        {                                                                   \
            float sc4[4];                                                   \
            _Pragma("unroll")                                               \
            for (int j = 0; j < 4; j++) {                                   \
                float d = 0.0f;                                             \
                _Pragma("unroll")                                           \
                for (int dd = 0; dd < 8; dd++) d += qf[dd] * (float)kk[j][dd]; \
                d += __shfl_xor(d, 1);                                      \
                d += __shfl_xor(d, 2);                                      \
                d += __shfl_xor(d, 4);                                      \
                sc4[j] = TEMP * (d + pp[j]);                                \
            }                                                               \
            float mb   = fmaxf(fmaxf(sc4[0], sc4[1]), fmaxf(sc4[2], sc4[3])); \
            float mnew = fmaxf(m, mb);                                      \
            float sc   = __expf(m - mnew);                                  \
            float pe0 = __expf(sc4[0] - mnew);                              \
            float pe1 = __expf(sc4[1] - mnew);                              \
            float pe2 = __expf(sc4[2] - mnew);                              \
            float pe3 = __expf(sc4[3] - mnew);                              \
            z = z * sc + (pe0 + pe1 + pe2 + pe3);                           \
            _Pragma("unroll")                                               \
            for (int dd = 0; dd < 8; dd++) {                                \
                float tt = acc[dd] * sc;                                    \
                tt = fmaf(pe0, (float)vv[0][dd], tt);                       \
                tt = fmaf(pe1, (float)vv[1][dd], tt);                       \
                tt = fmaf(pe2, (float)vv[2][dd], tt);                       \
                tt = fmaf(pe3, (float)vv[3][dd], tt);                       \
                acc[dd] = tt;                                               \
            }                                                               \
            m = mnew;                                                       \
        }

        LOADB(beg, ka, va, pa)
        for (int i = beg; i < end; i += 4) {
            if (i + 4 < end) { LOADB(i + 4, kb2, vb2, pb2) }
            COMPUTE(ka, va, pa)
            #pragma unroll
            for (int j = 0; j < 4; j++) { ka[j] = kb2[j]; va[j] = vb2[j]; pa[j] = pb2[j]; }
        }
        float inv = 1.0f / z;
        #pragma unroll
        for (int dd = 0; dd < 8; dd++) acc[dd] *= inv;
        #undef LOADB
        #undef COMPUTE
    }

    #pragma unroll
    for (int j = 0; j < 8; j++) uo.h[j] = __float2bfloat16(acc[j]);
    *(short8*)(O + rowbase + lane * 8) = uo.v8;
}

// ---------------- launch ------------------------------------------------------
extern "C" void kernel_launch(void* const* d_in, const int* in_sizes, int n_in,
                              void* d_out, int out_size, void* d_ws, size_t ws_size,
                              hipStream_t stream)
{
    const float* queries = (const float*)d_in[0];
    const float* keys    = (const float*)d_in[1];
    const float* values  = (const float*)d_in[2];
    const int*   adj     = (const int*)d_in[3];
    const float* epe     = (const float*)d_in[4];
    const float* Wq = (const float*)d_in[5];
    const float* bq = (const float*)d_in[6];
    const float* Wk = (const float*)d_in[7];
    const float* bk = (const float*)d_in[8];
    const float* Wv = (const float*)d_in[9];
    const float* bv = (const float*)d_in[10];
    const float* Wo = (const float*)d_in[11];
    const float* bo = (const float*)d_in[12];
    float* out = (float*)d_out;

    const int* dst = adj;
    const int* src = adj + NE;

    const int    M   = NB * LL;                     // 16384
    const size_t NLM = (size_t)M * MDL;             // 8,388,608

    char* w = (char*)d_ws;
    __hip_bfloat16* Qb  = (__hip_bfloat16*)w; w += NLM * 2;      // 16.78 MB
    __hip_bfloat16* Kb  = (__hip_bfloat16*)w; w += NLM * 2;
    __hip_bfloat16* Vb  = (__hip_bfloat16*)w; w += NLM * 2;
    __hip_bfloat16* Ob  = (__hip_bfloat16*)w; w += NLM * 2;
    __hip_bfloat16* Wqt = (__hip_bfloat16*)w; w += (size_t)MDL * IN_C * 2;
    __hip_bfloat16* Wkt = (__hip_bfloat16*)w; w += (size_t)MDL * IN_C * 2;
    __hip_bfloat16* Wvt = (__hip_bfloat16*)w; w += (size_t)MDL * IN_C * 2;
    __hip_bfloat16* Wot = (__hip_bfloat16*)w; w += (size_t)MDL * MDL * 2;
    int* counts  = (int*)w; w += 4096 * sizeof(int);
    int* offsets = (int*)w; w += 4100 * sizeof(int);
    int* cursor  = (int*)w; w += 4096 * sizeof(int);
    int* reorder = (int*)w; w += 4096 * sizeof(int);
    int*   src_s = (int*)w; w += NE * sizeof(int);
    float* epe_s = (float*)w; w += (size_t)NB * NE * 8 * sizeof(float);  // 8.39 MB

    // CSR build
    hipMemsetAsync(counts, 0, 4096 * sizeof(int), stream);
    count_edges<<<NE / 256, 256, 0, stream>>>(dst, counts, NE);
    scan_offsets<<<1, 1024, 0, stream>>>(counts, offsets, cursor, reorder);

    // fused prep: scatter+gather | weight transposes
    prep<<<896, 256, 0, stream>>>(dst, src, epe, cursor, src_s, epe_s,
                                  Wq, Wk, Wv, Wo, Wqt, Wkt, Wvt, Wot);

    // QKV projections (one launch, z=3, fused fp32->bf16 A-staging)
    dim3 g3(MDL / 128, M / 128, 3);
    gemm_qkv<<<g3, 256, 0, stream>>>(queries, keys, values, Wqt, Wkt, Wvt,
                                     bq, bk, bv, Qb, Kb, Vb, M, MDL, IN_C);

    // fused sparse attention (16384 node-waves, 4 waves/block, XCD + reorder)
    sparse_attn7<<<(NB * LL) / 4, 256, 0, stream>>>(Qb, Kb, Vb, src_s, epe_s,
                                                    offsets, reorder, Ob);

    // output projection (fp32 out + bias, BK=64)
    dim3 g(MDL / 128, M / 128);
    gemm_out<<<g, 256, 0, stream>>>(Ob, Wot, bo, out, M, MDL, MDL);
}

// Round 8
// 132.029 us; speedup vs baseline: 1.1894x; 1.0476x over previous
//
#include <hip/hip_runtime.h>
#include <hip/hip_bf16.h>
#include <math.h>
#include <stdint.h>

// Problem constants (SparseAttention_46969762349725)
#define HEADS 8
#define IN_C  256
#define MDL   512
#define NB    4        // batch
#define LL    4096     // nodes
#define NE    65536    // edges
#define EDIM  64       // per-head dim = MDL/HEADS
#define TEMP  0.125f   // 1/sqrt(64)

typedef __bf16 bf16x8 __attribute__((ext_vector_type(8)));
typedef float  f32x4  __attribute__((ext_vector_type(4)));
typedef short  short8 __attribute__((ext_vector_type(8)));

__device__ __forceinline__ void glds16(const void* g, void* l) {
    __builtin_amdgcn_global_load_lds(
        (const __attribute__((address_space(1))) void*)g,
        (__attribute__((address_space(3))) void*)l, 16, 0, 0);
}

__device__ __forceinline__ short8 cvt8(float4 a, float4 b) {
    union { short8 v; __hip_bfloat16 h[8]; } u;
    u.h[0] = __float2bfloat16(a.x); u.h[1] = __float2bfloat16(a.y);
    u.h[2] = __float2bfloat16(a.z); u.h[3] = __float2bfloat16(a.w);
    u.h[4] = __float2bfloat16(b.x); u.h[5] = __float2bfloat16(b.y);
    u.h[6] = __float2bfloat16(b.z); u.h[7] = __float2bfloat16(b.w);
    return u.v;
}

// ---------------- QKV GEMM: A fp32 (fused convert), Bt bf16, C bf16, BK=64 ---
// 128x128 tile, 4 waves (2x2), 16x16x32 bf16 MFMA, 4 k-steps.
__global__ __launch_bounds__(256) void gemm_qkv(
    const float* __restrict__ A0, const float* __restrict__ A1,
    const float* __restrict__ A2,
    const __hip_bfloat16* __restrict__ B0, const __hip_bfloat16* __restrict__ B1,
    const __hip_bfloat16* __restrict__ B2,
    const float* __restrict__ b0, const float* __restrict__ b1,
    const float* __restrict__ b2,
    __hip_bfloat16* __restrict__ C0, __hip_bfloat16* __restrict__ C1,
    __hip_bfloat16* __restrict__ C2, int M, int N, int K)
{
    __shared__ __align__(16) __hip_bfloat16 As[128 * 64];
    __shared__ __align__(16) __hip_bfloat16 Bs[128 * 64];

    const int z = blockIdx.z;
    const float* A           = (z == 0) ? A0 : (z == 1) ? A1 : A2;
    const __hip_bfloat16* Bt = (z == 0) ? B0 : (z == 1) ? B1 : B2;
    const float* bias        = (z == 0) ? b0 : (z == 1) ? b1 : b2;
    __hip_bfloat16* C        = (z == 0) ? C0 : (z == 1) ? C1 : C2;

    const int tid  = threadIdx.x;
    const int lane = tid & 63;
    const int w    = tid >> 6;
    const int wr   = w >> 1, wc = w & 1;
    const int bm   = blockIdx.y * 128, bn = blockIdx.x * 128;

    // staging: 1024 chunks (128 rows x 8 chunks of 8 bf16), 4 per thread
    const float*          gA[4];
    const __hip_bfloat16* gB[4];
    __hip_bfloat16* lAw[4];
    __hip_bfloat16* lB[4];
    #pragma unroll
    for (int it = 0; it < 4; it++) {
        int idx  = it * 256 + tid;
        int r    = idx >> 3;
        int cpos = idx & 7;
        int cdat = cpos ^ (r & 7);
        gA[it]  = A  + (size_t)(bm + r) * K + cdat * 8;
        gB[it]  = Bt + (size_t)(bn + r) * K + cdat * 8;
        lAw[it] = As + r * 64 + cpos * 8;
        lB[it]  = Bs + (size_t)(it * 256 + w * 64) * 8;
    }

    int fa[2][4], fb[2][4];
    #pragma unroll
    for (int kk = 0; kk < 2; kk++)
        #pragma unroll
        for (int i = 0; i < 4; i++) {
            int rA = wr * 64 + i * 16 + (lane & 15);
            int gc = kk * 4 + (lane >> 4);
            fa[kk][i] = rA * 64 + (gc ^ (rA & 7)) * 8;
            int rB = wc * 64 + i * 16 + (lane & 15);
            fb[kk][i] = rB * 64 + (gc ^ (rB & 7)) * 8;
        }

    f32x4 acc[4][4] = {};

    for (int k0 = 0; k0 < K; k0 += 64) {
        #pragma unroll
        for (int it = 0; it < 4; it++) glds16(gB[it] + k0, lB[it]);
        #pragma unroll
        for (int it = 0; it < 4; it++) {
            float4 a = *(const float4*)(gA[it] + k0);
            float4 b = *(const float4*)(gA[it] + k0 + 4);
            *(short8*)lAw[it] = cvt8(a, b);
        }
        __syncthreads();

        #pragma unroll
        for (int kk = 0; kk < 2; kk++) {
            bf16x8 av[4], bv[4];
            #pragma unroll
            for (int i = 0; i < 4; i++) av[i] = *(const bf16x8*)(As + fa[kk][i]);
            #pragma unroll
            for (int i = 0; i < 4; i++) bv[i] = *(const bf16x8*)(Bs + fb[kk][i]);
            #pragma unroll
            for (int mi = 0; mi < 4; mi++)
                #pragma unroll
                for (int ni = 0; ni < 4; ni++)
                    acc[mi][ni] = __builtin_amdgcn_mfma_f32_16x16x32_bf16(
                        av[mi], bv[ni], acc[mi][ni], 0, 0, 0);
        }
        __syncthreads();
    }

    #pragma unroll
    for (int mi = 0; mi < 4; mi++) {
        int row = bm + wr * 64 + mi * 16 + (lane >> 4) * 4;
        #pragma unroll
        for (int ni = 0; ni < 4; ni++) {
            int col = bn + wc * 64 + ni * 16 + (lane & 15);
            float bb = bias[col];
            #pragma unroll
            for (int j = 0; j < 4; j++)
                C[(size_t)(row + j) * N + col] = __float2bfloat16(acc[mi][ni][j] + bb);
        }
    }
}

// ---------------- output GEMM: bf16 x bf16 -> fp32, BK=64 --------------------
__global__ __launch_bounds__(256) void gemm_out(
    const __hip_bfloat16* __restrict__ A, const __hip_bfloat16* __restrict__ Bt,
    const float* __restrict__ bias, float* __restrict__ C, int M, int N, int K)
{
    __shared__ __align__(16) __hip_bfloat16 As[128 * 64];
    __shared__ __align__(16) __hip_bfloat16 Bs[128 * 64];

    const int tid  = threadIdx.x;
    const int lane = tid & 63;
    const int w    = tid >> 6;
    const int wr   = w >> 1, wc = w & 1;
    const int bm   = blockIdx.y * 128, bn = blockIdx.x * 128;

    const __hip_bfloat16* gA[4];
    const __hip_bfloat16* gB[4];
    __hip_bfloat16* lA[4];
    __hip_bfloat16* lB[4];
    #pragma unroll
    for (int it = 0; it < 4; it++) {
        int idx = it * 256 + tid;
        int r = idx >> 3;
        int c = (idx & 7) ^ (r & 7);
        gA[it] = A  + (size_t)(bm + r) * K + c * 8;
        gB[it] = Bt + (size_t)(bn + r) * K + c * 8;
        lA[it] = As + (size_t)(it * 256 + w * 64) * 8;
        lB[it] = Bs + (size_t)(it * 256 + w * 64) * 8;
    }

    int fa[2][4], fb[2][4];
    #pragma unroll
    for (int kk = 0; kk < 2; kk++)
        #pragma unroll
        for (int i = 0; i < 4; i++) {
            int rA = wr * 64 + i * 16 + (lane & 15);
            int gc = kk * 4 + (lane >> 4);
            fa[kk][i] = rA * 64 + (gc ^ (rA & 7)) * 8;
            int rB = wc * 64 + i * 16 + (lane & 15);
            fb[kk][i] = rB * 64 + (gc ^ (rB & 7)) * 8;
        }

    f32x4 acc[4][4] = {};

    for (int k0 = 0; k0 < K; k0 += 64) {
        #pragma unroll
        for (int it = 0; it < 4; it++) {
            glds16(gA[it] + k0, lA[it]);
            glds16(gB[it] + k0, lB[it]);
        }
        __syncthreads();

        #pragma unroll
        for (int kk = 0; kk < 2; kk++) {
            bf16x8 av[4], bv[4];
            #pragma unroll
            for (int i = 0; i < 4; i++) av[i] = *(const bf16x8*)(As + fa[kk][i]);
            #pragma unroll
            for (int i = 0; i < 4; i++) bv[i] = *(const bf16x8*)(Bs + fb[kk][i]);
            #pragma unroll
            for (int mi = 0; mi < 4; mi++)
                #pragma unroll
                for (int ni = 0; ni < 4; ni++)
                    acc[mi][ni] = __builtin_amdgcn_mfma_f32_16x16x32_bf16(
                        av[mi], bv[ni], acc[mi][ni], 0, 0, 0);
        }
        __syncthreads();
    }

    #pragma unroll
    for (int mi = 0; mi < 4; mi++) {
        int row = bm + wr * 64 + mi * 16 + (lane >> 4) * 4;
        #pragma unroll
        for (int ni = 0; ni < 4; ni++) {
            int col = bn + wc * 64 + ni * 16 + (lane & 15);
            float bb = bias[col];
            #pragma unroll
            for (int j = 0; j < 4; j++)
                C[(size_t)(row + j) * N + col] = acc[mi][ni][j] + bb;
        }
    }
}

// ---------------- CSR build over dst = adj[0] --------------------------------
__global__ void count_edges(const int* __restrict__ dst, int* __restrict__ counts, int ne) {
    int e = blockIdx.x * blockDim.x + threadIdx.x;
    if (e < ne) atomicAdd(&counts[dst[e]], 1);
}

// scan + cursor + degree-descending bucket reorder (heaviest nodes first)
__global__ __launch_bounds__(1024) void scan_offsets(
    const int* __restrict__ counts, int* __restrict__ offsets,
    int* __restrict__ cursor, int* __restrict__ reorder)
{
    __shared__ int wsum[16];
    __shared__ int bcnt[9], boff[9];
    const int tid  = threadIdx.x;
    const int lane = tid & 63;
    const int wid  = tid >> 6;

    if (tid < 9) bcnt[tid] = 0;

    int c[4];
    int base = tid * 4;
    int s = 0;
    #pragma unroll
    for (int i = 0; i < 4; i++) { c[i] = counts[base + i]; s += c[i]; }

    int v = s;
    #pragma unroll
    for (int off = 1; off < 64; off <<= 1) {
        int t = __shfl_up(v, off);
        if (lane >= off) v += t;
    }
    if (lane == 63) wsum[wid] = v;
    __syncthreads();
    if (wid == 0) {
        int wv = (lane < 16) ? wsum[lane] : 0;
        #pragma unroll
        for (int off = 1; off < 16; off <<= 1) {
            int t = __shfl_up(wv, off);
            if (lane >= off) wv += t;
        }
        if (lane < 16) wsum[lane] = wv;
    }
    __syncthreads();

    int prefix = (wid > 0 ? wsum[wid - 1] : 0) + (v - s);
    int run = prefix;
    int mybk[4];
    #pragma unroll
    for (int i = 0; i < 4; i++) {
        offsets[base + i] = run;
        cursor[base + i]  = run;
        run += c[i];
        int sc = (c[i] + 7) >> 3; if (sc > 8) sc = 8;
        mybk[i] = 8 - sc;                       // 0 = heaviest bucket
        atomicAdd(&bcnt[mybk[i]], 1);
    }
    if (tid == 1023) offsets[4096] = run;
    __syncthreads();
    if (tid == 0) {
        int acc0 = 0;
        #pragma unroll
        for (int b = 0; b < 9; b++) { boff[b] = acc0; acc0 += bcnt[b]; }
    }
    __syncthreads();
    #pragma unroll
    for (int i = 0; i < 4; i++) {
        int pos = atomicAdd(&boff[mybk[i]], 1);
        reorder[pos] = base + i;
    }
}

// ---------------- fused prep: scatter(+gather) | weight transposes -----------
__global__ __launch_bounds__(256) void prep(
    const int* __restrict__ dst, const int* __restrict__ srcarr,
    const float* __restrict__ epe, int* __restrict__ cursor,
    int* __restrict__ src_s, float* __restrict__ epe_s,
    const float* __restrict__ Wq, const float* __restrict__ Wk,
    const float* __restrict__ Wv, const float* __restrict__ Wo,
    __hip_bfloat16* __restrict__ Wqt, __hip_bfloat16* __restrict__ Wkt,
    __hip_bfloat16* __restrict__ Wvt, __hip_bfloat16* __restrict__ Wot)
{
    __shared__ float t[32][33];
    const int b = blockIdx.x;

    if (b < 256) {
        int e = b * 256 + threadIdx.x;
        int p = atomicAdd(&cursor[dst[e]], 1);
        src_s[p] = srcarr[e];
        #pragma unroll
        for (int n = 0; n < NB; n++) {
            float4 a2, b2;
            const float* base = epe + (size_t)(n * HEADS) * NE + e;
            a2.x = base[0 * NE]; a2.y = base[1 * NE]; a2.z = base[2 * NE]; a2.w = base[3 * NE];
            b2.x = base[4 * NE]; b2.y = base[5 * NE]; b2.z = base[6 * NE]; b2.w = base[7 * NE];
            float* o = epe_s + ((size_t)n * NE + p) * 8;
            *(float4*)o       = a2;
            *(float4*)(o + 4) = b2;
        }
    } else {
        int bb = b - 256;
        const float* W; __hip_bfloat16* Wt; int K, tt;
        if (bb < 384) {
            int m = bb >> 7; tt = bb & 127; K = IN_C;
            W  = (m == 0) ? Wq  : (m == 1) ? Wk  : Wv;
            Wt = (m == 0) ? Wqt : (m == 1) ? Wkt : Wvt;
        } else {
            tt = bb - 384; K = MDL; W = Wo; Wt = Wot;
        }
        const int N = MDL;
        int bx = (tt & 15) * 32;            // n
        int by = (tt >> 4) * 32;            // k
        int tx = threadIdx.x & 31, ty = threadIdx.x >> 5;   // 32 x 8
        #pragma unroll
        for (int i = 0; i < 4; i++)
            t[ty + i * 8][tx] = W[(size_t)(by + ty + i * 8) * N + bx + tx];
        __syncthreads();
        #pragma unroll
        for (int i = 0; i < 4; i++)
            Wt[(size_t)(bx + ty + i * 8) * K + by + tx] =
                __float2bfloat16(t[tx][ty + i * 8]);
    }
}

// ---------------- pass 1: scores (K only) ------------------------------------
// writes raw scores [n][pos][8 heads] and per-(task,head) (m, 1/z)
__global__ __launch_bounds__(256) void sparse_score(
    const __hip_bfloat16* __restrict__ Qb, const __hip_bfloat16* __restrict__ Kb,
    const int* __restrict__ src_s, const float* __restrict__ epe_s,
    const int* __restrict__ offsets, const int* __restrict__ reorder,
    float* __restrict__ score_s, float2* __restrict__ mz)
{
    const int lane = threadIdx.x & 63;
    const int wid  = threadIdx.x >> 6;
    const int bid  = blockIdx.x;
    const int xcd  = bid & 7;
    const int n    = xcd >> 1;
    const int base = ((bid >> 3) << 1) | (xcd & 1);
    const int dstn = reorder[(base << 2) | wid];
    const int task = n * LL + dstn;
    const int hg   = lane >> 3;

    const int beg = offsets[dstn];
    const int end = offsets[dstn + 1];
    const int deg = end - beg;
    if (deg == 0) return;

    bf16x8 q8 = *(const bf16x8*)(Qb + (size_t)task * MDL + lane * 8);
    float qf[8];
    #pragma unroll
    for (int j = 0; j < 8; j++) qf[j] = (float)q8[j];

    const __hip_bfloat16* Kn = Kb + (size_t)n * LL * MDL + lane * 8;
    const float* pe_n = epe_s + (size_t)n * NE * 8 + hg;
    float* sc_n = score_s + (size_t)n * NE * 8 + hg;

    float m = -INFINITY, z = 0.0f;

    if (deg <= 64) {
        const int my_src = src_s[beg + ((lane < deg) ? lane : (deg - 1))];

        #pragma unroll
        for (int slot = 0; slot < 8; slot++) {
            const int r0 = slot * 8;
            if (r0 < deg) {
                bf16x8 kk[8];
                #pragma unroll
                for (int j = 0; j < 8; j++) {
                    int s = __shfl(my_src, r0 + j);
                    kk[j] = *(const bf16x8*)(Kn + (size_t)s * MDL);
                }
                const int rel_mine = r0 + (lane & 7);
                float pp = (rel_mine < deg)
                         ? pe_n[(size_t)(beg + rel_mine) * 8] : -INFINITY;

                float p[8];
                #pragma unroll
                for (int j = 0; j < 8; j++) {
                    float d = 0.0f;
                    #pragma unroll
                    for (int dd = 0; dd < 8; dd++)
                        d = fmaf(qf[dd], (float)kk[j][dd], d);
                    p[j] = d;
                }
                // transpose-reduce butterfly within 8-lane groups
                float n0, n1, n2, n3, u0, u1, sraw;
                {
                    float a0 = (lane & 1) ? p[1] : p[0];
                    float b0 = (lane & 1) ? p[0] : p[1];
                    n0 = a0 + __shfl_xor(b0, 1);
                    float a1 = (lane & 1) ? p[3] : p[2];
                    float b1 = (lane & 1) ? p[2] : p[3];
                    n1 = a1 + __shfl_xor(b1, 1);
                    float a2 = (lane & 1) ? p[5] : p[4];
                    float b2 = (lane & 1) ? p[4] : p[5];
                    n2 = a2 + __shfl_xor(b2, 1);
                    float a3 = (lane & 1) ? p[7] : p[6];
                    float b3 = (lane & 1) ? p[6] : p[7];
                    n3 = a3 + __shfl_xor(b3, 1);

                    float c0 = (lane & 2) ? n1 : n0;
                    float d0 = (lane & 2) ? n0 : n1;
                    u0 = c0 + __shfl_xor(d0, 2);
                    float c1 = (lane & 2) ? n3 : n2;
                    float d1 = (lane & 2) ? n2 : n3;
                    u1 = c1 + __shfl_xor(d1, 2);

                    float e0 = (lane & 4) ? u1 : u0;
                    float f0 = (lane & 4) ? u0 : u1;
                    sraw = e0 + __shfl_xor(f0, 4);
                }

                float sc_my = TEMP * (sraw + pp);     // pads -> -inf
                if (rel_mine < deg)
                    sc_n[(size_t)(beg + rel_mine) * 8] = sc_my;

                float gm = sc_my;
                gm = fmaxf(gm, __shfl_xor(gm, 1));
                gm = fmaxf(gm, __shfl_xor(gm, 2));
                gm = fmaxf(gm, __shfl_xor(gm, 4));
                float mnew = fmaxf(m, gm);
                float e_my = __expf(sc_my - mnew);
                float gs = e_my;
                gs += __shfl_xor(gs, 1);
                gs += __shfl_xor(gs, 2);
                gs += __shfl_xor(gs, 4);
                z = z * __expf(m - mnew) + gs;
                m = mnew;
            }
        }
    } else {
        // fallback: chunked, K-only, scores to memory
        for (int i = beg; i < end; i += 4) {
            float sc4[4];
            #pragma unroll
            for (int j = 0; j < 4; j++) {
                int idx = i + j;
                int ok  = idx < end;
                int s   = ok ? src_s[idx] : src_s[beg];
                bf16x8 kk = *(const bf16x8*)(Kn + (size_t)s * MDL);
                float pp = ok ? pe_n[(size_t)idx * 8] : -INFINITY;
                float d = 0.0f;
                #pragma unroll
                for (int dd = 0; dd < 8; dd++) d += qf[dd] * (float)kk[dd];
                d += __shfl_xor(d, 1);
                d += __shfl_xor(d, 2);
                d += __shfl_xor(d, 4);
                sc4[j] = TEMP * (d + pp);
                if (ok && (lane & 7) == 0)
                    sc_n[(size_t)idx * 8] = sc4[j];
            }
            float mb   = fmaxf(fmaxf(sc4[0], sc4[1]), fmaxf(sc4[2], sc4[3]));
            float mnew = fmaxf(m, mb);
            float sc   = __expf(m - mnew);
            float s0 = __expf(sc4[0] - mnew);
            float s1 = __expf(sc4[1] - mnew);
            float s2 = __expf(sc4[2] - mnew);
            float s3 = __expf(sc4[3] - mnew);
            z = z * sc + (s0 + s1 + s2 + s3);
            m = mnew;
        }
    }

    if ((lane & 7) == 0) {
        float2 v; v.x = m; v.y = 1.0f / z;
        mz[(size_t)task * 8 + hg] = v;
    }
}

// ---------------- pass 2: output (V only), no serial chain -------------------
__global__ __launch_bounds__(256) void sparse_out(
    const __hip_bfloat16* __restrict__ Vb,
    const int* __restrict__ src_s, const float* __restrict__ score_s,
    const int* __restrict__ offsets, const int* __restrict__ reorder,
    const float2* __restrict__ mz, __hip_bfloat16* __restrict__ O)
{
    const int lane = threadIdx.x & 63;
    const int wid  = threadIdx.x >> 6;
    const int bid  = blockIdx.x;
    const int xcd  = bid & 7;
    const int n    = xcd >> 1;
    const int base = ((bid >> 3) << 1) | (xcd & 1);
    const int dstn = reorder[(base << 2) | wid];
    const int task = n * LL + dstn;
    const int hg   = lane >> 3;

    const size_t rowbase = (size_t)task * MDL;
    const int beg = offsets[dstn];
    const int end = offsets[dstn + 1];
    const int deg = end - beg;

    union { short8 v8; __hip_bfloat16 h[8]; } uo;
    if (deg == 0) {
        #pragma unroll
        for (int j = 0; j < 8; j++) uo.h[j] = __float2bfloat16(0.0f);
        *(short8*)(O + rowbase + lane * 8) = uo.v8;
        return;
    }

    float2 mzv = mz[(size_t)task * 8 + hg];
    const float m = mzv.x, zinv = mzv.y;

    const __hip_bfloat16* Vn = Vb + (size_t)n * LL * MDL + lane * 8;
    const float* sc_n = score_s + (size_t)n * NE * 8 + hg;

    float acc[8] = {};

    if (deg <= 64) {
        const int my_src = src_s[beg + ((lane < deg) ? lane : (deg - 1))];

        #pragma unroll
        for (int slot = 0; slot < 8; slot++) {
            const int r0 = slot * 8;
            if (r0 < deg) {
                bf16x8 vv[8];
                #pragma unroll
                for (int j = 0; j < 8; j++) {
                    int s = __shfl(my_src, r0 + j);
                    vv[j] = *(const bf16x8*)(Vn + (size_t)s * MDL);
                }
                const int rel_mine = r0 + (lane & 7);
                float sc = (rel_mine < deg)
                         ? sc_n[(size_t)(beg + rel_mine) * 8] : -INFINITY;
                float a_l = __expf(sc - m) * zinv;    // pads -> 0
                #pragma unroll
                for (int j = 0; j < 8; j++) {
                    float al = __shfl(a_l, (lane & 56) | j);
                    #pragma unroll
                    for (int dd = 0; dd < 8; dd++)
                        acc[dd] = fmaf(al, (float)vv[j][dd], acc[dd]);
                }
            }
        }
    } else {
        for (int i = beg; i < end; i += 4) {
            #pragma unroll
            for (int j = 0; j < 4; j++) {
                int idx = i + j;
                int ok  = idx < end;
                int s   = ok ? src_s[idx] : src_s[beg];
                bf16x8 vv = *(const bf16x8*)(Vn + (size_t)s * MDL);
                float sc = ok ? sc_n[(size_t)idx * 8] : -INFINITY;
                float al = __expf(sc - m) * zinv;
                #pragma unroll
                for (int dd = 0; dd < 8; dd++)
                    acc[dd] = fmaf(al, (float)vv[dd], acc[dd]);
            }
        }
    }

    #pragma unroll
    for (int j = 0; j < 8; j++) uo.h[j] = __float2bfloat16(acc[j]);
    *(short8*)(O + rowbase + lane * 8) = uo.v8;
}

// ---------------- launch ------------------------------------------------------
extern "C" void kernel_launch(void* const* d_in, const int* in_sizes, int n_in,
                              void* d_out, int out_size, void* d_ws, size_t ws_size,
                              hipStream_t stream)
{
    const float* queries = (const float*)d_in[0];
    const float* keys    = (const float*)d_in[1];
    const float* values  = (const float*)d_in[2];
    const int*   adj     = (const int*)d_in[3];
    const float* epe     = (const float*)d_in[4];
    const float* Wq = (const float*)d_in[5];
    const float* bq = (const float*)d_in[6];
    const float* Wk = (const float*)d_in[7];
    const float* bk = (const float*)d_in[8];
    const float* Wv = (const float*)d_in[9];
    const float* bv = (const float*)d_in[10];
    const float* Wo = (const float*)d_in[11];
    const float* bo = (const float*)d_in[12];
    float* out = (float*)d_out;

    const int* dst = adj;
    const int* src = adj + NE;

    const int    M   = NB * LL;                     // 16384
    const size_t NLM = (size_t)M * MDL;             // 8,388,608

    char* w = (char*)d_ws;
    __hip_bfloat16* Qb  = (__hip_bfloat16*)w; w += NLM * 2;      // 16.78 MB
    __hip_bfloat16* Kb  = (__hip_bfloat16*)w; w += NLM * 2;
    __hip_bfloat16* Vb  = (__hip_bfloat16*)w; w += NLM * 2;
    __hip_bfloat16* Ob  = (__hip_bfloat16*)w; w += NLM * 2;
    __hip_bfloat16* Wqt = (__hip_bfloat16*)w; w += (size_t)MDL * IN_C * 2;
    __hip_bfloat16* Wkt = (__hip_bfloat16*)w; w += (size_t)MDL * IN_C * 2;
    __hip_bfloat16* Wvt = (__hip_bfloat16*)w; w += (size_t)MDL * IN_C * 2;
    __hip_bfloat16* Wot = (__hip_bfloat16*)w; w += (size_t)MDL * MDL * 2;
    int* counts  = (int*)w; w += 4096 * sizeof(int);
    int* offsets = (int*)w; w += 4100 * sizeof(int);
    int* cursor  = (int*)w; w += 4096 * sizeof(int);
    int* reorder = (int*)w; w += 4096 * sizeof(int);
    int*   src_s = (int*)w; w += NE * sizeof(int);
    float* epe_s   = (float*)w;  w += (size_t)NB * NE * 8 * sizeof(float);  // 8.39 MB
    float* score_s = (float*)w;  w += (size_t)NB * NE * 8 * sizeof(float);  // 8.39 MB
    float2* mz     = (float2*)w; w += (size_t)M * 8 * sizeof(float2);       // 1.05 MB

    // CSR build
    hipMemsetAsync(counts, 0, 4096 * sizeof(int), stream);
    count_edges<<<NE / 256, 256, 0, stream>>>(dst, counts, NE);
    scan_offsets<<<1, 1024, 0, stream>>>(counts, offsets, cursor, reorder);

    // fused prep: scatter+gather | weight transposes
    prep<<<896, 256, 0, stream>>>(dst, src, epe, cursor, src_s, epe_s,
                                  Wq, Wk, Wv, Wo, Wqt, Wkt, Wvt, Wot);

    // QKV projections (one launch, z=3, fused fp32->bf16 A-staging, BK=64)
    dim3 g3(MDL / 128, M / 128, 3);
    gemm_qkv<<<g3, 256, 0, stream>>>(queries, keys, values, Wqt, Wkt, Wvt,
                                     bq, bk, bv, Qb, Kb, Vb, M, MDL, IN_C);

    // sparse attention, two phase-separated dispatches
    sparse_score<<<(NB * LL) / 4, 256, 0, stream>>>(Qb, Kb, src_s, epe_s,
                                                    offsets, reorder, score_s, mz);
    sparse_out<<<(NB * LL) / 4, 256, 0, stream>>>(Vb, src_s, score_s,
                                                  offsets, reorder, mz, Ob);

    // output projection (fp32 out + bias, BK=64)
    dim3 g(MDL / 128, M / 128);
    gemm_out<<<g, 256, 0, stream>>>(Ob, Wot, bo, out, M, MDL, MDL);
}

// Round 9
// 123.192 us; speedup vs baseline: 1.2747x; 1.0717x over previous
//
#include <hip/hip_runtime.h>
#include <hip/hip_bf16.h>
#include <math.h>
#include <stdint.h>

// Problem constants (SparseAttention_46969762349725)
#define HEADS 8
#define IN_C  256
#define MDL   512
#define NB    4        // batch
#define LL    4096     // nodes
#define NE    65536    // edges
#define EDIM  64       // per-head dim = MDL/HEADS
#define TEMP  0.125f   // 1/sqrt(64)

typedef __bf16 bf16x8 __attribute__((ext_vector_type(8)));
typedef float  f32x4  __attribute__((ext_vector_type(4)));
typedef short  short8 __attribute__((ext_vector_type(8)));

__device__ __forceinline__ void glds16(const void* g, void* l) {
    __builtin_amdgcn_global_load_lds(
        (const __attribute__((address_space(1))) void*)g,
        (__attribute__((address_space(3))) void*)l, 16, 0, 0);
}

__device__ __forceinline__ short8 cvt8(float4 a, float4 b) {
    union { short8 v; __hip_bfloat16 h[8]; } u;
    u.h[0] = __float2bfloat16(a.x); u.h[1] = __float2bfloat16(a.y);
    u.h[2] = __float2bfloat16(a.z); u.h[3] = __float2bfloat16(a.w);
    u.h[4] = __float2bfloat16(b.x); u.h[5] = __float2bfloat16(b.y);
    u.h[6] = __float2bfloat16(b.z); u.h[7] = __float2bfloat16(b.w);
    return u.v;
}

// XCD-aware tile map: 512 blocks/slice = 128 bm x 4 bn; each XCD owns 16
// contiguous bm (A footprint 2.1MB -> L2-resident) and walks bn outermost.
__device__ __forceinline__ void tile_map(int* bm, int* bn) {
    int lin = blockIdx.y * gridDim.x + blockIdx.x;   // 0..511
    int xcd = lin & 7;
    int t   = lin >> 3;                              // 0..63
    *bm = (xcd * 16 + (t & 15)) * 128;
    *bn = (t >> 4) * 128;
}

// ---------------- QKV GEMM: A fp32 (fused convert), Bt bf16, C bf16, BK=64 ---
__global__ __launch_bounds__(256) void gemm_qkv(
    const float* __restrict__ A0, const float* __restrict__ A1,
    const float* __restrict__ A2,
    const __hip_bfloat16* __restrict__ B0, const __hip_bfloat16* __restrict__ B1,
    const __hip_bfloat16* __restrict__ B2,
    const float* __restrict__ b0, const float* __restrict__ b1,
    const float* __restrict__ b2,
    __hip_bfloat16* __restrict__ C0, __hip_bfloat16* __restrict__ C1,
    __hip_bfloat16* __restrict__ C2, int M, int N, int K)
{
    __shared__ __align__(16) __hip_bfloat16 As[128 * 64];
    __shared__ __align__(16) __hip_bfloat16 Bs[128 * 64];

    const int z = blockIdx.z;
    const float* A           = (z == 0) ? A0 : (z == 1) ? A1 : A2;
    const __hip_bfloat16* Bt = (z == 0) ? B0 : (z == 1) ? B1 : B2;
    const float* bias        = (z == 0) ? b0 : (z == 1) ? b1 : b2;
    __hip_bfloat16* C        = (z == 0) ? C0 : (z == 1) ? C1 : C2;

    const int tid  = threadIdx.x;
    const int lane = tid & 63;
    const int w    = tid >> 6;
    const int wr   = w >> 1, wc = w & 1;
    int bm, bn;
    tile_map(&bm, &bn);

    // staging: 1024 chunks (128 rows x 8 chunks of 8 bf16), 4 per thread
    const float*          gA[4];
    const __hip_bfloat16* gB[4];
    __hip_bfloat16* lAw[4];
    __hip_bfloat16* lB[4];
    #pragma unroll
    for (int it = 0; it < 4; it++) {
        int idx  = it * 256 + tid;
        int r    = idx >> 3;
        int cpos = idx & 7;
        int cdat = cpos ^ (r & 7);
        gA[it]  = A  + (size_t)(bm + r) * K + cdat * 8;
        gB[it]  = Bt + (size_t)(bn + r) * K + cdat * 8;
        lAw[it] = As + r * 64 + cpos * 8;
        lB[it]  = Bs + (size_t)(it * 256 + w * 64) * 8;
    }

    int fa[2][4], fb[2][4];
    #pragma unroll
    for (int kk = 0; kk < 2; kk++)
        #pragma unroll
        for (int i = 0; i < 4; i++) {
            int rA = wr * 64 + i * 16 + (lane & 15);
            int gc = kk * 4 + (lane >> 4);
            fa[kk][i] = rA * 64 + (gc ^ (rA & 7)) * 8;
            int rB = wc * 64 + i * 16 + (lane & 15);
            fb[kk][i] = rB * 64 + (gc ^ (rB & 7)) * 8;
        }

    f32x4 acc[4][4] = {};

    for (int k0 = 0; k0 < K; k0 += 64) {
        #pragma unroll
        for (int it = 0; it < 4; it++) glds16(gB[it] + k0, lB[it]);
        #pragma unroll
        for (int it = 0; it < 4; it++) {
            float4 a = *(const float4*)(gA[it] + k0);
            float4 b = *(const float4*)(gA[it] + k0 + 4);
            *(short8*)lAw[it] = cvt8(a, b);
        }
        __syncthreads();

        #pragma unroll
        for (int kk = 0; kk < 2; kk++) {
            bf16x8 av[4], bv[4];
            #pragma unroll
            for (int i = 0; i < 4; i++) av[i] = *(const bf16x8*)(As + fa[kk][i]);
            #pragma unroll
            for (int i = 0; i < 4; i++) bv[i] = *(const bf16x8*)(Bs + fb[kk][i]);
            #pragma unroll
            for (int mi = 0; mi < 4; mi++)
                #pragma unroll
                for (int ni = 0; ni < 4; ni++)
                    acc[mi][ni] = __builtin_amdgcn_mfma_f32_16x16x32_bf16(
                        av[mi], bv[ni], acc[mi][ni], 0, 0, 0);
        }
        __syncthreads();
    }

    #pragma unroll
    for (int mi = 0; mi < 4; mi++) {
        int row = bm + wr * 64 + mi * 16 + (lane >> 4) * 4;
        #pragma unroll
        for (int ni = 0; ni < 4; ni++) {
            int col = bn + wc * 64 + ni * 16 + (lane & 15);
            float bb = bias[col];
            #pragma unroll
            for (int j = 0; j < 4; j++)
                C[(size_t)(row + j) * N + col] = __float2bfloat16(acc[mi][ni][j] + bb);
        }
    }
}

// ---------------- output GEMM: bf16 x bf16 -> fp32, BK=64 --------------------
__global__ __launch_bounds__(256) void gemm_out(
    const __hip_bfloat16* __restrict__ A, const __hip_bfloat16* __restrict__ Bt,
    const float* __restrict__ bias, float* __restrict__ C, int M, int N, int K)
{
    __shared__ __align__(16) __hip_bfloat16 As[128 * 64];
    __shared__ __align__(16) __hip_bfloat16 Bs[128 * 64];

    const int tid  = threadIdx.x;
    const int lane = tid & 63;
    const int w    = tid >> 6;
    const int wr   = w >> 1, wc = w & 1;
    int bm, bn;
    tile_map(&bm, &bn);

    const __hip_bfloat16* gA[4];
    const __hip_bfloat16* gB[4];
    __hip_bfloat16* lA[4];
    __hip_bfloat16* lB[4];
    #pragma unroll
    for (int it = 0; it < 4; it++) {
        int idx = it * 256 + tid;
        int r = idx >> 3;
        int c = (idx & 7) ^ (r & 7);
        gA[it] = A  + (size_t)(bm + r) * K + c * 8;
        gB[it] = Bt + (size_t)(bn + r) * K + c * 8;
        lA[it] = As + (size_t)(it * 256 + w * 64) * 8;
        lB[it] = Bs + (size_t)(it * 256 + w * 64) * 8;
    }

    int fa[2][4], fb[2][4];
    #pragma unroll
    for (int kk = 0; kk < 2; kk++)
        #pragma unroll
        for (int i = 0; i < 4; i++) {
            int rA = wr * 64 + i * 16 + (lane & 15);
            int gc = kk * 4 + (lane >> 4);
            fa[kk][i] = rA * 64 + (gc ^ (rA & 7)) * 8;
            int rB = wc * 64 + i * 16 + (lane & 15);
            fb[kk][i] = rB * 64 + (gc ^ (rB & 7)) * 8;
        }

    f32x4 acc[4][4] = {};

    for (int k0 = 0; k0 < K; k0 += 64) {
        #pragma unroll
        for (int it = 0; it < 4; it++) {
            glds16(gA[it] + k0, lA[it]);
            glds16(gB[it] + k0, lB[it]);
        }
        __syncthreads();

        #pragma unroll
        for (int kk = 0; kk < 2; kk++) {
            bf16x8 av[4], bv[4];
            #pragma unroll
            for (int i = 0; i < 4; i++) av[i] = *(const bf16x8*)(As + fa[kk][i]);
            #pragma unroll
            for (int i = 0; i < 4; i++) bv[i] = *(const bf16x8*)(Bs + fb[kk][i]);
            #pragma unroll
            for (int mi = 0; mi < 4; mi++)
                #pragma unroll
                for (int ni = 0; ni < 4; ni++)
                    acc[mi][ni] = __builtin_amdgcn_mfma_f32_16x16x32_bf16(
                        av[mi], bv[ni], acc[mi][ni], 0, 0, 0);
        }
        __syncthreads();
    }

    #pragma unroll
    for (int mi = 0; mi < 4; mi++) {
        int row = bm + wr * 64 + mi * 16 + (lane >> 4) * 4;
        #pragma unroll
        for (int ni = 0; ni < 4; ni++) {
            int col = bn + wc * 64 + ni * 16 + (lane & 15);
            float bb = bias[col];
            #pragma unroll
            for (int j = 0; j < 4; j++)
                C[(size_t)(row + j) * N + col] = acc[mi][ni][j] + bb;
        }
    }
}

// ---------------- CSR build over dst = adj[0] --------------------------------
__global__ void count_edges(const int* __restrict__ dst, int* __restrict__ counts, int ne) {
    int e = blockIdx.x * blockDim.x + threadIdx.x;
    if (e < ne) atomicAdd(&counts[dst[e]], 1);
}

// scan + cursor + degree-descending bucket reorder (heaviest nodes first)
__global__ __launch_bounds__(1024) void scan_offsets(
    const int* __restrict__ counts, int* __restrict__ offsets,
    int* __restrict__ cursor, int* __restrict__ reorder)
{
    __shared__ int wsum[16];
    __shared__ int bcnt[9], boff[9];
    const int tid  = threadIdx.x;
    const int lane = tid & 63;
    const int wid  = tid >> 6;

    if (tid < 9) bcnt[tid] = 0;

    int c[4];
    int base = tid * 4;
    int s = 0;
    #pragma unroll
    for (int i = 0; i < 4; i++) { c[i] = counts[base + i]; s += c[i]; }

    int v = s;
    #pragma unroll
    for (int off = 1; off < 64; off <<= 1) {
        int t = __shfl_up(v, off);
        if (lane >= off) v += t;
    }
    if (lane == 63) wsum[wid] = v;
    __syncthreads();
    if (wid == 0) {
        int wv = (lane < 16) ? wsum[lane] : 0;
        #pragma unroll
        for (int off = 1; off < 16; off <<= 1) {
            int t = __shfl_up(wv, off);
            if (lane >= off) wv += t;
        }
        if (lane < 16) wsum[lane] = wv;
    }
    __syncthreads();

    int prefix = (wid > 0 ? wsum[wid - 1] : 0) + (v - s);
    int run = prefix;
    int mybk[4];
    #pragma unroll
    for (int i = 0; i < 4; i++) {
        offsets[base + i] = run;
        cursor[base + i]  = run;
        run += c[i];
        int sc = (c[i] + 7) >> 3; if (sc > 8) sc = 8;
        mybk[i] = 8 - sc;                       // 0 = heaviest bucket
        atomicAdd(&bcnt[mybk[i]], 1);
    }
    if (tid == 1023) offsets[4096] = run;
    __syncthreads();
    if (tid == 0) {
        int acc0 = 0;
        #pragma unroll
        for (int b = 0; b < 9; b++) { boff[b] = acc0; acc0 += bcnt[b]; }
    }
    __syncthreads();
    #pragma unroll
    for (int i = 0; i < 4; i++) {
        int pos = atomicAdd(&boff[mybk[i]], 1);
        reorder[pos] = base + i;
    }
}

// ---------------- fused prep: scatter(+gather) | weight transposes -----------
__global__ __launch_bounds__(256) void prep(
    const int* __restrict__ dst, const int* __restrict__ srcarr,
    const float* __restrict__ epe, int* __restrict__ cursor,
    int* __restrict__ src_s, float* __restrict__ epe_s,
    const float* __restrict__ Wq, const float* __restrict__ Wk,
    const float* __restrict__ Wv, const float* __restrict__ Wo,
    __hip_bfloat16* __restrict__ Wqt, __hip_bfloat16* __restrict__ Wkt,
    __hip_bfloat16* __restrict__ Wvt, __hip_bfloat16* __restrict__ Wot)
{
    __shared__ float t[32][33];
    const int b = blockIdx.x;

    if (b < 256) {
        int e = b * 256 + threadIdx.x;
        int p = atomicAdd(&cursor[dst[e]], 1);
        src_s[p] = srcarr[e];
        #pragma unroll
        for (int n = 0; n < NB; n++) {
            float4 a2, b2;
            const float* base = epe + (size_t)(n * HEADS) * NE + e;
            a2.x = base[0 * NE]; a2.y = base[1 * NE]; a2.z = base[2 * NE]; a2.w = base[3 * NE];
            b2.x = base[4 * NE]; b2.y = base[5 * NE]; b2.z = base[6 * NE]; b2.w = base[7 * NE];
            float* o = epe_s + ((size_t)n * NE + p) * 8;
            *(float4*)o       = a2;
            *(float4*)(o + 4) = b2;
        }
    } else {
        int bb = b - 256;
        const float* W; __hip_bfloat16* Wt; int K, tt;
        if (bb < 384) {
            int m = bb >> 7; tt = bb & 127; K = IN_C;
            W  = (m == 0) ? Wq  : (m == 1) ? Wk  : Wv;
            Wt = (m == 0) ? Wqt : (m == 1) ? Wkt : Wvt;
        } else {
            tt = bb - 384; K = MDL; W = Wo; Wt = Wot;
        }
        const int N = MDL;
        int bx = (tt & 15) * 32;            // n
        int by = (tt >> 4) * 32;            // k
        int tx = threadIdx.x & 31, ty = threadIdx.x >> 5;   // 32 x 8
        #pragma unroll
        for (int i = 0; i < 4; i++)
            t[ty + i * 8][tx] = W[(size_t)(by + ty + i * 8) * N + bx + tx];
        __syncthreads();
        #pragma unroll
        for (int i = 0; i < 4; i++)
            Wt[(size_t)(bx + ty + i * 8) * K + by + tx] =
                __float2bfloat16(t[tx][ty + i * 8]);
    }
}

// ---------------- pass 1: scores (K only) ------------------------------------
// writes raw scores [n][pos][8 heads] and per-(task,head) (m, 1/z)
__global__ __launch_bounds__(256) void sparse_score(
    const __hip_bfloat16* __restrict__ Qb, const __hip_bfloat16* __restrict__ Kb,
    const int* __restrict__ src_s, const float* __restrict__ epe_s,
    const int* __restrict__ offsets, const int* __restrict__ reorder,
    float* __restrict__ score_s, float2* __restrict__ mz)
{
    const int lane = threadIdx.x & 63;
    const int wid  = threadIdx.x >> 6;
    const int bid  = blockIdx.x;
    const int xcd  = bid & 7;
    const int n    = xcd >> 1;
    const int base = ((bid >> 3) << 1) | (xcd & 1);
    const int dstn = reorder[(base << 2) | wid];
    const int task = n * LL + dstn;
    const int hg   = lane >> 3;

    const int beg = offsets[dstn];
    const int end = offsets[dstn + 1];
    const int deg = end - beg;
    if (deg == 0) return;

    bf16x8 q8 = *(const bf16x8*)(Qb + (size_t)task * MDL + lane * 8);
    float qf[8];
    #pragma unroll
    for (int j = 0; j < 8; j++) qf[j] = (float)q8[j];

    const __hip_bfloat16* Kn = Kb + (size_t)n * LL * MDL + lane * 8;
    const float* pe_n = epe_s + (size_t)n * NE * 8 + hg;
    float* sc_n = score_s + (size_t)n * NE * 8 + hg;

    float m = -INFINITY, z = 0.0f;

    if (deg <= 64) {
        const int my_src = src_s[beg + ((lane < deg) ? lane : (deg - 1))];

        #pragma unroll
        for (int slot = 0; slot < 8; slot++) {
            const int r0 = slot * 8;
            if (r0 < deg) {
                bf16x8 kk[8];
                #pragma unroll
                for (int j = 0; j < 8; j++) {
                    int s = __shfl(my_src, r0 + j);
                    kk[j] = *(const bf16x8*)(Kn + (size_t)s * MDL);
                }
                const int rel_mine = r0 + (lane & 7);
                float pp = (rel_mine < deg)
                         ? pe_n[(size_t)(beg + rel_mine) * 8] : -INFINITY;

                float p[8];
                #pragma unroll
                for (int j = 0; j < 8; j++) {
                    float d = 0.0f;
                    #pragma unroll
                    for (int dd = 0; dd < 8; dd++)
                        d = fmaf(qf[dd], (float)kk[j][dd], d);
                    p[j] = d;
                }
                // transpose-reduce butterfly within 8-lane groups
                float n0, n1, n2, n3, u0, u1, sraw;
                {
                    float a0 = (lane & 1) ? p[1] : p[0];
                    float b0 = (lane & 1) ? p[0] : p[1];
                    n0 = a0 + __shfl_xor(b0, 1);
                    float a1 = (lane & 1) ? p[3] : p[2];
                    float b1 = (lane & 1) ? p[2] : p[3];
                    n1 = a1 + __shfl_xor(b1, 1);
                    float a2 = (lane & 1) ? p[5] : p[4];
                    float b2 = (lane & 1) ? p[4] : p[5];
                    n2 = a2 + __shfl_xor(b2, 1);
                    float a3 = (lane & 1) ? p[7] : p[6];
                    float b3 = (lane & 1) ? p[6] : p[7];
                    n3 = a3 + __shfl_xor(b3, 1);

                    float c0 = (lane & 2) ? n1 : n0;
                    float d0 = (lane & 2) ? n0 : n1;
                    u0 = c0 + __shfl_xor(d0, 2);
                    float c1 = (lane & 2) ? n3 : n2;
                    float d1 = (lane & 2) ? n2 : n3;
                    u1 = c1 + __shfl_xor(d1, 2);

                    float e0 = (lane & 4) ? u1 : u0;
                    float f0 = (lane & 4) ? u0 : u1;
                    sraw = e0 + __shfl_xor(f0, 4);
                }

                float sc_my = TEMP * (sraw + pp);     // pads -> -inf
                if (rel_mine < deg)
                    sc_n[(size_t)(beg + rel_mine) * 8] = sc_my;

                float gm = sc_my;
                gm = fmaxf(gm, __shfl_xor(gm, 1));
                gm = fmaxf(gm, __shfl_xor(gm, 2));
                gm = fmaxf(gm, __shfl_xor(gm, 4));
                float mnew = fmaxf(m, gm);
                float e_my = __expf(sc_my - mnew);
                float gs = e_my;
                gs += __shfl_xor(gs, 1);
                gs += __shfl_xor(gs, 2);
                gs += __shfl_xor(gs, 4);
                z = z * __expf(m - mnew) + gs;
                m = mnew;
            }
        }
    } else {
        // fallback: chunked, K-only, scores to memory
        for (int i = beg; i < end; i += 4) {
            float sc4[4];
            #pragma unroll
            for (int j = 0; j < 4; j++) {
                int idx = i + j;
                int ok  = idx < end;
                int s   = ok ? src_s[idx] : src_s[beg];
                bf16x8 kk = *(const bf16x8*)(Kn + (size_t)s * MDL);
                float pp = ok ? pe_n[(size_t)idx * 8] : -INFINITY;
                float d = 0.0f;
                #pragma unroll
                for (int dd = 0; dd < 8; dd++) d += qf[dd] * (float)kk[dd];
                d += __shfl_xor(d, 1);
                d += __shfl_xor(d, 2);
                d += __shfl_xor(d, 4);
                sc4[j] = TEMP * (d + pp);
                if (ok && (lane & 7) == 0)
                    sc_n[(size_t)idx * 8] = sc4[j];
            }
            float mb   = fmaxf(fmaxf(sc4[0], sc4[1]), fmaxf(sc4[2], sc4[3]));
            float mnew = fmaxf(m, mb);
            float sc   = __expf(m - mnew);
            float s0 = __expf(sc4[0] - mnew);
            float s1 = __expf(sc4[1] - mnew);
            float s2 = __expf(sc4[2] - mnew);
            float s3 = __expf(sc4[3] - mnew);
            z = z * sc + (s0 + s1 + s2 + s3);
            m = mnew;
        }
    }

    if ((lane & 7) == 0) {
        float2 v; v.x = m; v.y = 1.0f / z;
        mz[(size_t)task * 8 + hg] = v;
    }
}

// ---------------- pass 2: output (V only), no serial chain -------------------
__global__ __launch_bounds__(256) void sparse_out(
    const __hip_bfloat16* __restrict__ Vb,
    const int* __restrict__ src_s, const float* __restrict__ score_s,
    const int* __restrict__ offsets, const int* __restrict__ reorder,
    const float2* __restrict__ mz, __hip_bfloat16* __restrict__ O)
{
    const int lane = threadIdx.x & 63;
    const int wid  = threadIdx.x >> 6;
    const int bid  = blockIdx.x;
    const int xcd  = bid & 7;
    const int n    = xcd >> 1;
    const int base = ((bid >> 3) << 1) | (xcd & 1);
    const int dstn = reorder[(base << 2) | wid];
    const int task = n * LL + dstn;
    const int hg   = lane >> 3;

    const size_t rowbase = (size_t)task * MDL;
    const int beg = offsets[dstn];
    const int end = offsets[dstn + 1];
    const int deg = end - beg;

    union { short8 v8; __hip_bfloat16 h[8]; } uo;
    if (deg == 0) {
        #pragma unroll
        for (int j = 0; j < 8; j++) uo.h[j] = __float2bfloat16(0.0f);
        *(short8*)(O + rowbase + lane * 8) = uo.v8;
        return;
    }

    float2 mzv = mz[(size_t)task * 8 + hg];
    const float m = mzv.x, zinv = mzv.y;

    const __hip_bfloat16* Vn = Vb + (size_t)n * LL * MDL + lane * 8;
    const float* sc_n = score_s + (size_t)n * NE * 8 + hg;

    float acc[8] = {};

    if (deg <= 64) {
        const int my_src = src_s[beg + ((lane < deg) ? lane : (deg - 1))];

        #pragma unroll
        for (int slot = 0; slot < 8; slot++) {
            const int r0 = slot * 8;
            if (r0 < deg) {
                bf16x8 vv[8];
                #pragma unroll
                for (int j = 0; j < 8; j++) {
                    int s = __shfl(my_src, r0 + j);
                    vv[j] = *(const bf16x8*)(Vn + (size_t)s * MDL);
                }
                const int rel_mine = r0 + (lane & 7);
                float sc = (rel_mine < deg)
                         ? sc_n[(size_t)(beg + rel_mine) * 8] : -INFINITY;
                float a_l = __expf(sc - m) * zinv;    // pads -> 0
                #pragma unroll
                for (int j = 0; j < 8; j++) {
                    float al = __shfl(a_l, (lane & 56) | j);
                    #pragma unroll
                    for (int dd = 0; dd < 8; dd++)
                        acc[dd] = fmaf(al, (float)vv[j][dd], acc[dd]);
                }
            }
        }
    } else {
        for (int i = beg; i < end; i += 4) {
            #pragma unroll
            for (int j = 0; j < 4; j++) {
                int idx = i + j;
                int ok  = idx < end;
                int s   = ok ? src_s[idx] : src_s[beg];
                bf16x8 vv = *(const bf16x8*)(Vn + (size_t)s * MDL);
                float sc = ok ? sc_n[(size_t)idx * 8] : -INFINITY;
                float al = __expf(sc - m) * zinv;
                #pragma unroll
                for (int dd = 0; dd < 8; dd++)
                    acc[dd] = fmaf(al, (float)vv[dd], acc[dd]);
            }
        }
    }

    #pragma unroll
    for (int j = 0; j < 8; j++) uo.h[j] = __float2bfloat16(acc[j]);
    *(short8*)(O + rowbase + lane * 8) = uo.v8;
}

// ---------------- launch ------------------------------------------------------
extern "C" void kernel_launch(void* const* d_in, const int* in_sizes, int n_in,
                              void* d_out, int out_size, void* d_ws, size_t ws_size,
                              hipStream_t stream)
{
    const float* queries = (const float*)d_in[0];
    const float* keys    = (const float*)d_in[1];
    const float* values  = (const float*)d_in[2];
    const int*   adj     = (const int*)d_in[3];
    const float* epe     = (const float*)d_in[4];
    const float* Wq = (const float*)d_in[5];
    const float* bq = (const float*)d_in[6];
    const float* Wk = (const float*)d_in[7];
    const float* bk = (const float*)d_in[8];
    const float* Wv = (const float*)d_in[9];
    const float* bv = (const float*)d_in[10];
    const float* Wo = (const float*)d_in[11];
    const float* bo = (const float*)d_in[12];
    float* out = (float*)d_out;

    const int* dst = adj;
    const int* src = adj + NE;

    const int    M   = NB * LL;                     // 16384
    const size_t NLM = (size_t)M * MDL;             // 8,388,608

    char* w = (char*)d_ws;
    __hip_bfloat16* Qb  = (__hip_bfloat16*)w; w += NLM * 2;      // 16.78 MB
    __hip_bfloat16* Kb  = (__hip_bfloat16*)w; w += NLM * 2;
    __hip_bfloat16* Vb  = (__hip_bfloat16*)w; w += NLM * 2;
    __hip_bfloat16* Ob  = (__hip_bfloat16*)w; w += NLM * 2;
    __hip_bfloat16* Wqt = (__hip_bfloat16*)w; w += (size_t)MDL * IN_C * 2;
    __hip_bfloat16* Wkt = (__hip_bfloat16*)w; w += (size_t)MDL * IN_C * 2;
    __hip_bfloat16* Wvt = (__hip_bfloat16*)w; w += (size_t)MDL * IN_C * 2;
    __hip_bfloat16* Wot = (__hip_bfloat16*)w; w += (size_t)MDL * MDL * 2;
    int* counts  = (int*)w; w += 4096 * sizeof(int);
    int* offsets = (int*)w; w += 4100 * sizeof(int);
    int* cursor  = (int*)w; w += 4096 * sizeof(int);
    int* reorder = (int*)w; w += 4096 * sizeof(int);
    int*   src_s = (int*)w; w += NE * sizeof(int);
    float* epe_s   = (float*)w;  w += (size_t)NB * NE * 8 * sizeof(float);  // 8.39 MB
    float* score_s = (float*)w;  w += (size_t)NB * NE * 8 * sizeof(float);  // 8.39 MB
    float2* mz     = (float2*)w; w += (size_t)M * 8 * sizeof(float2);       // 1.05 MB

    // CSR build
    hipMemsetAsync(counts, 0, 4096 * sizeof(int), stream);
    count_edges<<<NE / 256, 256, 0, stream>>>(dst, counts, NE);
    scan_offsets<<<1, 1024, 0, stream>>>(counts, offsets, cursor, reorder);

    // fused prep: scatter+gather | weight transposes
    prep<<<896, 256, 0, stream>>>(dst, src, epe, cursor, src_s, epe_s,
                                  Wq, Wk, Wv, Wo, Wqt, Wkt, Wvt, Wot);

    // QKV projections (one launch, z=3, fused fp32->bf16 A-staging, BK=64,
    // XCD-aware tile map)
    dim3 g3(MDL / 128, M / 128, 3);
    gemm_qkv<<<g3, 256, 0, stream>>>(queries, keys, values, Wqt, Wkt, Wvt,
                                     bq, bk, bv, Qb, Kb, Vb, M, MDL, IN_C);

    // sparse attention, two phase-separated dispatches
    sparse_score<<<(NB * LL) / 4, 256, 0, stream>>>(Qb, Kb, src_s, epe_s,
                                                    offsets, reorder, score_s, mz);
    sparse_out<<<(NB * LL) / 4, 256, 0, stream>>>(Vb, src_s, score_s,
                                                  offsets, reorder, mz, Ob);

    // output projection (fp32 out + bias, BK=64, XCD-aware tile map)
    dim3 g(MDL / 128, M / 128);
    gemm_out<<<g, 256, 0, stream>>>(Ob, Wot, bo, out, M, MDL, MDL);
}

// Round 10
// 122.991 us; speedup vs baseline: 1.2768x; 1.0016x over previous
//
#include <hip/hip_runtime.h>
#include <hip/hip_bf16.h>
#include <math.h>
#include <stdint.h>

// Problem constants (SparseAttention_46969762349725)
#define HEADS 8
#define IN_C  256
#define MDL   512
#define NB    4        // batch
#define LL    4096     // nodes
#define NE    65536    // edges
#define EDIM  64       // per-head dim = MDL/HEADS
#define TEMP  0.125f   // 1/sqrt(64)

typedef __bf16 bf16x8 __attribute__((ext_vector_type(8)));
typedef float  f32x4  __attribute__((ext_vector_type(4)));
typedef short  short8 __attribute__((ext_vector_type(8)));

__device__ __forceinline__ void glds16(const void* g, void* l) {
    __builtin_amdgcn_global_load_lds(
        (const __attribute__((address_space(1))) void*)g,
        (__attribute__((address_space(3))) void*)l, 16, 0, 0);
}

__device__ __forceinline__ short8 cvt8(float4 a, float4 b) {
    union { short8 v; __hip_bfloat16 h[8]; } u;
    u.h[0] = __float2bfloat16(a.x); u.h[1] = __float2bfloat16(a.y);
    u.h[2] = __float2bfloat16(a.z); u.h[3] = __float2bfloat16(a.w);
    u.h[4] = __float2bfloat16(b.x); u.h[5] = __float2bfloat16(b.y);
    u.h[6] = __float2bfloat16(b.z); u.h[7] = __float2bfloat16(b.w);
    return u.v;
}

// XCD-aware tile map: 512 blocks/slice = 128 bm x 4 bn; each XCD owns 16
// contiguous bm (A footprint L2-resident) and walks bn outermost.
__device__ __forceinline__ void tile_map(int* bm, int* bn) {
    int lin = blockIdx.y * gridDim.x + blockIdx.x;   // 0..511
    int xcd = lin & 7;
    int t   = lin >> 3;                              // 0..63
    *bm = (xcd * 16 + (t & 15)) * 128;
    *bn = (t >> 4) * 128;
}

// ---------------- QKV GEMM: A fp32 (fused cvt), Bt bf16, C bf16 --------------
// 128x128 tile, BK=64, double-buffered LDS, 2-phase pipeline:
// issue next-tile loads BEFORE computing current tile.
__global__ __launch_bounds__(256) void gemm_qkv(
    const float* __restrict__ A0, const float* __restrict__ A1,
    const float* __restrict__ A2,
    const __hip_bfloat16* __restrict__ B0, const __hip_bfloat16* __restrict__ B1,
    const __hip_bfloat16* __restrict__ B2,
    const float* __restrict__ b0, const float* __restrict__ b1,
    const float* __restrict__ b2,
    __hip_bfloat16* __restrict__ C0, __hip_bfloat16* __restrict__ C1,
    __hip_bfloat16* __restrict__ C2, int M, int N, int K)
{
    __shared__ __align__(16) __hip_bfloat16 As[2][128 * 64];
    __shared__ __align__(16) __hip_bfloat16 Bs[2][128 * 64];

    const int z = blockIdx.z;
    const float* A           = (z == 0) ? A0 : (z == 1) ? A1 : A2;
    const __hip_bfloat16* Bt = (z == 0) ? B0 : (z == 1) ? B1 : B2;
    const float* bias        = (z == 0) ? b0 : (z == 1) ? b1 : b2;
    __hip_bfloat16* C        = (z == 0) ? C0 : (z == 1) ? C1 : C2;

    const int tid  = threadIdx.x;
    const int lane = tid & 63;
    const int w    = tid >> 6;
    const int wr   = w >> 1, wc = w & 1;
    int bm, bn;
    tile_map(&bm, &bn);

    // staging geometry: 1024 chunks (128 rows x 8 chunks of 8 bf16), 4/thread
    const float*          gA[4];
    const __hip_bfloat16* gB[4];
    int lAoff[4], lBoff[4];
    #pragma unroll
    for (int it = 0; it < 4; it++) {
        int idx  = it * 256 + tid;
        int r    = idx >> 3;
        int cpos = idx & 7;
        int cdat = cpos ^ (r & 7);
        gA[it]  = A  + (size_t)(bm + r) * K + cdat * 8;
        gB[it]  = Bt + (size_t)(bn + r) * K + cdat * 8;
        lAoff[it] = r * 64 + cpos * 8;
        lBoff[it] = (it * 256 + w * 64) * 8;
    }

    int fa[2][4], fb[2][4];
    #pragma unroll
    for (int kk = 0; kk < 2; kk++)
        #pragma unroll
        for (int i = 0; i < 4; i++) {
            int rA = wr * 64 + i * 16 + (lane & 15);
            int gc = kk * 4 + (lane >> 4);
            fa[kk][i] = rA * 64 + (gc ^ (rA & 7)) * 8;
            int rB = wc * 64 + i * 16 + (lane & 15);
            fb[kk][i] = rB * 64 + (gc ^ (rB & 7)) * 8;
        }

    f32x4 acc[4][4] = {};

    // prologue: stage k0=0 into buffer 0
    #pragma unroll
    for (int it = 0; it < 4; it++) glds16(gB[it], &Bs[0][lBoff[it]]);
    {
        float4 p0[4], p1[4];
        #pragma unroll
        for (int it = 0; it < 4; it++) {
            p0[it] = *(const float4*)(gA[it]);
            p1[it] = *(const float4*)(gA[it] + 4);
        }
        #pragma unroll
        for (int it = 0; it < 4; it++)
            *(short8*)&As[0][lAoff[it]] = cvt8(p0[it], p1[it]);
    }
    __syncthreads();

    int cur = 0;
    for (int k0 = 0; k0 < K; k0 += 64) {
        const int nxt = cur ^ 1;
        const bool has_next = (k0 + 64 < K);
        float4 p0[4], p1[4];
        if (has_next) {
            // issue next-tile loads FIRST (latency hides under MFMA below)
            #pragma unroll
            for (int it = 0; it < 4; it++)
                glds16(gB[it] + k0 + 64, &Bs[nxt][lBoff[it]]);
            #pragma unroll
            for (int it = 0; it < 4; it++) {
                p0[it] = *(const float4*)(gA[it] + k0 + 64);
                p1[it] = *(const float4*)(gA[it] + k0 + 64 + 4);
            }
        }

        // compute current buffer
        #pragma unroll
        for (int kk = 0; kk < 2; kk++) {
            bf16x8 av[4], bv[4];
            #pragma unroll
            for (int i = 0; i < 4; i++) av[i] = *(const bf16x8*)&As[cur][fa[kk][i]];
            #pragma unroll
            for (int i = 0; i < 4; i++) bv[i] = *(const bf16x8*)&Bs[cur][fb[kk][i]];
            #pragma unroll
            for (int mi = 0; mi < 4; mi++)
                #pragma unroll
                for (int ni = 0; ni < 4; ni++)
                    acc[mi][ni] = __builtin_amdgcn_mfma_f32_16x16x32_bf16(
                        av[mi], bv[ni], acc[mi][ni], 0, 0, 0);
        }

        if (has_next) {
            #pragma unroll
            for (int it = 0; it < 4; it++)
                *(short8*)&As[nxt][lAoff[it]] = cvt8(p0[it], p1[it]);
        }
        __syncthreads();
        cur = nxt;
    }

    #pragma unroll
    for (int mi = 0; mi < 4; mi++) {
        int row = bm + wr * 64 + mi * 16 + (lane >> 4) * 4;
        #pragma unroll
        for (int ni = 0; ni < 4; ni++) {
            int col = bn + wc * 64 + ni * 16 + (lane & 15);
            float bb = bias[col];
            #pragma unroll
            for (int j = 0; j < 4; j++)
                C[(size_t)(row + j) * N + col] = __float2bfloat16(acc[mi][ni][j] + bb);
        }
    }
}

// ---------------- output GEMM: bf16 x bf16 -> fp32, BK=64, 2-phase -----------
__global__ __launch_bounds__(256) void gemm_out(
    const __hip_bfloat16* __restrict__ A, const __hip_bfloat16* __restrict__ Bt,
    const float* __restrict__ bias, float* __restrict__ C, int M, int N, int K)
{
    __shared__ __align__(16) __hip_bfloat16 As[2][128 * 64];
    __shared__ __align__(16) __hip_bfloat16 Bs[2][128 * 64];

    const int tid  = threadIdx.x;
    const int lane = tid & 63;
    const int w    = tid >> 6;
    const int wr   = w >> 1, wc = w & 1;
    int bm, bn;
    tile_map(&bm, &bn);

    const __hip_bfloat16* gA[4];
    const __hip_bfloat16* gB[4];
    int lAoff[4], lBoff[4];
    #pragma unroll
    for (int it = 0; it < 4; it++) {
        int idx = it * 256 + tid;
        int r = idx >> 3;
        int c = (idx & 7) ^ (r & 7);
        gA[it] = A  + (size_t)(bm + r) * K + c * 8;
        gB[it] = Bt + (size_t)(bn + r) * K + c * 8;
        lAoff[it] = (it * 256 + w * 64) * 8;
        lBoff[it] = (it * 256 + w * 64) * 8;
    }

    int fa[2][4], fb[2][4];
    #pragma unroll
    for (int kk = 0; kk < 2; kk++)
        #pragma unroll
        for (int i = 0; i < 4; i++) {
            int rA = wr * 64 + i * 16 + (lane & 15);
            int gc = kk * 4 + (lane >> 4);
            fa[kk][i] = rA * 64 + (gc ^ (rA & 7)) * 8;
            int rB = wc * 64 + i * 16 + (lane & 15);
            fb[kk][i] = rB * 64 + (gc ^ (rB & 7)) * 8;
        }

    f32x4 acc[4][4] = {};

    // prologue
    #pragma unroll
    for (int it = 0; it < 4; it++) {
        glds16(gA[it], &As[0][lAoff[it]]);
        glds16(gB[it], &Bs[0][lBoff[it]]);
    }
    __syncthreads();

    int cur = 0;
    for (int k0 = 0; k0 < K; k0 += 64) {
        const int nxt = cur ^ 1;
        if (k0 + 64 < K) {
            #pragma unroll
            for (int it = 0; it < 4; it++) {
                glds16(gA[it] + k0 + 64, &As[nxt][lAoff[it]]);
                glds16(gB[it] + k0 + 64, &Bs[nxt][lBoff[it]]);
            }
        }

        #pragma unroll
        for (int kk = 0; kk < 2; kk++) {
            bf16x8 av[4], bv[4];
            #pragma unroll
            for (int i = 0; i < 4; i++) av[i] = *(const bf16x8*)&As[cur][fa[kk][i]];
            #pragma unroll
            for (int i = 0; i < 4; i++) bv[i] = *(const bf16x8*)&Bs[cur][fb[kk][i]];
            #pragma unroll
            for (int mi = 0; mi < 4; mi++)
                #pragma unroll
                for (int ni = 0; ni < 4; ni++)
                    acc[mi][ni] = __builtin_amdgcn_mfma_f32_16x16x32_bf16(
                        av[mi], bv[ni], acc[mi][ni], 0, 0, 0);
        }
        __syncthreads();
        cur = nxt;
    }

    #pragma unroll
    for (int mi = 0; mi < 4; mi++) {
        int row = bm + wr * 64 + mi * 16 + (lane >> 4) * 4;
        #pragma unroll
        for (int ni = 0; ni < 4; ni++) {
            int col = bn + wc * 64 + ni * 16 + (lane & 15);
            float bb = bias[col];
            #pragma unroll
            for (int j = 0; j < 4; j++)
                C[(size_t)(row + j) * N + col] = acc[mi][ni][j] + bb;
        }
    }
}

// ---------------- fused CSR build: histogram + scan + reorder ----------------
// one block, 1024 threads; LDS histogram of all 65536 dst entries, then scan
// to offsets/cursor and degree-descending bucket reorder.
__global__ __launch_bounds__(1024) void csr_build(
    const int* __restrict__ dst, int* __restrict__ offsets,
    int* __restrict__ cursor, int* __restrict__ reorder)
{
    __shared__ int hist[4096];
    __shared__ int wsum[16];
    __shared__ int bcnt[9], boff[9];
    const int tid  = threadIdx.x;
    const int lane = tid & 63;
    const int wid  = tid >> 6;

    #pragma unroll
    for (int i = 0; i < 4; i++) hist[tid + i * 1024] = 0;
    if (tid < 9) bcnt[tid] = 0;
    __syncthreads();

    const int4* d4 = (const int4*)dst;
    #pragma unroll
    for (int i = 0; i < 16; i++) {
        int4 v = d4[i * 1024 + tid];
        atomicAdd(&hist[v.x], 1);
        atomicAdd(&hist[v.y], 1);
        atomicAdd(&hist[v.z], 1);
        atomicAdd(&hist[v.w], 1);
    }
    __syncthreads();

    int c[4];
    int base = tid * 4;
    int s = 0;
    #pragma unroll
    for (int i = 0; i < 4; i++) { c[i] = hist[base + i]; s += c[i]; }

    int v = s;
    #pragma unroll
    for (int off = 1; off < 64; off <<= 1) {
        int t = __shfl_up(v, off);
        if (lane >= off) v += t;
    }
    if (lane == 63) wsum[wid] = v;
    __syncthreads();
    if (wid == 0) {
        int wv = (lane < 16) ? wsum[lane] : 0;
        #pragma unroll
        for (int off = 1; off < 16; off <<= 1) {
            int t = __shfl_up(wv, off);
            if (lane >= off) wv += t;
        }
        if (lane < 16) wsum[lane] = wv;
    }
    __syncthreads();

    int prefix = (wid > 0 ? wsum[wid - 1] : 0) + (v - s);
    int run = prefix;
    int mybk[4];
    #pragma unroll
    for (int i = 0; i < 4; i++) {
        offsets[base + i] = run;
        cursor[base + i]  = run;
        run += c[i];
        int sc = (c[i] + 7) >> 3; if (sc > 8) sc = 8;
        mybk[i] = 8 - sc;                       // 0 = heaviest bucket
        atomicAdd(&bcnt[mybk[i]], 1);
    }
    if (tid == 1023) offsets[4096] = run;
    __syncthreads();
    if (tid == 0) {
        int acc0 = 0;
        #pragma unroll
        for (int b = 0; b < 9; b++) { boff[b] = acc0; acc0 += bcnt[b]; }
    }
    __syncthreads();
    #pragma unroll
    for (int i = 0; i < 4; i++) {
        int pos = atomicAdd(&boff[mybk[i]], 1);
        reorder[pos] = base + i;
    }
}

// ---------------- fused prep: scatter(+gather) | weight transposes -----------
__global__ __launch_bounds__(256) void prep(
    const int* __restrict__ dst, const int* __restrict__ srcarr,
    const float* __restrict__ epe, int* __restrict__ cursor,
    int* __restrict__ src_s, float* __restrict__ epe_s,
    const float* __restrict__ Wq, const float* __restrict__ Wk,
    const float* __restrict__ Wv, const float* __restrict__ Wo,
    __hip_bfloat16* __restrict__ Wqt, __hip_bfloat16* __restrict__ Wkt,
    __hip_bfloat16* __restrict__ Wvt, __hip_bfloat16* __restrict__ Wot)
{
    __shared__ float t[32][33];
    const int b = blockIdx.x;

    if (b < 256) {
        int e = b * 256 + threadIdx.x;
        int p = atomicAdd(&cursor[dst[e]], 1);
        src_s[p] = srcarr[e];
        #pragma unroll
        for (int n = 0; n < NB; n++) {
            float4 a2, b2;
            const float* base = epe + (size_t)(n * HEADS) * NE + e;
            a2.x = base[0 * NE]; a2.y = base[1 * NE]; a2.z = base[2 * NE]; a2.w = base[3 * NE];
            b2.x = base[4 * NE]; b2.y = base[5 * NE]; b2.z = base[6 * NE]; b2.w = base[7 * NE];
            float* o = epe_s + ((size_t)n * NE + p) * 8;
            *(float4*)o       = a2;
            *(float4*)(o + 4) = b2;
        }
    } else {
        int bb = b - 256;
        const float* W; __hip_bfloat16* Wt; int K, tt;
        if (bb < 384) {
            int m = bb >> 7; tt = bb & 127; K = IN_C;
            W  = (m == 0) ? Wq  : (m == 1) ? Wk  : Wv;
            Wt = (m == 0) ? Wqt : (m == 1) ? Wkt : Wvt;
        } else {
            tt = bb - 384; K = MDL; W = Wo; Wt = Wot;
        }
        const int N = MDL;
        int bx = (tt & 15) * 32;            // n
        int by = (tt >> 4) * 32;            // k
        int tx = threadIdx.x & 31, ty = threadIdx.x >> 5;   // 32 x 8
        #pragma unroll
        for (int i = 0; i < 4; i++)
            t[ty + i * 8][tx] = W[(size_t)(by + ty + i * 8) * N + bx + tx];
        __syncthreads();
        #pragma unroll
        for (int i = 0; i < 4; i++)
            Wt[(size_t)(bx + ty + i * 8) * K + by + tx] =
                __float2bfloat16(t[tx][ty + i * 8]);
    }
}

// ---------------- pass 1: scores (K only) ------------------------------------
__global__ __launch_bounds__(256) void sparse_score(
    const __hip_bfloat16* __restrict__ Qb, const __hip_bfloat16* __restrict__ Kb,
    const int* __restrict__ src_s, const float* __restrict__ epe_s,
    const int* __restrict__ offsets, const int* __restrict__ reorder,
    float* __restrict__ score_s, float2* __restrict__ mz)
{
    const int lane = threadIdx.x & 63;
    const int wid  = threadIdx.x >> 6;
    const int bid  = blockIdx.x;
    const int xcd  = bid & 7;
    const int n    = xcd >> 1;
    const int base = ((bid >> 3) << 1) | (xcd & 1);
    const int dstn = reorder[(base << 2) | wid];
    const int task = n * LL + dstn;
    const int hg   = lane >> 3;

    const int beg = offsets[dstn];
    const int end = offsets[dstn + 1];
    const int deg = end - beg;
    if (deg == 0) return;

    bf16x8 q8 = *(const bf16x8*)(Qb + (size_t)task * MDL + lane * 8);
    float qf[8];
    #pragma unroll
    for (int j = 0; j < 8; j++) qf[j] = (float)q8[j];

    const __hip_bfloat16* Kn = Kb + (size_t)n * LL * MDL + lane * 8;
    const float* pe_n = epe_s + (size_t)n * NE * 8 + hg;
    float* sc_n = score_s + (size_t)n * NE * 8 + hg;

    float m = -INFINITY, z = 0.0f;

    if (deg <= 64) {
        const int my_src = src_s[beg + ((lane < deg) ? lane : (deg - 1))];

        #pragma unroll
        for (int slot = 0; slot < 8; slot++) {
            const int r0 = slot * 8;
            if (r0 < deg) {
                bf16x8 kk[8];
                #pragma unroll
                for (int j = 0; j < 8; j++) {
                    int s = __shfl(my_src, r0 + j);
                    kk[j] = *(const bf16x8*)(Kn + (size_t)s * MDL);
                }
                const int rel_mine = r0 + (lane & 7);
                float pp = (rel_mine < deg)
                         ? pe_n[(size_t)(beg + rel_mine) * 8] : -INFINITY;

                float p[8];
                #pragma unroll
                for (int j = 0; j < 8; j++) {
                    float d = 0.0f;
                    #pragma unroll
                    for (int dd = 0; dd < 8; dd++)
                        d = fmaf(qf[dd], (float)kk[j][dd], d);
                    p[j] = d;
                }
                // transpose-reduce butterfly within 8-lane groups
                float n0, n1, n2, n3, u0, u1, sraw;
                {
                    float a0 = (lane & 1) ? p[1] : p[0];
                    float b0 = (lane & 1) ? p[0] : p[1];
                    n0 = a0 + __shfl_xor(b0, 1);
                    float a1 = (lane & 1) ? p[3] : p[2];
                    float b1 = (lane & 1) ? p[2] : p[3];
                    n1 = a1 + __shfl_xor(b1, 1);
                    float a2 = (lane & 1) ? p[5] : p[4];
                    float b2 = (lane & 1) ? p[4] : p[5];
                    n2 = a2 + __shfl_xor(b2, 1);
                    float a3 = (lane & 1) ? p[7] : p[6];
                    float b3 = (lane & 1) ? p[6] : p[7];
                    n3 = a3 + __shfl_xor(b3, 1);

                    float c0 = (lane & 2) ? n1 : n0;
                    float d0 = (lane & 2) ? n0 : n1;
                    u0 = c0 + __shfl_xor(d0, 2);
                    float c1 = (lane & 2) ? n3 : n2;
                    float d1 = (lane & 2) ? n2 : n3;
                    u1 = c1 + __shfl_xor(d1, 2);

                    float e0 = (lane & 4) ? u1 : u0;
                    float f0 = (lane & 4) ? u0 : u1;
                    sraw = e0 + __shfl_xor(f0, 4);
                }

                float sc_my = TEMP * (sraw + pp);     // pads -> -inf
                if (rel_mine < deg)
                    sc_n[(size_t)(beg + rel_mine) * 8] = sc_my;

                float gm = sc_my;
                gm = fmaxf(gm, __shfl_xor(gm, 1));
                gm = fmaxf(gm, __shfl_xor(gm, 2));
                gm = fmaxf(gm, __shfl_xor(gm, 4));
                float mnew = fmaxf(m, gm);
                float e_my = __expf(sc_my - mnew);
                float gs = e_my;
                gs += __shfl_xor(gs, 1);
                gs += __shfl_xor(gs, 2);
                gs += __shfl_xor(gs, 4);
                z = z * __expf(m - mnew) + gs;
                m = mnew;
            }
        }
    } else {
        for (int i = beg; i < end; i += 4) {
            float sc4[4];
            #pragma unroll
            for (int j = 0; j < 4; j++) {
                int idx = i + j;
                int ok  = idx < end;
                int s   = ok ? src_s[idx] : src_s[beg];
                bf16x8 kk = *(const bf16x8*)(Kn + (size_t)s * MDL);
                float pp = ok ? pe_n[(size_t)idx * 8] : -INFINITY;
                float d = 0.0f;
                #pragma unroll
                for (int dd = 0; dd < 8; dd++) d += qf[dd] * (float)kk[dd];
                d += __shfl_xor(d, 1);
                d += __shfl_xor(d, 2);
                d += __shfl_xor(d, 4);
                sc4[j] = TEMP * (d + pp);
                if (ok && (lane & 7) == 0)
                    sc_n[(size_t)idx * 8] = sc4[j];
            }
            float mb   = fmaxf(fmaxf(sc4[0], sc4[1]), fmaxf(sc4[2], sc4[3]));
            float mnew = fmaxf(m, mb);
            float sc   = __expf(m - mnew);
            float s0 = __expf(sc4[0] - mnew);
            float s1 = __expf(sc4[1] - mnew);
            float s2 = __expf(sc4[2] - mnew);
            float s3 = __expf(sc4[3] - mnew);
            z = z * sc + (s0 + s1 + s2 + s3);
            m = mnew;
        }
    }

    if ((lane & 7) == 0) {
        float2 v; v.x = m; v.y = 1.0f / z;
        mz[(size_t)task * 8 + hg] = v;
    }
}

// ---------------- pass 2: output (V only), no serial chain -------------------
__global__ __launch_bounds__(256) void sparse_out(
    const __hip_bfloat16* __restrict__ Vb,
    const int* __restrict__ src_s, const float* __restrict__ score_s,
    const int* __restrict__ offsets, const int* __restrict__ reorder,
    const float2* __restrict__ mz, __hip_bfloat16* __restrict__ O)
{
    const int lane = threadIdx.x & 63;
    const int wid  = threadIdx.x >> 6;
    const int bid  = blockIdx.x;
    const int xcd  = bid & 7;
    const int n    = xcd >> 1;
    const int base = ((bid >> 3) << 1) | (xcd & 1);
    const int dstn = reorder[(base << 2) | wid];
    const int task = n * LL + dstn;
    const int hg   = lane >> 3;

    const size_t rowbase = (size_t)task * MDL;
    const int beg = offsets[dstn];
    const int end = offsets[dstn + 1];
    const int deg = end - beg;

    union { short8 v8; __hip_bfloat16 h[8]; } uo;
    if (deg == 0) {
        #pragma unroll
        for (int j = 0; j < 8; j++) uo.h[j] = __float2bfloat16(0.0f);
        *(short8*)(O + rowbase + lane * 8) = uo.v8;
        return;
    }

    float2 mzv = mz[(size_t)task * 8 + hg];
    const float m = mzv.x, zinv = mzv.y;

    const __hip_bfloat16* Vn = Vb + (size_t)n * LL * MDL + lane * 8;
    const float* sc_n = score_s + (size_t)n * NE * 8 + hg;

    float acc[8] = {};

    if (deg <= 64) {
        const int my_src = src_s[beg + ((lane < deg) ? lane : (deg - 1))];

        #pragma unroll
        for (int slot = 0; slot < 8; slot++) {
            const int r0 = slot * 8;
            if (r0 < deg) {
                bf16x8 vv[8];
                #pragma unroll
                for (int j = 0; j < 8; j++) {
                    int s = __shfl(my_src, r0 + j);
                    vv[j] = *(const bf16x8*)(Vn + (size_t)s * MDL);
                }
                const int rel_mine = r0 + (lane & 7);
                float sc = (rel_mine < deg)
                         ? sc_n[(size_t)(beg + rel_mine) * 8] : -INFINITY;
                float a_l = __expf(sc - m) * zinv;    // pads -> 0
                #pragma unroll
                for (int j = 0; j < 8; j++) {
                    float al = __shfl(a_l, (lane & 56) | j);
                    #pragma unroll
                    for (int dd = 0; dd < 8; dd++)
                        acc[dd] = fmaf(al, (float)vv[j][dd], acc[dd]);
                }
            }
        }
    } else {
        for (int i = beg; i < end; i += 4) {
            #pragma unroll
            for (int j = 0; j < 4; j++) {
                int idx = i + j;
                int ok  = idx < end;
                int s   = ok ? src_s[idx] : src_s[beg];
                bf16x8 vv = *(const bf16x8*)(Vn + (size_t)s * MDL);
                float sc = ok ? sc_n[(size_t)idx * 8] : -INFINITY;
                float al = __expf(sc - m) * zinv;
                #pragma unroll
                for (int dd = 0; dd < 8; dd++)
                    acc[dd] = fmaf(al, (float)vv[dd], acc[dd]);
            }
        }
    }

    #pragma unroll
    for (int j = 0; j < 8; j++) uo.h[j] = __float2bfloat16(acc[j]);
    *(short8*)(O + rowbase + lane * 8) = uo.v8;
}

// ---------------- launch ------------------------------------------------------
extern "C" void kernel_launch(void* const* d_in, const int* in_sizes, int n_in,
                              void* d_out, int out_size, void* d_ws, size_t ws_size,
                              hipStream_t stream)
{
    const float* queries = (const float*)d_in[0];
    const float* keys    = (const float*)d_in[1];
    const float* values  = (const float*)d_in[2];
    const int*   adj     = (const int*)d_in[3];
    const float* epe     = (const float*)d_in[4];
    const float* Wq = (const float*)d_in[5];
    const float* bq = (const float*)d_in[6];
    const float* Wk = (const float*)d_in[7];
    const float* bk = (const float*)d_in[8];
    const float* Wv = (const float*)d_in[9];
    const float* bv = (const float*)d_in[10];
    const float* Wo = (const float*)d_in[11];
    const float* bo = (const float*)d_in[12];
    float* out = (float*)d_out;

    const int* dst = adj;
    const int* src = adj + NE;

    const int    M   = NB * LL;                     // 16384
    const size_t NLM = (size_t)M * MDL;             // 8,388,608

    char* w = (char*)d_ws;
    __hip_bfloat16* Qb  = (__hip_bfloat16*)w; w += NLM * 2;      // 16.78 MB
    __hip_bfloat16* Kb  = (__hip_bfloat16*)w; w += NLM * 2;
    __hip_bfloat16* Vb  = (__hip_bfloat16*)w; w += NLM * 2;
    __hip_bfloat16* Ob  = (__hip_bfloat16*)w; w += NLM * 2;
    __hip_bfloat16* Wqt = (__hip_bfloat16*)w; w += (size_t)MDL * IN_C * 2;
    __hip_bfloat16* Wkt = (__hip_bfloat16*)w; w += (size_t)MDL * IN_C * 2;
    __hip_bfloat16* Wvt = (__hip_bfloat16*)w; w += (size_t)MDL * IN_C * 2;
    __hip_bfloat16* Wot = (__hip_bfloat16*)w; w += (size_t)MDL * MDL * 2;
    int* offsets = (int*)w; w += 4100 * sizeof(int);
    int* cursor  = (int*)w; w += 4096 * sizeof(int);
    int* reorder = (int*)w; w += 4096 * sizeof(int);
    int*   src_s = (int*)w; w += NE * sizeof(int);
    float* epe_s   = (float*)w;  w += (size_t)NB * NE * 8 * sizeof(float);  // 8.39 MB
    float* score_s = (float*)w;  w += (size_t)NB * NE * 8 * sizeof(float);  // 8.39 MB
    float2* mz     = (float2*)w; w += (size_t)M * 8 * sizeof(float2);       // 1.05 MB

    // CSR build: one fused kernel (histogram + scan + reorder)
    csr_build<<<1, 1024, 0, stream>>>(dst, offsets, cursor, reorder);

    // fused prep: scatter+gather | weight transposes
    prep<<<896, 256, 0, stream>>>(dst, src, epe, cursor, src_s, epe_s,
                                  Wq, Wk, Wv, Wo, Wqt, Wkt, Wvt, Wot);

    // QKV projections (one launch, z=3, fused fp32->bf16 A-staging, BK=64,
    // double-buffered 2-phase pipeline, XCD-aware tile map)
    dim3 g3(MDL / 128, M / 128, 3);
    gemm_qkv<<<g3, 256, 0, stream>>>(queries, keys, values, Wqt, Wkt, Wvt,
                                     bq, bk, bv, Qb, Kb, Vb, M, MDL, IN_C);

    // sparse attention, two phase-separated dispatches
    sparse_score<<<(NB * LL) / 4, 256, 0, stream>>>(Qb, Kb, src_s, epe_s,
                                                    offsets, reorder, score_s, mz);
    sparse_out<<<(NB * LL) / 4, 256, 0, stream>>>(Vb, src_s, score_s,
                                                  offsets, reorder, mz, Ob);

    // output projection (fp32 out + bias, BK=64, 2-phase, XCD-aware tile map)
    dim3 g(MDL / 128, M / 128);
    gemm_out<<<g, 256, 0, stream>>>(Ob, Wot, bo, out, M, MDL, MDL);
}

// Round 11
// 116.372 us; speedup vs baseline: 1.3494x; 1.0569x over previous
//
#include <hip/hip_runtime.h>
#include <hip/hip_bf16.h>
#include <math.h>
#include <stdint.h>

// Problem constants (SparseAttention_46969762349725)
#define HEADS 8
#define IN_C  256
#define MDL   512
#define NB    4        // batch
#define LL    4096     // nodes
#define NE    65536    // edges
#define EDIM  64       // per-head dim = MDL/HEADS
#define TEMP  0.125f   // 1/sqrt(64)

typedef __bf16 bf16x8 __attribute__((ext_vector_type(8)));
typedef float  f32x4  __attribute__((ext_vector_type(4)));
typedef short  short8 __attribute__((ext_vector_type(8)));

__device__ __forceinline__ void glds16(const void* g, void* l) {
    __builtin_amdgcn_global_load_lds(
        (const __attribute__((address_space(1))) void*)g,
        (__attribute__((address_space(3))) void*)l, 16, 0, 0);
}

__device__ __forceinline__ short8 cvt8(float4 a, float4 b) {
    union { short8 v; __hip_bfloat16 h[8]; } u;
    u.h[0] = __float2bfloat16(a.x); u.h[1] = __float2bfloat16(a.y);
    u.h[2] = __float2bfloat16(a.z); u.h[3] = __float2bfloat16(a.w);
    u.h[4] = __float2bfloat16(b.x); u.h[5] = __float2bfloat16(b.y);
    u.h[6] = __float2bfloat16(b.z); u.h[7] = __float2bfloat16(b.w);
    return u.v;
}

// ---------------- QKV GEMM: flat 1536-block grid, z folded into blockIdx -----
// 128x128 tile, BK=64, single-buffer LDS (32KB -> ~5 blocks/CU), 4 waves.
// XCD map: each XCD walks 16 contiguous bm-tiles of one z at a time
// (A footprint 2.1MB, L2-resident), bn outermost within z.
__global__ __launch_bounds__(256) void gemm_qkv(
    const float* __restrict__ A0, const float* __restrict__ A1,
    const float* __restrict__ A2,
    const __hip_bfloat16* __restrict__ B0, const __hip_bfloat16* __restrict__ B1,
    const __hip_bfloat16* __restrict__ B2,
    const float* __restrict__ b0, const float* __restrict__ b1,
    const float* __restrict__ b2,
    __hip_bfloat16* __restrict__ C0, __hip_bfloat16* __restrict__ C1,
    __hip_bfloat16* __restrict__ C2)
{
    __shared__ __align__(16) __hip_bfloat16 As[128 * 64];
    __shared__ __align__(16) __hip_bfloat16 Bs[128 * 64];

    const int K = IN_C, N = MDL;
    const int lin  = blockIdx.x;            // 0..1535
    const int xcd  = lin & 7;
    const int t    = lin >> 3;              // 0..191
    const int z    = t >> 6;                // 0..2
    const int rest = t & 63;
    const int bm   = (xcd * 16 + (rest & 15)) * 128;
    const int bn   = (rest >> 4) * 128;

    const float* A           = (z == 0) ? A0 : (z == 1) ? A1 : A2;
    const __hip_bfloat16* Bt = (z == 0) ? B0 : (z == 1) ? B1 : B2;
    const float* bias        = (z == 0) ? b0 : (z == 1) ? b1 : b2;
    __hip_bfloat16* C        = (z == 0) ? C0 : (z == 1) ? C1 : C2;

    const int tid  = threadIdx.x;
    const int lane = tid & 63;
    const int w    = tid >> 6;
    const int wr   = w >> 1, wc = w & 1;

    // staging: 1024 chunks (128 rows x 8 chunks of 8 elems), 4 per thread
    const float*          gA[4];
    const __hip_bfloat16* gB[4];
    __hip_bfloat16* lAw[4];
    __hip_bfloat16* lB[4];
    #pragma unroll
    for (int it = 0; it < 4; it++) {
        int idx  = it * 256 + tid;
        int r    = idx >> 3;
        int cpos = idx & 7;
        int cdat = cpos ^ (r & 7);
        gA[it]  = A  + (size_t)(bm + r) * K + cdat * 8;
        gB[it]  = Bt + (size_t)(bn + r) * K + cdat * 8;
        lAw[it] = As + r * 64 + cpos * 8;
        lB[it]  = Bs + (size_t)(it * 256 + w * 64) * 8;
    }

    int fa[2][4], fb[2][4];
    #pragma unroll
    for (int kk = 0; kk < 2; kk++)
        #pragma unroll
        for (int i = 0; i < 4; i++) {
            int rA = wr * 64 + i * 16 + (lane & 15);
            int gc = kk * 4 + (lane >> 4);
            fa[kk][i] = rA * 64 + (gc ^ (rA & 7)) * 8;
            int rB = wc * 64 + i * 16 + (lane & 15);
            fb[kk][i] = rB * 64 + (gc ^ (rB & 7)) * 8;
        }

    f32x4 acc[4][4] = {};

    for (int k0 = 0; k0 < K; k0 += 64) {
        #pragma unroll
        for (int it = 0; it < 4; it++) glds16(gB[it] + k0, lB[it]);
        #pragma unroll
        for (int it = 0; it < 4; it++) {
            float4 a = *(const float4*)(gA[it] + k0);
            float4 b = *(const float4*)(gA[it] + k0 + 4);
            *(short8*)lAw[it] = cvt8(a, b);
        }
        __syncthreads();

        #pragma unroll
        for (int kk = 0; kk < 2; kk++) {
            bf16x8 av[4], bv[4];
            #pragma unroll
            for (int i = 0; i < 4; i++) av[i] = *(const bf16x8*)(As + fa[kk][i]);
            #pragma unroll
            for (int i = 0; i < 4; i++) bv[i] = *(const bf16x8*)(Bs + fb[kk][i]);
            #pragma unroll
            for (int mi = 0; mi < 4; mi++)
                #pragma unroll
                for (int ni = 0; ni < 4; ni++)
                    acc[mi][ni] = __builtin_amdgcn_mfma_f32_16x16x32_bf16(
                        av[mi], bv[ni], acc[mi][ni], 0, 0, 0);
        }
        __syncthreads();
    }

    #pragma unroll
    for (int mi = 0; mi < 4; mi++) {
        int row = bm + wr * 64 + mi * 16 + (lane >> 4) * 4;
        #pragma unroll
        for (int ni = 0; ni < 4; ni++) {
            int col = bn + wc * 64 + ni * 16 + (lane & 15);
            float bb = bias[col];
            #pragma unroll
            for (int j = 0; j < 4; j++)
                C[(size_t)(row + j) * N + col] = __float2bfloat16(acc[mi][ni][j] + bb);
        }
    }
}

// ---------------- output GEMM: 64x128 tile, 1024 blocks, BK=64 ---------------
// LDS 24KB -> ~6 blocks/CU. XCD map: 32 contiguous bm-tiles/XCD (2MB, L2-fit).
__global__ __launch_bounds__(256) void gemm_out(
    const __hip_bfloat16* __restrict__ A, const __hip_bfloat16* __restrict__ Bt,
    const float* __restrict__ bias, float* __restrict__ C)
{
    __shared__ __align__(16) __hip_bfloat16 As[64 * 64];
    __shared__ __align__(16) __hip_bfloat16 Bs[128 * 64];

    const int K = MDL, N = MDL;
    const int lin = blockIdx.x;             // 0..1023
    const int xcd = lin & 7;
    const int t   = lin >> 3;               // 0..127
    const int bm  = (xcd * 32 + (t & 31)) * 64;
    const int bn  = (t >> 5) * 128;

    const int tid  = threadIdx.x;
    const int lane = tid & 63;
    const int w    = tid >> 6;
    const int wr   = w >> 1, wc = w & 1;    // wave: 32 rows x 64 cols

    // A staging: 512 chunks (64 rows x 8), 2 per thread
    const __hip_bfloat16* gA[2];
    __hip_bfloat16* lA[2];
    #pragma unroll
    for (int it = 0; it < 2; it++) {
        int idx = it * 256 + tid;
        int r = idx >> 3;
        int c = (idx & 7) ^ (r & 7);
        gA[it] = A + (size_t)(bm + r) * K + c * 8;
        lA[it] = As + (size_t)(it * 256 + w * 64) * 8;
    }
    // B staging: 1024 chunks (128 rows x 8), 4 per thread
    const __hip_bfloat16* gB[4];
    __hip_bfloat16* lB[4];
    #pragma unroll
    for (int it = 0; it < 4; it++) {
        int idx = it * 256 + tid;
        int r = idx >> 3;
        int c = (idx & 7) ^ (r & 7);
        gB[it] = Bt + (size_t)(bn + r) * K + c * 8;
        lB[it] = Bs + (size_t)(it * 256 + w * 64) * 8;
    }

    int fa[2][2], fb[2][4];
    #pragma unroll
    for (int kk = 0; kk < 2; kk++) {
        int gc = kk * 4 + (lane >> 4);
        #pragma unroll
        for (int i = 0; i < 2; i++) {
            int rA = wr * 32 + i * 16 + (lane & 15);
            fa[kk][i] = rA * 64 + (gc ^ (rA & 7)) * 8;
        }
        #pragma unroll
        for (int i = 0; i < 4; i++) {
            int rB = wc * 64 + i * 16 + (lane & 15);
            fb[kk][i] = rB * 64 + (gc ^ (rB & 7)) * 8;
        }
    }

    f32x4 acc[2][4] = {};

    for (int k0 = 0; k0 < K; k0 += 64) {
        #pragma unroll
        for (int it = 0; it < 2; it++) glds16(gA[it] + k0, lA[it]);
        #pragma unroll
        for (int it = 0; it < 4; it++) glds16(gB[it] + k0, lB[it]);
        __syncthreads();

        #pragma unroll
        for (int kk = 0; kk < 2; kk++) {
            bf16x8 av[2], bv[4];
            #pragma unroll
            for (int i = 0; i < 2; i++) av[i] = *(const bf16x8*)(As + fa[kk][i]);
            #pragma unroll
            for (int i = 0; i < 4; i++) bv[i] = *(const bf16x8*)(Bs + fb[kk][i]);
            #pragma unroll
            for (int mi = 0; mi < 2; mi++)
                #pragma unroll
                for (int ni = 0; ni < 4; ni++)
                    acc[mi][ni] = __builtin_amdgcn_mfma_f32_16x16x32_bf16(
                        av[mi], bv[ni], acc[mi][ni], 0, 0, 0);
        }
        __syncthreads();
    }

    #pragma unroll
    for (int mi = 0; mi < 2; mi++) {
        int row = bm + wr * 32 + mi * 16 + (lane >> 4) * 4;
        #pragma unroll
        for (int ni = 0; ni < 4; ni++) {
            int col = bn + wc * 64 + ni * 16 + (lane & 15);
            float bb = bias[col];
            #pragma unroll
            for (int j = 0; j < 4; j++)
                C[(size_t)(row + j) * N + col] = acc[mi][ni][j] + bb;
        }
    }
}

// ---------------- fused CSR build: histogram + scan + reorder ----------------
__global__ __launch_bounds__(1024) void csr_build(
    const int* __restrict__ dst, int* __restrict__ offsets,
    int* __restrict__ cursor, int* __restrict__ reorder)
{
    __shared__ int hist[4096];
    __shared__ int wsum[16];
    __shared__ int bcnt[9], boff[9];
    const int tid  = threadIdx.x;
    const int lane = tid & 63;
    const int wid  = tid >> 6;

    #pragma unroll
    for (int i = 0; i < 4; i++) hist[tid + i * 1024] = 0;
    if (tid < 9) bcnt[tid] = 0;
    __syncthreads();

    const int4* d4 = (const int4*)dst;
    #pragma unroll
    for (int i = 0; i < 16; i++) {
        int4 v = d4[i * 1024 + tid];
        atomicAdd(&hist[v.x], 1);
        atomicAdd(&hist[v.y], 1);
        atomicAdd(&hist[v.z], 1);
        atomicAdd(&hist[v.w], 1);
    }
    __syncthreads();

    int c[4];
    int base = tid * 4;
    int s = 0;
    #pragma unroll
    for (int i = 0; i < 4; i++) { c[i] = hist[base + i]; s += c[i]; }

    int v = s;
    #pragma unroll
    for (int off = 1; off < 64; off <<= 1) {
        int t = __shfl_up(v, off);
        if (lane >= off) v += t;
    }
    if (lane == 63) wsum[wid] = v;
    __syncthreads();
    if (wid == 0) {
        int wv = (lane < 16) ? wsum[lane] : 0;
        #pragma unroll
        for (int off = 1; off < 16; off <<= 1) {
            int t = __shfl_up(wv, off);
            if (lane >= off) wv += t;
        }
        if (lane < 16) wsum[lane] = wv;
    }
    __syncthreads();

    int prefix = (wid > 0 ? wsum[wid - 1] : 0) + (v - s);
    int run = prefix;
    int mybk[4];
    #pragma unroll
    for (int i = 0; i < 4; i++) {
        offsets[base + i] = run;
        cursor[base + i]  = run;
        run += c[i];
        int sc = (c[i] + 7) >> 3; if (sc > 8) sc = 8;
        mybk[i] = 8 - sc;                       // 0 = heaviest bucket
        atomicAdd(&bcnt[mybk[i]], 1);
    }
    if (tid == 1023) offsets[4096] = run;
    __syncthreads();
    if (tid == 0) {
        int acc0 = 0;
        #pragma unroll
        for (int b = 0; b < 9; b++) { boff[b] = acc0; acc0 += bcnt[b]; }
    }
    __syncthreads();
    #pragma unroll
    for (int i = 0; i < 4; i++) {
        int pos = atomicAdd(&boff[mybk[i]], 1);
        reorder[pos] = base + i;
    }
}

// ---------------- fused prep: scatter(+gather) | weight transposes -----------
__global__ __launch_bounds__(256) void prep(
    const int* __restrict__ dst, const int* __restrict__ srcarr,
    const float* __restrict__ epe, int* __restrict__ cursor,
    int* __restrict__ src_s, float* __restrict__ epe_s,
    const float* __restrict__ Wq, const float* __restrict__ Wk,
    const float* __restrict__ Wv, const float* __restrict__ Wo,
    __hip_bfloat16* __restrict__ Wqt, __hip_bfloat16* __restrict__ Wkt,
    __hip_bfloat16* __restrict__ Wvt, __hip_bfloat16* __restrict__ Wot)
{
    __shared__ float t[32][33];
    const int b = blockIdx.x;

    if (b < 256) {
        int e = b * 256 + threadIdx.x;
        int p = atomicAdd(&cursor[dst[e]], 1);
        src_s[p] = srcarr[e];
        #pragma unroll
        for (int n = 0; n < NB; n++) {
            float4 a2, b2;
            const float* base = epe + (size_t)(n * HEADS) * NE + e;
            a2.x = base[0 * NE]; a2.y = base[1 * NE]; a2.z = base[2 * NE]; a2.w = base[3 * NE];
            b2.x = base[4 * NE]; b2.y = base[5 * NE]; b2.z = base[6 * NE]; b2.w = base[7 * NE];
            float* o = epe_s + ((size_t)n * NE + p) * 8;
            *(float4*)o       = a2;
            *(float4*)(o + 4) = b2;
        }
    } else {
        int bb = b - 256;
        const float* W; __hip_bfloat16* Wt; int K, tt;
        if (bb < 384) {
            int m = bb >> 7; tt = bb & 127; K = IN_C;
            W  = (m == 0) ? Wq  : (m == 1) ? Wk  : Wv;
            Wt = (m == 0) ? Wqt : (m == 1) ? Wkt : Wvt;
        } else {
            tt = bb - 384; K = MDL; W = Wo; Wt = Wot;
        }
        const int N = MDL;
        int bx = (tt & 15) * 32;            // n
        int by = (tt >> 4) * 32;            // k
        int tx = threadIdx.x & 31, ty = threadIdx.x >> 5;   // 32 x 8
        #pragma unroll
        for (int i = 0; i < 4; i++)
            t[ty + i * 8][tx] = W[(size_t)(by + ty + i * 8) * N + bx + tx];
        __syncthreads();
        #pragma unroll
        for (int i = 0; i < 4; i++)
            Wt[(size_t)(bx + ty + i * 8) * K + by + tx] =
                __float2bfloat16(t[tx][ty + i * 8]);
    }
}

// ---------------- pass 1: scores (K only) ------------------------------------
__global__ __launch_bounds__(256) void sparse_score(
    const __hip_bfloat16* __restrict__ Qb, const __hip_bfloat16* __restrict__ Kb,
    const int* __restrict__ src_s, const float* __restrict__ epe_s,
    const int* __restrict__ offsets, const int* __restrict__ reorder,
    float* __restrict__ score_s, float2* __restrict__ mz)
{
    const int lane = threadIdx.x & 63;
    const int wid  = threadIdx.x >> 6;
    const int bid  = blockIdx.x;
    const int xcd  = bid & 7;
    const int n    = xcd >> 1;
    const int base = ((bid >> 3) << 1) | (xcd & 1);
    const int dstn = reorder[(base << 2) | wid];
    const int task = n * LL + dstn;
    const int hg   = lane >> 3;

    const int beg = offsets[dstn];
    const int end = offsets[dstn + 1];
    const int deg = end - beg;
    if (deg == 0) return;

    bf16x8 q8 = *(const bf16x8*)(Qb + (size_t)task * MDL + lane * 8);
    float qf[8];
    #pragma unroll
    for (int j = 0; j < 8; j++) qf[j] = (float)q8[j];

    const __hip_bfloat16* Kn = Kb + (size_t)n * LL * MDL + lane * 8;
    const float* pe_n = epe_s + (size_t)n * NE * 8 + hg;
    float* sc_n = score_s + (size_t)n * NE * 8 + hg;

    float m = -INFINITY, z = 0.0f;

    if (deg <= 64) {
        const int my_src = src_s[beg + ((lane < deg) ? lane : (deg - 1))];

        #pragma unroll
        for (int slot = 0; slot < 8; slot++) {
            const int r0 = slot * 8;
            if (r0 < deg) {
                bf16x8 kk[8];
                #pragma unroll
                for (int j = 0; j < 8; j++) {
                    int s = __shfl(my_src, r0 + j);
                    kk[j] = *(const bf16x8*)(Kn + (size_t)s * MDL);
                }
                const int rel_mine = r0 + (lane & 7);
                float pp = (rel_mine < deg)
                         ? pe_n[(size_t)(beg + rel_mine) * 8] : -INFINITY;

                float p[8];
                #pragma unroll
                for (int j = 0; j < 8; j++) {
                    float d = 0.0f;
                    #pragma unroll
                    for (int dd = 0; dd < 8; dd++)
                        d = fmaf(qf[dd], (float)kk[j][dd], d);
                    p[j] = d;
                }
                // transpose-reduce butterfly within 8-lane groups
                float n0, n1, n2, n3, u0, u1, sraw;
                {
                    float a0 = (lane & 1) ? p[1] : p[0];
                    float b0 = (lane & 1) ? p[0] : p[1];
                    n0 = a0 + __shfl_xor(b0, 1);
                    float a1 = (lane & 1) ? p[3] : p[2];
                    float b1 = (lane & 1) ? p[2] : p[3];
                    n1 = a1 + __shfl_xor(b1, 1);
                    float a2 = (lane & 1) ? p[5] : p[4];
                    float b2 = (lane & 1) ? p[4] : p[5];
                    n2 = a2 + __shfl_xor(b2, 1);
                    float a3 = (lane & 1) ? p[7] : p[6];
                    float b3 = (lane & 1) ? p[6] : p[7];
                    n3 = a3 + __shfl_xor(b3, 1);

                    float c0 = (lane & 2) ? n1 : n0;
                    float d0 = (lane & 2) ? n0 : n1;
                    u0 = c0 + __shfl_xor(d0, 2);
                    float c1 = (lane & 2) ? n3 : n2;
                    float d1 = (lane & 2) ? n2 : n3;
                    u1 = c1 + __shfl_xor(d1, 2);

                    float e0 = (lane & 4) ? u1 : u0;
                    float f0 = (lane & 4) ? u0 : u1;
                    sraw = e0 + __shfl_xor(f0, 4);
                }

                float sc_my = TEMP * (sraw + pp);     // pads -> -inf
                if (rel_mine < deg)
                    sc_n[(size_t)(beg + rel_mine) * 8] = sc_my;

                float gm = sc_my;
                gm = fmaxf(gm, __shfl_xor(gm, 1));
                gm = fmaxf(gm, __shfl_xor(gm, 2));
                gm = fmaxf(gm, __shfl_xor(gm, 4));
                float mnew = fmaxf(m, gm);
                float e_my = __expf(sc_my - mnew);
                float gs = e_my;
                gs += __shfl_xor(gs, 1);
                gs += __shfl_xor(gs, 2);
                gs += __shfl_xor(gs, 4);
                z = z * __expf(m - mnew) + gs;
                m = mnew;
            }
        }
    } else {
        for (int i = beg; i < end; i += 4) {
            float sc4[4];
            #pragma unroll
            for (int j = 0; j < 4; j++) {
                int idx = i + j;
                int ok  = idx < end;
                int s   = ok ? src_s[idx] : src_s[beg];
                bf16x8 kk = *(const bf16x8*)(Kn + (size_t)s * MDL);
                float pp = ok ? pe_n[(size_t)idx * 8] : -INFINITY;
                float d = 0.0f;
                #pragma unroll
                for (int dd = 0; dd < 8; dd++) d += qf[dd] * (float)kk[dd];
                d += __shfl_xor(d, 1);
                d += __shfl_xor(d, 2);
                d += __shfl_xor(d, 4);
                sc4[j] = TEMP * (d + pp);
                if (ok && (lane & 7) == 0)
                    sc_n[(size_t)idx * 8] = sc4[j];
            }
            float mb   = fmaxf(fmaxf(sc4[0], sc4[1]), fmaxf(sc4[2], sc4[3]));
            float mnew = fmaxf(m, mb);
            float sc   = __expf(m - mnew);
            float s0 = __expf(sc4[0] - mnew);
            float s1 = __expf(sc4[1] - mnew);
            float s2 = __expf(sc4[2] - mnew);
            float s3 = __expf(sc4[3] - mnew);
            z = z * sc + (s0 + s1 + s2 + s3);
            m = mnew;
        }
    }

    if ((lane & 7) == 0) {
        float2 v; v.x = m; v.y = 1.0f / z;
        mz[(size_t)task * 8 + hg] = v;
    }
}

// ---------------- pass 2: output (V only), no serial chain -------------------
__global__ __launch_bounds__(256) void sparse_out(
    const __hip_bfloat16* __restrict__ Vb,
    const int* __restrict__ src_s, const float* __restrict__ score_s,
    const int* __restrict__ offsets, const int* __restrict__ reorder,
    const float2* __restrict__ mz, __hip_bfloat16* __restrict__ O)
{
    const int lane = threadIdx.x & 63;
    const int wid  = threadIdx.x >> 6;
    const int bid  = blockIdx.x;
    const int xcd  = bid & 7;
    const int n    = xcd >> 1;
    const int base = ((bid >> 3) << 1) | (xcd & 1);
    const int dstn = reorder[(base << 2) | wid];
    const int task = n * LL + dstn;
    const int hg   = lane >> 3;

    const size_t rowbase = (size_t)task * MDL;
    const int beg = offsets[dstn];
    const int end = offsets[dstn + 1];
    const int deg = end - beg;

    union { short8 v8; __hip_bfloat16 h[8]; } uo;
    if (deg == 0) {
        #pragma unroll
        for (int j = 0; j < 8; j++) uo.h[j] = __float2bfloat16(0.0f);
        *(short8*)(O + rowbase + lane * 8) = uo.v8;
        return;
    }

    float2 mzv = mz[(size_t)task * 8 + hg];
    const float m = mzv.x, zinv = mzv.y;

    const __hip_bfloat16* Vn = Vb + (size_t)n * LL * MDL + lane * 8;
    const float* sc_n = score_s + (size_t)n * NE * 8 + hg;

    float acc[8] = {};

    if (deg <= 64) {
        const int my_src = src_s[beg + ((lane < deg) ? lane : (deg - 1))];

        #pragma unroll
        for (int slot = 0; slot < 8; slot++) {
            const int r0 = slot * 8;
            if (r0 < deg) {
                bf16x8 vv[8];
                #pragma unroll
                for (int j = 0; j < 8; j++) {
                    int s = __shfl(my_src, r0 + j);
                    vv[j] = *(const bf16x8*)(Vn + (size_t)s * MDL);
                }
                const int rel_mine = r0 + (lane & 7);
                float sc = (rel_mine < deg)
                         ? sc_n[(size_t)(beg + rel_mine) * 8] : -INFINITY;
                float a_l = __expf(sc - m) * zinv;    // pads -> 0
                #pragma unroll
                for (int j = 0; j < 8; j++) {
                    float al = __shfl(a_l, (lane & 56) | j);
                    #pragma unroll
                    for (int dd = 0; dd < 8; dd++)
                        acc[dd] = fmaf(al, (float)vv[j][dd], acc[dd]);
                }
            }
        }
    } else {
        for (int i = beg; i < end; i += 4) {
            #pragma unroll
            for (int j = 0; j < 4; j++) {
                int idx = i + j;
                int ok  = idx < end;
                int s   = ok ? src_s[idx] : src_s[beg];
                bf16x8 vv = *(const bf16x8*)(Vn + (size_t)s * MDL);
                float sc = ok ? sc_n[(size_t)idx * 8] : -INFINITY;
                float al = __expf(sc - m) * zinv;
                #pragma unroll
                for (int dd = 0; dd < 8; dd++)
                    acc[dd] = fmaf(al, (float)vv[dd], acc[dd]);
            }
        }
    }

    #pragma unroll
    for (int j = 0; j < 8; j++) uo.h[j] = __float2bfloat16(acc[j]);
    *(short8*)(O + rowbase + lane * 8) = uo.v8;
}

// ---------------- launch ------------------------------------------------------
extern "C" void kernel_launch(void* const* d_in, const int* in_sizes, int n_in,
                              void* d_out, int out_size, void* d_ws, size_t ws_size,
                              hipStream_t stream)
{
    const float* queries = (const float*)d_in[0];
    const float* keys    = (const float*)d_in[1];
    const float* values  = (const float*)d_in[2];
    const int*   adj     = (const int*)d_in[3];
    const float* epe     = (const float*)d_in[4];
    const float* Wq = (const float*)d_in[5];
    const float* bq = (const float*)d_in[6];
    const float* Wk = (const float*)d_in[7];
    const float* bk = (const float*)d_in[8];
    const float* Wv = (const float*)d_in[9];
    const float* bv = (const float*)d_in[10];
    const float* Wo = (const float*)d_in[11];
    const float* bo = (const float*)d_in[12];
    float* out = (float*)d_out;

    const int* dst = adj;
    const int* src = adj + NE;

    const int    M   = NB * LL;                     // 16384
    const size_t NLM = (size_t)M * MDL;             // 8,388,608

    char* w = (char*)d_ws;
    __hip_bfloat16* Qb  = (__hip_bfloat16*)w; w += NLM * 2;      // 16.78 MB
    __hip_bfloat16* Kb  = (__hip_bfloat16*)w; w += NLM * 2;
    __hip_bfloat16* Vb  = (__hip_bfloat16*)w; w += NLM * 2;
    __hip_bfloat16* Ob  = (__hip_bfloat16*)w; w += NLM * 2;
    __hip_bfloat16* Wqt = (__hip_bfloat16*)w; w += (size_t)MDL * IN_C * 2;
    __hip_bfloat16* Wkt = (__hip_bfloat16*)w; w += (size_t)MDL * IN_C * 2;
    __hip_bfloat16* Wvt = (__hip_bfloat16*)w; w += (size_t)MDL * IN_C * 2;
    __hip_bfloat16* Wot = (__hip_bfloat16*)w; w += (size_t)MDL * MDL * 2;
    int* offsets = (int*)w; w += 4100 * sizeof(int);
    int* cursor  = (int*)w; w += 4096 * sizeof(int);
    int* reorder = (int*)w; w += 4096 * sizeof(int);
    int*   src_s = (int*)w; w += NE * sizeof(int);
    float* epe_s   = (float*)w;  w += (size_t)NB * NE * 8 * sizeof(float);  // 8.39 MB
    float* score_s = (float*)w;  w += (size_t)NB * NE * 8 * sizeof(float);  // 8.39 MB
    float2* mz     = (float2*)w; w += (size_t)M * 8 * sizeof(float2);       // 1.05 MB

    // CSR build: one fused kernel (histogram + scan + reorder)
    csr_build<<<1, 1024, 0, stream>>>(dst, offsets, cursor, reorder);

    // fused prep: scatter+gather | weight transposes
    prep<<<896, 256, 0, stream>>>(dst, src, epe, cursor, src_s, epe_s,
                                  Wq, Wk, Wv, Wo, Wqt, Wkt, Wvt, Wot);

    // QKV projections: ONE flat 1536-block launch (z folded into grid)
    gemm_qkv<<<1536, 256, 0, stream>>>(queries, keys, values, Wqt, Wkt, Wvt,
                                       bq, bk, bv, Qb, Kb, Vb);

    // sparse attention, two phase-separated dispatches
    sparse_score<<<(NB * LL) / 4, 256, 0, stream>>>(Qb, Kb, src_s, epe_s,
                                                    offsets, reorder, score_s, mz);
    sparse_out<<<(NB * LL) / 4, 256, 0, stream>>>(Vb, src_s, score_s,
                                                  offsets, reorder, mz, Ob);

    // output projection: 64x128 tiles, 1024 blocks
    gemm_out<<<1024, 256, 0, stream>>>(Ob, Wot, bo, out);
}